// Round 5
// baseline (306.873 us; speedup 1.0000x reference)
//
#include <hip/hip_runtime.h>
#include <hip/hip_bf16.h>

// ============================================================================
// IDASR pipeline on gfx950 — round 19.
// Post-mortem r18: 4 structurally different gemm_big schedules all land at
// 48±0.3us (only gather-BYTE reduction ever moved it). gemm_big is 17% of
// the pipeline and at a local floor — pivot to the other 239us.
// Change (pipeline-level, gemm_big kept byte-identical to r18):
//  * Attention-weight path FUSED into sampler: c1 MLP (98->256, Wc1 repacked
//    K-major for coalesced loads), c2 (256->49, 4 lanes/output from LDS),
//    and per-head softmax (same shfl math as softmax_k) now run per-q-block
//    inside sampler; attnval is written ONCE, post-softmax.
//  * Eliminates 3 dispatches (gemm_bt c1, gemm_bt c2 @64 blocks, softmax_k)
//    + relbuf/hid1/wcb round-trips (~25MB glue traffic).
//  * rel path now f32 end-to-end (was bf16 through relbuf) — accuracy up.
// ============================================================================

typedef unsigned short u16;
typedef unsigned int u32;
using frag_ab = __attribute__((ext_vector_type(8))) short;  // 8 x bf16
using frag_cd = __attribute__((ext_vector_type(4))) float;  // 4 x f32 acc

#define HW 4096
#define NQ 4096
#define KBIG 12576
#define SPLITK 16
#define KCHUNK 800
#define JMAX 5
#define KQ 2304
#define QSPLIT 3
#define QCHUNK 768
#define NBLK_QKV (64 * 6 * QSPLIT)   // 1152
#define NBLK_OFF1 (64 * 8)           // 512

static __device__ __forceinline__ u16 f2b(float f) {
  union { __hip_bfloat16 h; u16 u; } c; c.h = __float2bfloat16(f); return c.u;
}
static __device__ __forceinline__ float b2f(u16 v) {
  return __uint_as_float((u32)v << 16);
}
static __device__ __forceinline__ u32 pk2(float a, float b) {
  union { __hip_bfloat162 h; u32 u; } c;
  c.h = __float22bfloat162_rn(float2{a, b});
  return c.u;
}
// async global->LDS, 16B per lane. LDS dest is wave-uniform base + lane*16.
static __device__ __forceinline__ void glds16(const u16* g, u16* l) {
  __builtin_amdgcn_global_load_lds(
      (const __attribute__((address_space(1))) u32*)(g),
      (__attribute__((address_space(3))) u32*)(l), 16, 0, 0);
}
// sigma^{-1} for the 16B-slot swizzle sigma(l) = l ^ ((l>>2)&7).
static __device__ __forceinline__ int swz_inv(int t) {
  return t ^ ((t >> 2) & 7) ^ ((t >> 4) & 1);
}

#define BM 64
#define BN 64
#define BK 32
#define LDSS 40   // padded lds row stride for reg-staged tiles

// ---------------------------------------------------------------------------
// Generic bf16 GEMM (64x64 tile): off2 layer only now.
// ---------------------------------------------------------------------------
__global__ __launch_bounds__(256)
void gemm_bt(const u16* __restrict__ A, const u16* __restrict__ Bt,
             void* __restrict__ Cv, const float* __restrict__ bias,
             int N, int K, int ldc, int flags,   // 1=relu, 2=bf16 out
             long sA, long sB, long sC, int sBias)
{
  __shared__ u16 As[BM * LDSS];
  __shared__ u16 Bs[BN * LDSS];
  const int z = blockIdx.z;
  A  += (long)z * sA;
  Bt += (long)z * sB;
  const float* bz = bias ? bias + (long)z * sBias : nullptr;

  const int tid  = threadIdx.x;
  const int m0   = blockIdx.x * BM;
  const int n0   = blockIdx.y * BN;
  const int wave = tid >> 6, lane = tid & 63;
  const int mw = (wave & 1) * 32, nw = (wave >> 1) * 32;
  const int lr = lane & 15, lk = lane >> 4;
  const int srow = tid >> 2, scol = (tid & 3) * 8;

  frag_cd acc[2][2] = {};
  const u16* aptr = A + (size_t)(m0 + srow) * K + scol;
  const bool bok  = (n0 + srow) < N;
  const u16* bptr = Bt + (size_t)(n0 + srow) * K + scol;

  uint4 av = *(const uint4*)(aptr);
  uint4 bv = bok ? *(const uint4*)(bptr) : uint4{0u, 0u, 0u, 0u};

  for (int k0 = 0; k0 < K; k0 += BK) {
    *(uint4*)&As[srow * LDSS + scol] = av;
    *(uint4*)&Bs[srow * LDSS + scol] = bv;
    __syncthreads();
    if (k0 + BK < K) {
      av = *(const uint4*)(aptr + k0 + BK);
      bv = bok ? *(const uint4*)(bptr + k0 + BK) : uint4{0u, 0u, 0u, 0u};
    }
    frag_ab af0 = *(const frag_ab*)&As[(mw      + lr) * LDSS + lk * 8];
    frag_ab af1 = *(const frag_ab*)&As[(mw + 16 + lr) * LDSS + lk * 8];
    frag_ab bf0 = *(const frag_ab*)&Bs[(nw      + lr) * LDSS + lk * 8];
    frag_ab bf1 = *(const frag_ab*)&Bs[(nw + 16 + lr) * LDSS + lk * 8];
    acc[0][0] = __builtin_amdgcn_mfma_f32_16x16x32_bf16(af0, bf0, acc[0][0], 0, 0, 0);
    acc[0][1] = __builtin_amdgcn_mfma_f32_16x16x32_bf16(af0, bf1, acc[0][1], 0, 0, 0);
    acc[1][0] = __builtin_amdgcn_mfma_f32_16x16x32_bf16(af1, bf0, acc[1][0], 0, 0, 0);
    acc[1][1] = __builtin_amdgcn_mfma_f32_16x16x32_bf16(af1, bf1, acc[1][1], 0, 0, 0);
    __syncthreads();
  }

  const bool relu = flags & 1;
  const bool obf  = flags & 2;
  #pragma unroll
  for (int i = 0; i < 2; i++)
    #pragma unroll
    for (int j = 0; j < 2; j++) {
      int col = n0 + nw + j * 16 + lr;
      if (col >= N) continue;
      float badd = bz ? bz[col] : 0.f;
      #pragma unroll
      for (int r = 0; r < 4; r++) {
        int row = m0 + mw + i * 16 + lk * 4 + r;
        float v = acc[i][j][r] + badd;
        if (relu) v = fmaxf(v, 0.f);
        size_t idx = (size_t)z * sC + (size_t)row * ldc + col;
        if (obf) ((u16*)Cv)[idx] = f2b(v);
        else     ((float*)Cv)[idx] = v;
      }
    }
}

// ---------------------------------------------------------------------------
// Implicit-im2col conv GEMM, 64x64 tile (ch conv only now).
// ---------------------------------------------------------------------------
template<int W3, int SH, int PAD>
__global__ __launch_bounds__(256)
void gemm_conv(const u16* __restrict__ feat, const u16* __restrict__ Bt,
               void* __restrict__ Cv, const float* __restrict__ bias,
               int N, int K, int ldc, int flags, int FC, int cbStride,
               long sB, long sC, int sBias)
{
  __shared__ u16 As[BM * LDSS];
  __shared__ u16 Bs[BN * LDSS];
  const int z = blockIdx.z;
  Bt += (long)z * sB;
  const float* bz = bias ? bias + (long)z * sBias : nullptr;
  const int cb = z * cbStride;

  const int tid  = threadIdx.x;
  const int m0   = blockIdx.x * BM;
  const int n0   = blockIdx.y * BN;
  const int wave = tid >> 6, lane = tid & 63;
  const int mw = (wave & 1) * 32, nw = (wave >> 1) * 32;
  const int lr = lane & 15, lk = lane >> 4;
  const int srow = tid >> 2, scol = (tid & 3) * 8;
  const int p = m0 + srow, y = p >> 6, x = p & 63;

  frag_cd acc[2][2] = {};
  const bool bok  = (n0 + srow) < N;
  const u16* bptr = Bt + (size_t)(n0 + srow) * K + scol;

  auto stageA = [&](int k0) -> uint4 {
    int k = k0 + scol;
    int s = k >> SH;
    int c = k & ((1 << SH) - 1);
    int dy = s / W3, dx = s - dy * W3;
    int yy = y + dy - PAD, xx = x + dx - PAD;
    if (((unsigned)yy < 64u) && ((unsigned)xx < 64u))
      return *(const uint4*)&feat[(size_t)(yy * 64 + xx) * FC + cb + c];
    return uint4{0u, 0u, 0u, 0u};
  };

  uint4 av = stageA(0);
  uint4 bv = bok ? *(const uint4*)(bptr) : uint4{0u, 0u, 0u, 0u};

  for (int k0 = 0; k0 < K; k0 += BK) {
    *(uint4*)&As[srow * LDSS + scol] = av;
    *(uint4*)&Bs[srow * LDSS + scol] = bv;
    __syncthreads();
    if (k0 + BK < K) {
      av = stageA(k0 + BK);
      bv = bok ? *(const uint4*)(bptr + k0 + BK) : uint4{0u, 0u, 0u, 0u};
    }
    frag_ab af0 = *(const frag_ab*)&As[(mw      + lr) * LDSS + lk * 8];
    frag_ab af1 = *(const frag_ab*)&As[(mw + 16 + lr) * LDSS + lk * 8];
    frag_ab bf0 = *(const frag_ab*)&Bs[(nw      + lr) * LDSS + lk * 8];
    frag_ab bf1 = *(const frag_ab*)&Bs[(nw + 16 + lr) * LDSS + lk * 8];
    acc[0][0] = __builtin_amdgcn_mfma_f32_16x16x32_bf16(af0, bf0, acc[0][0], 0, 0, 0);
    acc[0][1] = __builtin_amdgcn_mfma_f32_16x16x32_bf16(af0, bf1, acc[0][1], 0, 0, 0);
    acc[1][0] = __builtin_amdgcn_mfma_f32_16x16x32_bf16(af1, bf0, acc[1][0], 0, 0, 0);
    acc[1][1] = __builtin_amdgcn_mfma_f32_16x16x32_bf16(af1, bf1, acc[1][1], 0, 0, 0);
    __syncthreads();
  }

  const bool relu = flags & 1;
  const bool obf  = flags & 2;
  #pragma unroll
  for (int i = 0; i < 2; i++)
    #pragma unroll
    for (int j = 0; j < 2; j++) {
      int col = n0 + nw + j * 16 + lr;
      if (col >= N) continue;
      float badd = bz ? bz[col] : 0.f;
      #pragma unroll
      for (int r = 0; r < 4; r++) {
        int row = m0 + mw + i * 16 + lk * 4 + r;
        float v = acc[i][j][r] + badd;
        if (relu) v = fmaxf(v, 0.f);
        size_t idx = (size_t)z * sC + (size_t)row * ldc + col;
        if (obf) ((u16*)Cv)[idx] = f2b(v);
        else     ((float*)Cv)[idx] = v;
      }
    }
}

// ---------------------------------------------------------------------------
// Merged feat-consumer kernel: blocks [0,1152) = qkv GEMM (64x128 tile,
// implicit im2col A, glds-B (slot-swizzled), split-K(3), bf16 partials);
// blocks [1152,1664) = grouped 5x5 off1 conv (64x64 tile).
// ---------------------------------------------------------------------------
__global__ __launch_bounds__(256)
void gemm_feat(const u16* __restrict__ feat, const u16* __restrict__ Btqkv,
               u16* __restrict__ Pq, const u16* __restrict__ Btoff1,
               float* __restrict__ obuf, const float* __restrict__ b_off1)
{
  __shared__ u16 smem[6656];   // 13.3 KB: qkv As(2560)+Bs(4096); off1 uses 5120
  const int bid = blockIdx.x;
  const int tid = threadIdx.x;
  const int wave = tid >> 6, lane = tid & 63;
  const int lr = lane & 15, lk = lane >> 4;

  if (bid < NBLK_QKV) {
    // ----- qkv branch -----
    u16* As = smem;            // 64 * 40
    u16* Bs = smem + 64 * 40;  // 128 * 32, glds target (slot-swizzled)
    const int mz  = bid & 63;
    const int rest = bid >> 6;
    const int ny  = rest % 6;
    const int z   = rest / 6;
    const int m0  = mz * 64;
    const int n0  = ny * 128;
    const int kbeg = z * QCHUNK;
    const int kend = kbeg + QCHUNK;
    const int nw = wave * 32;
    const int arow = tid >> 2, acol = (tid & 3) * 8;
    const int p = m0 + arow, y = p >> 6, x = p & 63;

    frag_cd acc[4][2] = {};
    const int swl = swz_inv(tid);   // bijection on [0,256)
    const u16* bbase = Btqkv + (size_t)(n0 + (swl >> 2)) * KQ + (swl & 3) * 8 + kbeg;
    u16* bdst = &Bs[(size_t)tid * 8];

    auto stageA = [&](int k0) -> uint4 {
      int k = k0 + acol;
      int s = k >> 8, c = k & 255;
      int dy = s / 3, dx = s - dy * 3;
      int yy = y + dy - 1, xx = x + dx - 1;
      if (((unsigned)yy < 64u) && ((unsigned)xx < 64u))
        return *(const uint4*)&feat[(size_t)(yy * 64 + xx) * 256 + c];
      return uint4{0u, 0u, 0u, 0u};
    };

    uint4 av = stageA(kbeg);

    for (int k0 = kbeg; k0 < kend; k0 += BK) {
      glds16(bbase + (k0 - kbeg), bdst);
      glds16(bbase + (k0 - kbeg) + (size_t)64 * KQ, bdst + 2048);
      *(uint4*)&As[arow * LDSS + acol] = av;
      __syncthreads();
      if (k0 + BK < kend) av = stageA(k0 + BK);
      frag_ab af[4];
      #pragma unroll
      for (int i = 0; i < 4; i++)
        af[i] = *(const frag_ab*)&As[(i * 16 + lr) * LDSS + lk * 8];
      #pragma unroll
      for (int j = 0; j < 2; j++) {
        int n  = nw + j * 16 + lr;            // 0..127
        int nl = n & 63;                      // local row within half
        int sl = ((nl << 2) | lk) ^ (nl & 7); // swizzled 16B slot
        frag_ab bf = *(const frag_ab*)&Bs[((n & 64) << 5) + sl * 8];
        #pragma unroll
        for (int i = 0; i < 4; i++)
          acc[i][j] = __builtin_amdgcn_mfma_f32_16x16x32_bf16(af[i], bf, acc[i][j], 0, 0, 0);
      }
      __syncthreads();
    }

    #pragma unroll
    for (int i = 0; i < 4; i++)
      #pragma unroll
      for (int j = 0; j < 2; j++) {
        int col = n0 + nw + j * 16 + lr;
        #pragma unroll
        for (int r = 0; r < 4; r++) {
          int row = m0 + i * 16 + lk * 4 + r;
          Pq[(size_t)z * (NQ * 768) + (size_t)row * 768 + col] = f2b(acc[i][j][r]);
        }
      }
  } else {
    // ----- off1 grouped conv branch (5x5 pad2, 32 ch/group) -----
    u16* As = smem;            // 64 * 40
    u16* Bs = smem + 64 * 40;  // 64 * 40
    const int t  = bid - NBLK_QKV;
    const int m0 = (t & 63) * 64;
    const int g  = t >> 6;               // group 0..7
    const int cb = g * 32;
    const u16* Bt = Btoff1 + (size_t)g * 32 * 800;
    const float* bz = b_off1 + g * 32;
    const int mw = (wave & 1) * 32, nw = (wave >> 1) * 32;
    const int srow = tid >> 2, scol = (tid & 3) * 8;
    const int p = m0 + srow, y = p >> 6, x = p & 63;

    frag_cd acc[2][2] = {};
    const bool bok  = srow < 32;
    const u16* bptr = Bt + (size_t)srow * 800 + scol;

    auto stageA = [&](int k0) -> uint4 {
      int k = k0 + scol;
      int s = k >> 5;
      int c = k & 31;
      int dy = s / 5, dx = s - dy * 5;
      int yy = y + dy - 2, xx = x + dx - 2;
      if (((unsigned)yy < 64u) && ((unsigned)xx < 64u))
        return *(const uint4*)&feat[(size_t)(yy * 64 + xx) * 256 + cb + c];
      return uint4{0u, 0u, 0u, 0u};
    };

    uint4 av = stageA(0);
    uint4 bv = bok ? *(const uint4*)(bptr) : uint4{0u, 0u, 0u, 0u};

    for (int k0 = 0; k0 < 800; k0 += BK) {
      *(uint4*)&As[srow * LDSS + scol] = av;
      *(uint4*)&Bs[srow * LDSS + scol] = bv;
      __syncthreads();
      if (k0 + BK < 800) {
        av = stageA(k0 + BK);
        bv = bok ? *(const uint4*)(bptr + k0 + BK) : uint4{0u, 0u, 0u, 0u};
      }
      frag_ab af0 = *(const frag_ab*)&As[(mw      + lr) * LDSS + lk * 8];
      frag_ab af1 = *(const frag_ab*)&As[(mw + 16 + lr) * LDSS + lk * 8];
      frag_ab bf0 = *(const frag_ab*)&Bs[(nw      + lr) * LDSS + lk * 8];
      frag_ab bf1 = *(const frag_ab*)&Bs[(nw + 16 + lr) * LDSS + lk * 8];
      acc[0][0] = __builtin_amdgcn_mfma_f32_16x16x32_bf16(af0, bf0, acc[0][0], 0, 0, 0);
      acc[0][1] = __builtin_amdgcn_mfma_f32_16x16x32_bf16(af0, bf1, acc[0][1], 0, 0, 0);
      acc[1][0] = __builtin_amdgcn_mfma_f32_16x16x32_bf16(af1, bf0, acc[1][0], 0, 0, 0);
      acc[1][1] = __builtin_amdgcn_mfma_f32_16x16x32_bf16(af1, bf1, acc[1][1], 0, 0, 0);
      __syncthreads();
    }

    #pragma unroll
    for (int i = 0; i < 2; i++)
      #pragma unroll
      for (int j = 0; j < 2; j++) {
        int col = nw + j * 16 + lr;
        if (col >= 32) continue;
        float badd = bz[col];
        #pragma unroll
        for (int r = 0; r < 4; r++) {
          int row = m0 + mw + i * 16 + lk * 4 + r;
          obuf[(size_t)row * 256 + g * 32 + col] = acc[i][j][r] + badd;
        }
      }
  }
}

// sum QSPLIT bf16 qkv partials + bias -> fqkvb (bf16) and fqkvVb (bf16 V).
__global__ __launch_bounds__(256)
void reduce_qkv(const u16* __restrict__ P, const float* __restrict__ bias,
                u16* __restrict__ outb, u16* __restrict__ outV)
{
  int i8 = blockIdx.x * 256 + threadIdx.x;
  if (i8 >= NQ * 96) return;
  size_t i = (size_t)i8 * 8;
  int row = (int)(i / 768);
  int c = (int)(i % 768);
  float v[8];
  #pragma unroll
  for (int t = 0; t < 8; t++) v[t] = bias[c + t];
  for (int z = 0; z < QSPLIT; z++) {
    uint4 a = *(const uint4*)&P[(size_t)z * (NQ * 768) + i];
    u32 aw[4] = {a.x, a.y, a.z, a.w};
    #pragma unroll
    for (int t = 0; t < 4; t++) {
      v[2 * t]     += __uint_as_float(aw[t] << 16);
      v[2 * t + 1] += __uint_as_float(aw[t] & 0xffff0000u);
    }
  }
  uint4 ob = {pk2(v[0], v[1]), pk2(v[2], v[3]), pk2(v[4], v[5]), pk2(v[6], v[7])};
  *(uint4*)&outb[i] = ob;
  if (c >= 512) {
    // bf16 V gather table: identical values to fqkvb's V section, but a
    // dense 2 MB (pos,256) layout -> one uint4 per gather in gemm_big.
    *(uint4*)&outV[(size_t)row * 256 + (c - 512)] = ob;
  }
}

// ---------------------------------------------------------------------------
// Big MLP GEMM: fused gather-A (bf16 V, weight-mul + repack), 128x256 tile,
// BOTH tiles double-buffered, ONE barrier per K-iter, counted vmcnt, glds-B
// (slot-swizzled), split-K(16), bf16 partials. block 512 (8 waves),
// grid (32,16) = 2/CU (reg-capped: ~60 VGPR + 64 AGPR; (512,4) — do NOT
// raise min-waves, r15 spilled). BYTE-IDENTICAL to round 18.
// ---------------------------------------------------------------------------
__global__ __launch_bounds__(512, 4)
void gemm_big(const u16* __restrict__ Bt, const u16* __restrict__ fqkvV,
              const float* __restrict__ attnval, const int* __restrict__ vidx,
              u16* __restrict__ P)
{
  __shared__ u16 As[2 * 128 * LDSS];        // 20 KB double-buffered gather tile
  __shared__ u16 Bs[2 * 256 * 32];          // 32 KB double-buffered glds target
  __shared__ short s_vidx[JMAX * 128];      // 1.25 KB (ids < 4096 fit short)
  const int tid  = threadIdx.x;
  const int m0   = blockIdx.x * 128;
  const int z    = blockIdx.y;
  const int kbeg = z * KCHUNK;
  const int kend = min(KBIG, kbeg + KCHUNK);
  const int jbeg = kbeg >> 8;
  const int jcnt = ((kend - 1) >> 8) - jbeg + 1;   // <= 5
  const int wave = tid >> 6, lane = tid & 63;
  const int mw = (wave & 1) * 64, nwv = (wave >> 1) * 64;
  const int lr = lane & 15, lk = lane >> 4;
  const int arow = tid >> 2, acol = (tid & 3) * 8;  // 128 rows x 4x8
  const int q = m0 + arow;

  for (int t = tid; t < 128 * jcnt; t += 512) {
    int r = t & 127, jj = t >> 7;
    int j = jbeg + jj;
    s_vidx[t] = (short)((j < 49) ? vidx[(m0 + r) * 49 + j] : -1);
  }
  __syncthreads();   // s_vidx visible before pipeline starts

  // Unconditional gather: always issues exactly 2 VMEM loads (w then kv),
  // so per-wave vmcnt bookkeeping is exact. id<0 / j>=49 zeroed via select.
  auto loadA = [&](int k0, uint4& kv, float& w) {
    const int k = k0 + acol;
    const int j = k >> 8, c = k & 255;
    const int jj = j - jbeg;
    const int id = (int)s_vidx[jj * 128 + arow];
    const int jmin = min(j, 48);
    const int idc = (id >= 0) ? id : 0;
    float wraw = attnval[((size_t)(q * 49 + jmin)) * 8 + (c >> 5)];
    kv = *(const uint4*)(fqkvV + (size_t)idc * 256 + c);
    w = (id >= 0 && j < 49) ? wraw : 0.f;
  };

  auto stage = [&](u16* dst, const uint4& kvv, float w) {
    u32 aw[4] = {kvv.x, kvv.y, kvv.z, kvv.w};
    uint4 av;
    u32 avw[4];
    #pragma unroll
    for (int t = 0; t < 4; t++) {
      float lo = __uint_as_float(aw[t] << 16) * w;
      float hi = __uint_as_float(aw[t] & 0xffff0000u) * w;
      avw[t] = pk2(lo, hi);
    }
    av.x = avw[0]; av.y = avw[1]; av.z = avw[2]; av.w = avw[3];
    *(uint4*)&dst[arow * LDSS + acol] = av;
  };

  frag_cd acc[4][4] = {};
  uint4 kvc; float wc_;
  const int swl = swz_inv(tid);   // bijection on [0,512)
  const u16* bbase = Bt + (size_t)(swl >> 2) * KBIG + (swl & 3) * 8 + kbeg;
  const int nt = (kend - kbeg + BK - 1) / BK;

  // ---- prologue: A(0) gather -> stage As[0]; glds B(0) -> Bs[0];
  //      A(1) gather in flight; one convergence. ----
  loadA(kbeg, kvc, wc_);                       // A(0): 2 loads (oldest)
  glds16(bbase, &Bs[(size_t)tid * 8]);         // B(0): 2 glds (newer)
  glds16(bbase + (size_t)128 * KBIG, &Bs[(size_t)tid * 8 + 4096]);
  stage(As, kvc, wc_);                         // compiler waits A(0) loads
  loadA(kbeg + BK, kvc, wc_);                  // A(1) in flight
  asm volatile("s_waitcnt vmcnt(2) lgkmcnt(0)" ::: "memory");  // B(0) landed
  __builtin_amdgcn_s_barrier();

  int par = 0;
  for (int t = 0; t < nt; ++t, par ^= 1) {
    const int k0 = kbeg + t * BK;
    const u16* Asr = As + par * (128 * LDSS);
    if (t + 1 < nt) {
      // B(t+1) glds into the other buffer (2 oldest of this body's issues)
      u16* bd = &Bs[(size_t)(par ^ 1) * 8192 + (size_t)tid * 8];
      glds16(bbase + (k0 + BK - kbeg), bd);
      glds16(bbase + (k0 + BK - kbeg) + (size_t)128 * KBIG, bd + 4096);
      // stage A(t+1) (compiler-counted wait leaves the glds in flight)
      stage(As + (par ^ 1) * (128 * LDSS), kvc, wc_);
      // A(t+2) gather (clamped at the tail; surplus data never staged)
      loadA(min(k0 + 2 * BK, kend - BK), kvc, wc_);
    }
    // MFMA on buffers [par]
    const u16* bsrc = &Bs[(size_t)par * 8192 + ((nwv & 128) << 5)];
    const int nb = nwv & 127;
    frag_ab af[4];
    #pragma unroll
    for (int i = 0; i < 4; i++)
      af[i] = *(const frag_ab*)&Asr[(mw + i * 16 + lr) * LDSS + lk * 8];
    #pragma unroll
    for (int j = 0; j < 4; j++) {
      int nl = nb + j * 16 + lr;            // local row 0..127
      int sl = ((nl << 2) | lk) ^ (nl & 7); // swizzled 16B slot
      frag_ab bf = *(const frag_ab*)&bsrc[sl * 8];
      #pragma unroll
      for (int i = 0; i < 4; i++)
        acc[i][j] = __builtin_amdgcn_mfma_f32_16x16x32_bf16(af[i], bf, acc[i][j], 0, 0, 0);
    }
    // Single convergence: ds_reads retired + this body's glds landed
    // (outstanding afterwards: exactly the 2 A-gather loads).
    asm volatile("s_waitcnt vmcnt(2) lgkmcnt(0)" ::: "memory");
    __builtin_amdgcn_s_barrier();
  }

  #pragma unroll
  for (int i = 0; i < 4; i++)
    #pragma unroll
    for (int j = 0; j < 4; j++) {
      int col = nwv + j * 16 + lr;
      #pragma unroll
      for (int r = 0; r < 4; r++) {
        int row = m0 + mw + i * 16 + lk * 4 + r;
        P[(size_t)z * (NQ * 256) + (size_t)row * 256 + col] = f2b(acc[i][j][r]);
      }
    }
}

// ---------------------------------------------------------------------------
// Fused: hid2 = relu(sum_z Pb + bi1 + cell-tail); out = bi2 + skip + hid2.Wi2^T
// (cell tail = K cols 12544/5 of Wi1, moved out of gemm_big).
// ---------------------------------------------------------------------------
__global__ __launch_bounds__(256)
void reduce_final(const u16* __restrict__ Pb, const float* __restrict__ bi1,
                  const float* __restrict__ Wi2, const float* __restrict__ bi2,
                  const float* __restrict__ skipb, const float* __restrict__ cell,
                  const u16* __restrict__ Wi1p, float* __restrict__ out)
{
  const int q = blockIdx.x, c = threadIdx.x;
  float s = 0.f;
  #pragma unroll
  for (int z = 0; z < SPLITK; z++)
    s += b2f(Pb[(size_t)z * (NQ * 256) + (size_t)q * 256 + c]);
  s += bi1[c];
  // cell tail: rel_cell = cell * [H, W] = cell * 64
  {
    float cx = cell[q * 2] * 64.f, cy = cell[q * 2 + 1] * 64.f;
    const u16* wrow = Wi1p + (size_t)c * KBIG + 12544;
    s += b2f(wrow[0]) * cx + b2f(wrow[1]) * cy;
  }
  s = fmaxf(s, 0.f);

  __shared__ float part[3][4];
  float p0 = s * Wi2[c], p1 = s * Wi2[256 + c], p2 = s * Wi2[512 + c];
  #pragma unroll
  for (int off = 32; off; off >>= 1) {
    p0 += __shfl_xor(p0, off);
    p1 += __shfl_xor(p1, off);
    p2 += __shfl_xor(p2, off);
  }
  if ((c & 63) == 0) {
    int w = c >> 6;
    part[0][w] = p0; part[1][w] = p1; part[2][w] = p2;
  }
  __syncthreads();
  if (c < 3)
    out[q * 3 + c] = bi2[c] + skipb[q * 3 + c]
                   + part[c][0] + part[c][1] + part[c][2] + part[c][3];
}

// ---------------------------------------------------------------------------
// Weight packing — single launch for everything.
// ---------------------------------------------------------------------------
static __device__ __forceinline__
void packconv(const float* __restrict__ W, u16* __restrict__ Bt,
              int Cin, int K2, int idx)
{
  int o  = idx / (Cin * K2);
  int r  = idx - o * (Cin * K2);
  int ci = r / K2;
  int s  = r - ci * K2;
  Bt[(size_t)o * (Cin * K2) + s * Cin + ci] = f2b(W[idx]);
}
static __device__ __forceinline__
void packcast(const float* __restrict__ W, u16* __restrict__ Bt,
              int Kin, int Kout, int idx)
{
  int n = idx / Kout, k = idx - n * Kout;
  Bt[idx] = f2b(k < Kin ? W[(size_t)n * Kin + k] : 0.f);
}

#define SZ_CH   147456   // 256*64*9
#define SZ_QKV  589824   // 256*256*9
#define SZ_OFF1 204800   // 256*32*25
#define SZ_OFF2 25088    // 98*256
#define SZ_C1   32768    // 256*128
#define SZ_C2   12544    // 49*256
#define SZ_WI1  3219456  // 256*12576
#define SZ_PACK (SZ_CH + 3*SZ_QKV + SZ_OFF1 + SZ_OFF2 + SZ_C1 + SZ_C2 + 768 + SZ_WI1)

__global__ void pack_all(const float* W_ch, const float* W_q, const float* W_k,
                         const float* W_v, const float* W_off1, const float* W_off2,
                         const float* Wc1, const float* Wc2, const float* Wi1,
                         const float* b_q, const float* b_k, const float* b_v,
                         u16* Btch, u16* Btqkv, u16* Btoff1, u16* Btoff2,
                         u16* Btc1, u16* Btc2, u16* Wi1p, float* bqkv)
{
  int i = blockIdx.x * 256 + threadIdx.x;
  if (i < SZ_CH) { packconv(W_ch, Btch, 64, 9, i); return; }
  i -= SZ_CH;
  if (i < SZ_QKV) { packconv(W_q, Btqkv, 256, 9, i); return; }
  i -= SZ_QKV;
  if (i < SZ_QKV) { packconv(W_k, Btqkv + (size_t)256 * 2304, 256, 9, i); return; }
  i -= SZ_QKV;
  if (i < SZ_QKV) { packconv(W_v, Btqkv + (size_t)512 * 2304, 256, 9, i); return; }
  i -= SZ_QKV;
  if (i < SZ_OFF1) { packconv(W_off1, Btoff1, 32, 25, i); return; }
  i -= SZ_OFF1;
  if (i < SZ_OFF2) { packcast(W_off2, Btoff2, 256, 256, i); return; }
  i -= SZ_OFF2;
  if (i < SZ_C1) {
    // Wc1 (256 x 98) -> K-major Btc1t[k][c], k in [0,128) zero-padded:
    // coalesced per-k row reads in the fused sampler MLP.
    int c = i >> 7, k = i & 127;
    Btc1[(size_t)k * 256 + c] = f2b(k < 98 ? Wc1[c * 98 + k] : 0.f);
    return;
  }
  i -= SZ_C1;
  if (i < SZ_C2) { packcast(Wc2, Btc2, 256, 256, i); return; }
  i -= SZ_C2;
  if (i < 768) {
    bqkv[i] = (i < 256) ? b_q[i] : (i < 512) ? b_k[i - 256] : b_v[i - 512];
    return;
  }
  i -= 768;
  if (i < SZ_WI1) { packcast(Wi1, Wi1p, 12546, 12576, i); }
}

// ---------------------------------------------------------------------------
// Encoder conv: 3->64, 3x3 pad1, +bias, relu -> feat1 (HW,64) bf16
// ---------------------------------------------------------------------------
__global__ __launch_bounds__(64)
void conv_enc(const float* __restrict__ inp, const float* __restrict__ W,
              const float* __restrict__ b, u16* __restrict__ feat1)
{
  const int p = blockIdx.x, c = threadIdx.x;
  const int y = p >> 6, x = p & 63;
  float s = b[c];
  #pragma unroll
  for (int ci = 0; ci < 3; ci++)
    #pragma unroll
    for (int dy = 0; dy < 3; dy++) {
      int yy = y + dy - 1;
      if ((unsigned)yy >= 64u) continue;
      #pragma unroll
      for (int dx = 0; dx < 3; dx++) {
        int xx = x + dx - 1;
        if ((unsigned)xx >= 64u) continue;
        s += inp[ci * HW + yy * 64 + xx] * W[((c * 3 + ci) * 3 + dy) * 3 + dx];
      }
    }
  feat1[(size_t)p * 64 + c] = f2b(fmaxf(s, 0.f));
}

// ---------------------------------------------------------------------------
// LayerNorm(channel) + exact GELU
// ---------------------------------------------------------------------------
__global__ __launch_bounds__(256)
void ln_gelu(const float* __restrict__ x, const float* __restrict__ g,
             const float* __restrict__ b, u16* __restrict__ y)
{
  const int p = blockIdx.x, c = threadIdx.x;
  __shared__ float r1[4], r2[4];
  float v = x[(size_t)p * 256 + c];
  float s1 = v, s2 = v * v;
  #pragma unroll
  for (int off = 32; off; off >>= 1) {
    s1 += __shfl_xor(s1, off);
    s2 += __shfl_xor(s2, off);
  }
  if ((c & 63) == 0) { r1[c >> 6] = s1; r2[c >> 6] = s2; }
  __syncthreads();
  float t1 = r1[0] + r1[1] + r1[2] + r1[3];
  float t2 = r2[0] + r2[1] + r2[2] + r2[3];
  float mu  = t1 * (1.f / 256.f);
  float var = t2 * (1.f / 256.f) - mu * mu;
  float xn = (v - mu) * rsqrtf(var + 1e-5f) * g[c] + b[c];
  float ge = 0.5f * xn * (1.f + erff(xn * 0.70710678118654752f));
  y[(size_t)p * 256 + c] = f2b(ge);
}

// ---------------------------------------------------------------------------
// Per-query sampler — FUSED attention-weight path:
// phase 1: offsets/tap coords/q-sample/skip (as before, rel kept in LDS f32)
// phase 2: q.k dots -> s_att (LDS) ; c1 MLP (98->256, coalesced K-major Wc1)
// phase 3: c2 (256->49, 4 lanes per output from LDS)
// phase 4: per-head softmax (same math as old softmax_k) -> attnval (final)
// ---------------------------------------------------------------------------
__global__ __launch_bounds__(256)
void sampler(const float* __restrict__ coord, const u16* __restrict__ fqkvb,
             const float* __restrict__ offs, const float* __restrict__ inp,
             float* __restrict__ attnval, int* __restrict__ vidx,
             float* __restrict__ skipb, const u16* __restrict__ Btc1,
             const u16* __restrict__ Btc2, const float* __restrict__ bc1,
             const float* __restrict__ bc2)
{
  const int q = blockIdx.x;
  const int tid = threadIdx.x;
  __shared__ float s_off[98];
  __shared__ int   s_idx[49];
  __shared__ float s_q[256];
  __shared__ float s_rel[98];
  __shared__ float s_att[49 * 8];
  __shared__ float s_hid[256];
  __shared__ float s_wc[49];

  const float c0 = coord[q * 2], c1 = coord[q * 2 + 1];
  const float gxp = ((c1 + 1.f) * 64.f - 1.f) * 0.5f;
  const float gyp = ((c0 + 1.f) * 64.f - 1.f) * 0.5f;
  const int ixn = (int)rintf(gxp), iyn = (int)rintf(gyp);
  const bool inn = ((unsigned)ixn < 64u) && ((unsigned)iyn < 64u);

  if (tid < 98) {
    float v = inn ? offs[(size_t)(iyn * 64 + ixn) * 98 + tid] : 0.f;
    s_off[tid] = tanhf(v) * (2.f / 63.f);
  }
  __syncthreads();

  const float scky = inn ? (-1.f + (float)(2 * iyn + 1) * (1.f / 64.f)) : 0.f;
  const float sckx = inn ? (-1.f + (float)(2 * ixn + 1) * (1.f / 64.f)) : 0.f;

  if (tid < 49) {
    const int a = tid / 7, bb = tid - a * 7;
    float sy = scky + (float)(a - 3) * (2.f / 64.f) + s_off[2 * tid];
    float sx = sckx + (float)(bb - 3) * (2.f / 64.f) + s_off[2 * tid + 1];
    s_rel[2 * tid]     = (c0 - sy) * 64.f;
    s_rel[2 * tid + 1] = (c1 - sx) * 64.f;
    float gx2 = ((sx + 1.f) * 64.f - 1.f) * 0.5f;
    float gy2 = ((sy + 1.f) * 64.f - 1.f) * 0.5f;
    int ix2 = (int)rintf(gx2), iy2 = (int)rintf(gy2);
    int id = (((unsigned)ix2 < 64u) && ((unsigned)iy2 < 64u)) ? (iy2 * 64 + ix2) : -1;
    s_idx[tid] = id;
    vidx[q * 49 + tid] = id;
  }

  {
    const float x0f = floorf(gxp), y0f = floorf(gyp);
    const float wx = gxp - x0f, wy = gyp - y0f;
    const int x0 = (int)x0f, y0 = (int)y0f;
    float qc = 0.f;
    #pragma unroll
    for (int t = 0; t < 4; t++) {
      int xi = x0 + (t & 1), yi = y0 + (t >> 1);
      if (((unsigned)xi < 64u) && ((unsigned)yi < 64u)) {
        float w = ((t & 1) ? wx : 1.f - wx) * ((t >> 1) ? wy : 1.f - wy);
        qc += w * b2f(fqkvb[(size_t)(yi * 64 + xi) * 768 + tid]);
      }
    }
    s_q[tid] = qc * 0.17677669529663687f;
  }

  if (tid < 3) {
    float gx = fminf(fmaxf(gxp, 0.f), 63.f);
    float gy = fminf(fmaxf(gyp, 0.f), 63.f);
    float xf = floorf(gx), yf = floorf(gy);
    float wxs = gx - xf, wys = gy - yf;
    int xa = (int)xf, ya = (int)yf;
    int xb = min(xa + 1, 63), yb = min(ya + 1, 63);
    const float* ch = inp + tid * HW;
    float v = (1.f - wxs) * (1.f - wys) * ch[ya * 64 + xa]
            + wxs * (1.f - wys) * ch[ya * 64 + xb]
            + (1.f - wxs) * wys * ch[yb * 64 + xa]
            + wxs * wys * ch[yb * 64 + xb];
    skipb[q * 3 + tid] = v;
  }
  __syncthreads();

  // ---- c1 MLP: hid[c] = relu(bc1[c] + sum_k Wc1[c,k]*rel[k]) ----
  // Btc1 is K-major [128][256]: per-k row reads are fully coalesced; rel[k]
  // is an LDS broadcast.
  {
    float h1 = bc1[tid];
    #pragma unroll 2
    for (int k = 0; k < 98; k++)
      h1 += b2f(Btc1[(size_t)k * 256 + tid]) * s_rel[k];
    s_hid[tid] = fmaxf(h1, 0.f);
  }

  // ---- q.k dots -> s_att ----
  const int wave = tid >> 6, lane = tid & 63;
  const int half = lane >> 5, sub = lane & 31;
  const int ch0 = sub * 8;
  const int h = sub >> 2;
  float qv[8];
  #pragma unroll
  for (int i = 0; i < 8; i++) qv[i] = s_q[ch0 + i];

  for (int it = 0; it < 7; it++) {
    int j = it * 8 + wave * 2 + half;
    if (j >= 49) break;
    int id = s_idx[j];
    float p = 0.f;
    if (id >= 0) {
      uint4 kv = *(const uint4*)&fqkvb[(size_t)id * 768 + 256 + ch0];
      u32 w0 = kv.x, w1 = kv.y, w2 = kv.z, w3 = kv.w;
      p = fmaf(qv[0], __uint_as_float(w0 << 16), p);
      p = fmaf(qv[1], __uint_as_float(w0 & 0xffff0000u), p);
      p = fmaf(qv[2], __uint_as_float(w1 << 16), p);
      p = fmaf(qv[3], __uint_as_float(w1 & 0xffff0000u), p);
      p = fmaf(qv[4], __uint_as_float(w2 << 16), p);
      p = fmaf(qv[5], __uint_as_float(w2 & 0xffff0000u), p);
      p = fmaf(qv[6], __uint_as_float(w3 << 16), p);
      p = fmaf(qv[7], __uint_as_float(w3 & 0xffff0000u), p);
    }
    p += __shfl_down(p, 2, 4);
    p += __shfl_down(p, 1, 4);
    if ((sub & 3) == 0) s_att[j * 8 + h] = p;
  }
  __syncthreads();   // s_hid + s_att ready

  // ---- c2: wc[j] = bc2[j] + sum_c Wc2[j,c]*hid[c], 4 lanes per j ----
  if (tid < 196) {
    const int j = tid >> 2, p4 = tid & 3;
    float s2 = 0.f;
    const u16* w2 = Btc2 + (size_t)j * 256 + p4 * 64;
    const float* hsrc = s_hid + p4 * 64;
    #pragma unroll 4
    for (int i = 0; i < 64; i++)
      s2 += b2f(w2[i]) * hsrc[i];
    s2 += __shfl_down(s2, 2, 4);
    s2 += __shfl_down(s2, 1, 4);
    if (p4 == 0) s_wc[j] = s2 + bc2[j];
  }
  __syncthreads();   // s_wc ready

  // ---- softmax over j per head (identical math to old softmax_k) ----
  const int l = lane;
  #pragma unroll
  for (int pass = 0; pass < 2; pass++) {
    const int hh = wave + pass * 4;
    float v = (l < 49) ? s_wc[l] + s_att[l * 8 + hh] : -1e30f;
    float m = v;
    #pragma unroll
    for (int off = 32; off; off >>= 1) m = fmaxf(m, __shfl_xor(m, off));
    float e = (l < 49) ? expf(v - m) : 0.f;
    float ssum = e;
    #pragma unroll
    for (int off = 32; off; off >>= 1) ssum += __shfl_xor(ssum, off);
    if (l < 49) attnval[((size_t)q * 49 + l) * 8 + hh] = e / ssum;
  }
}

// ===========================================================================
extern "C" void kernel_launch(void* const* d_in, const int* in_sizes, int n_in,
                              void* d_out, int out_size, void* d_ws, size_t ws_size,
                              hipStream_t stream)
{
  const float* inp    = (const float*)d_in[0];
  const float* coord  = (const float*)d_in[1];
  const float* cell   = (const float*)d_in[2];
  const float* W_enc  = (const float*)d_in[3];
  const float* b_enc  = (const float*)d_in[4];
  const float* W_ch   = (const float*)d_in[5];
  const float* b_ch   = (const float*)d_in[6];
  const float* W_q    = (const float*)d_in[7];
  const float* b_q    = (const float*)d_in[8];
  const float* W_k    = (const float*)d_in[9];
  const float* b_k    = (const float*)d_in[10];
  const float* W_v    = (const float*)d_in[11];
  const float* b_v    = (const float*)d_in[12];
  const float* W_off1 = (const float*)d_in[13];
  const float* b_off1 = (const float*)d_in[14];
  const float* ln_g   = (const float*)d_in[15];
  const float* ln_b   = (const float*)d_in[16];
  const float* W_off2 = (const float*)d_in[17];
  const float* Wc1    = (const float*)d_in[18];
  const float* bc1    = (const float*)d_in[19];
  const float* Wc2    = (const float*)d_in[20];
  const float* bc2    = (const float*)d_in[21];
  const float* Wi1    = (const float*)d_in[22];
  const float* bi1    = (const float*)d_in[23];
  const float* Wi2    = (const float*)d_in[24];
  const float* bi2    = (const float*)d_in[25];

  char* base = (char*)d_ws;
  size_t off = 0;
  auto alloc = [&](size_t bytes) -> char* {
    char* r = base + off;
    off = (off + bytes + 255) & ~(size_t)255;
    return r;
  };

  // --- scratch region (dead before gemm_big runs; Pb aliases it) ---
  float* obuf   = (float*)alloc((size_t)HW * 256 * 4);
  u16*   ocg    = (u16*)  alloc((size_t)HW * 256 * 2);
  float* offsb  = (float*)alloc((size_t)HW * 98 * 4);
  u16*   feat1  = (u16*)  alloc((size_t)HW * 64 * 2);
  u16*   feat   = (u16*)  alloc((size_t)HW * 256 * 2);
  u16*   Btqkv  = (u16*)  alloc((size_t)768 * 2304 * 2);
  u16*   Btch   = (u16*)  alloc((size_t)256 * 576 * 2);
  u16*   Btoff1 = (u16*)  alloc((size_t)256 * 800 * 2);
  u16*   Btoff2 = (u16*)  alloc((size_t)98 * 256 * 2);
  u16*   Btc1   = (u16*)  alloc((size_t)128 * 256 * 2);
  u16*   Btc2   = (u16*)  alloc((size_t)49 * 256 * 2);
  // gemm_big bf16 partials alias scratch: 16 x 2MB = 33.6MB at base+0.
  u16* Pb = (u16*)base;
  // qkv bf16 partials at [36MB, 54.9MB): past live scratch (~14MB),
  // disjoint from Pb's 33.6MB, dead before gemm_big.
  u16* Pqb = (u16*)(base + ((size_t)36 << 20));
  {
    size_t need = ((size_t)36 << 20) + (size_t)QSPLIT * NQ * 768 * 2;
    if (off < need) off = (need + 255) & ~(size_t)255;
  }
  // --- persistent buffers ---
  u16*   fqkvb   = (u16*)  alloc((size_t)HW * 768 * 2);
  u16*   fqkvVb  = (u16*)  alloc((size_t)HW * 256 * 2);
  float* attnval = (float*)alloc((size_t)NQ * 49 * 8 * 4);
  int*   vidxb   = (int*)  alloc((size_t)NQ * 49 * 4);
  float* skipb   = (float*)alloc((size_t)NQ * 3 * 4);
  u16*   Wi1p    = (u16*)  alloc((size_t)256 * KBIG * 2);
  float* bqkv    = (float*)alloc(768 * 4);
  (void)ws_size; (void)in_sizes; (void)n_in; (void)out_size;

  // --- weight packing (single launch) ---
  pack_all<<<(SZ_PACK + 255) / 256, 256, 0, stream>>>(
      W_ch, W_q, W_k, W_v, W_off1, W_off2, Wc1, Wc2, Wi1, b_q, b_k, b_v,
      Btch, Btqkv, Btoff1, Btoff2, Btc1, Btc2, Wi1p, bqkv);

  // --- conv stack ---
  conv_enc<<<HW, 64, 0, stream>>>(inp, W_enc, b_enc, feat1);
  gemm_conv<3, 6, 1><<<dim3(64, 4, 1), 256, 0, stream>>>(
      feat1, Btch, feat, b_ch, 256, 576, 256, /*bf16*/2, 64, 0, 0, 0, 0);
  // merged qkv + off1 (overlap)
  gemm_feat<<<NBLK_QKV + NBLK_OFF1, 256, 0, stream>>>(
      feat, Btqkv, Pqb, Btoff1, obuf, b_off1);
  reduce_qkv<<<(NQ * 96 + 255) / 256, 256, 0, stream>>>(Pqb, bqkv, fqkvb, fqkvVb);
  ln_gelu<<<HW, 256, 0, stream>>>(obuf, ln_g, ln_b, ocg);
  gemm_bt<<<dim3(64, 2, 1), 256, 0, stream>>>(ocg, Btoff2, offsb, nullptr,
      98, 256, 98, 0, 0, 0, 0, 0);

  // --- per-query attention path (FUSED: q.k + wcoord MLP + softmax) ---
  sampler<<<NQ, 256, 0, stream>>>(coord, fqkvb, offsb, inp, attnval,
                                  vidxb, skipb, Btc1, Btc2, bc1, bc2);

  // --- big MLP: 128x256 tile, dbuf As+Bs, ONE barrier/iter, counted vmcnt,
  //     split-K(16), bf16 partials ---
  gemm_big<<<dim3(32, SPLITK), 512, 0, stream>>>(
      Wi1p, fqkvVb, attnval, vidxb, Pb);
  reduce_final<<<NQ, 256, 0, stream>>>(Pb, bi1, Wi2, bi2, skipb, cell, Wi1p,
                                       (float*)d_out);
}

// Round 6
// 297.261 us; speedup vs baseline: 1.0323x; 1.0323x over previous
//
#include <hip/hip_runtime.h>
#include <hip/hip_bf16.h>

// ============================================================================
// IDASR pipeline on gfx950 — round 20.
// Post-mortem r19: fused sampler regressed (62.4us, #1 kernel) — the c1 MLP
// used 98 SCALAR u16 global loads/thread (Common-mistake #2), c2 another 64.
// 25K VMEM insts/block for 400 MFLOP of work -> issue/latency bound
// (VALU 34%, HBM 4%, VGPR 16).
// Change (sampler + pack only, single variable = vectorize the fused MLP):
//  * Wc1 repacked ROW-major, K padded 98->104 (13x16B rows): 13 uint4
//    loads/thread, HOISTED to kernel entry (latency hides under phase 1).
//  * c2 slice reads vectorized: 8 uint4 per lane (rows 512B-aligned).
//  * s_rel zero-padded to 104.
// gemm_big/conv stack byte-identical to r18/r19.
// ============================================================================

typedef unsigned short u16;
typedef unsigned int u32;
using frag_ab = __attribute__((ext_vector_type(8))) short;  // 8 x bf16
using frag_cd = __attribute__((ext_vector_type(4))) float;  // 4 x f32 acc

#define HW 4096
#define NQ 4096
#define KBIG 12576
#define SPLITK 16
#define KCHUNK 800
#define JMAX 5
#define KQ 2304
#define QSPLIT 3
#define QCHUNK 768
#define NBLK_QKV (64 * 6 * QSPLIT)   // 1152
#define NBLK_OFF1 (64 * 8)           // 512

static __device__ __forceinline__ u16 f2b(float f) {
  union { __hip_bfloat16 h; u16 u; } c; c.h = __float2bfloat16(f); return c.u;
}
static __device__ __forceinline__ float b2f(u16 v) {
  return __uint_as_float((u32)v << 16);
}
static __device__ __forceinline__ u32 pk2(float a, float b) {
  union { __hip_bfloat162 h; u32 u; } c;
  c.h = __float22bfloat162_rn(float2{a, b});
  return c.u;
}
// async global->LDS, 16B per lane. LDS dest is wave-uniform base + lane*16.
static __device__ __forceinline__ void glds16(const u16* g, u16* l) {
  __builtin_amdgcn_global_load_lds(
      (const __attribute__((address_space(1))) u32*)(g),
      (__attribute__((address_space(3))) u32*)(l), 16, 0, 0);
}
// sigma^{-1} for the 16B-slot swizzle sigma(l) = l ^ ((l>>2)&7).
static __device__ __forceinline__ int swz_inv(int t) {
  return t ^ ((t >> 2) & 7) ^ ((t >> 4) & 1);
}

#define BM 64
#define BN 64
#define BK 32
#define LDSS 40   // padded lds row stride for reg-staged tiles

// ---------------------------------------------------------------------------
// Generic bf16 GEMM (64x64 tile): off2 layer only now.
// ---------------------------------------------------------------------------
__global__ __launch_bounds__(256)
void gemm_bt(const u16* __restrict__ A, const u16* __restrict__ Bt,
             void* __restrict__ Cv, const float* __restrict__ bias,
             int N, int K, int ldc, int flags,   // 1=relu, 2=bf16 out
             long sA, long sB, long sC, int sBias)
{
  __shared__ u16 As[BM * LDSS];
  __shared__ u16 Bs[BN * LDSS];
  const int z = blockIdx.z;
  A  += (long)z * sA;
  Bt += (long)z * sB;
  const float* bz = bias ? bias + (long)z * sBias : nullptr;

  const int tid  = threadIdx.x;
  const int m0   = blockIdx.x * BM;
  const int n0   = blockIdx.y * BN;
  const int wave = tid >> 6, lane = tid & 63;
  const int mw = (wave & 1) * 32, nw = (wave >> 1) * 32;
  const int lr = lane & 15, lk = lane >> 4;
  const int srow = tid >> 2, scol = (tid & 3) * 8;

  frag_cd acc[2][2] = {};
  const u16* aptr = A + (size_t)(m0 + srow) * K + scol;
  const bool bok  = (n0 + srow) < N;
  const u16* bptr = Bt + (size_t)(n0 + srow) * K + scol;

  uint4 av = *(const uint4*)(aptr);
  uint4 bv = bok ? *(const uint4*)(bptr) : uint4{0u, 0u, 0u, 0u};

  for (int k0 = 0; k0 < K; k0 += BK) {
    *(uint4*)&As[srow * LDSS + scol] = av;
    *(uint4*)&Bs[srow * LDSS + scol] = bv;
    __syncthreads();
    if (k0 + BK < K) {
      av = *(const uint4*)(aptr + k0 + BK);
      bv = bok ? *(const uint4*)(bptr + k0 + BK) : uint4{0u, 0u, 0u, 0u};
    }
    frag_ab af0 = *(const frag_ab*)&As[(mw      + lr) * LDSS + lk * 8];
    frag_ab af1 = *(const frag_ab*)&As[(mw + 16 + lr) * LDSS + lk * 8];
    frag_ab bf0 = *(const frag_ab*)&Bs[(nw      + lr) * LDSS + lk * 8];
    frag_ab bf1 = *(const frag_ab*)&Bs[(nw + 16 + lr) * LDSS + lk * 8];
    acc[0][0] = __builtin_amdgcn_mfma_f32_16x16x32_bf16(af0, bf0, acc[0][0], 0, 0, 0);
    acc[0][1] = __builtin_amdgcn_mfma_f32_16x16x32_bf16(af0, bf1, acc[0][1], 0, 0, 0);
    acc[1][0] = __builtin_amdgcn_mfma_f32_16x16x32_bf16(af1, bf0, acc[1][0], 0, 0, 0);
    acc[1][1] = __builtin_amdgcn_mfma_f32_16x16x32_bf16(af1, bf1, acc[1][1], 0, 0, 0);
    __syncthreads();
  }

  const bool relu = flags & 1;
  const bool obf  = flags & 2;
  #pragma unroll
  for (int i = 0; i < 2; i++)
    #pragma unroll
    for (int j = 0; j < 2; j++) {
      int col = n0 + nw + j * 16 + lr;
      if (col >= N) continue;
      float badd = bz ? bz[col] : 0.f;
      #pragma unroll
      for (int r = 0; r < 4; r++) {
        int row = m0 + mw + i * 16 + lk * 4 + r;
        float v = acc[i][j][r] + badd;
        if (relu) v = fmaxf(v, 0.f);
        size_t idx = (size_t)z * sC + (size_t)row * ldc + col;
        if (obf) ((u16*)Cv)[idx] = f2b(v);
        else     ((float*)Cv)[idx] = v;
      }
    }
}

// ---------------------------------------------------------------------------
// Implicit-im2col conv GEMM, 64x64 tile (ch conv only now).
// ---------------------------------------------------------------------------
template<int W3, int SH, int PAD>
__global__ __launch_bounds__(256)
void gemm_conv(const u16* __restrict__ feat, const u16* __restrict__ Bt,
               void* __restrict__ Cv, const float* __restrict__ bias,
               int N, int K, int ldc, int flags, int FC, int cbStride,
               long sB, long sC, int sBias)
{
  __shared__ u16 As[BM * LDSS];
  __shared__ u16 Bs[BN * LDSS];
  const int z = blockIdx.z;
  Bt += (long)z * sB;
  const float* bz = bias ? bias + (long)z * sBias : nullptr;
  const int cb = z * cbStride;

  const int tid  = threadIdx.x;
  const int m0   = blockIdx.x * BM;
  const int n0   = blockIdx.y * BN;
  const int wave = tid >> 6, lane = tid & 63;
  const int mw = (wave & 1) * 32, nw = (wave >> 1) * 32;
  const int lr = lane & 15, lk = lane >> 4;
  const int srow = tid >> 2, scol = (tid & 3) * 8;
  const int p = m0 + srow, y = p >> 6, x = p & 63;

  frag_cd acc[2][2] = {};
  const bool bok  = (n0 + srow) < N;
  const u16* bptr = Bt + (size_t)(n0 + srow) * K + scol;

  auto stageA = [&](int k0) -> uint4 {
    int k = k0 + scol;
    int s = k >> SH;
    int c = k & ((1 << SH) - 1);
    int dy = s / W3, dx = s - dy * W3;
    int yy = y + dy - PAD, xx = x + dx - PAD;
    if (((unsigned)yy < 64u) && ((unsigned)xx < 64u))
      return *(const uint4*)&feat[(size_t)(yy * 64 + xx) * FC + cb + c];
    return uint4{0u, 0u, 0u, 0u};
  };

  uint4 av = stageA(0);
  uint4 bv = bok ? *(const uint4*)(bptr) : uint4{0u, 0u, 0u, 0u};

  for (int k0 = 0; k0 < K; k0 += BK) {
    *(uint4*)&As[srow * LDSS + scol] = av;
    *(uint4*)&Bs[srow * LDSS + scol] = bv;
    __syncthreads();
    if (k0 + BK < K) {
      av = stageA(k0 + BK);
      bv = bok ? *(const uint4*)(bptr + k0 + BK) : uint4{0u, 0u, 0u, 0u};
    }
    frag_ab af0 = *(const frag_ab*)&As[(mw      + lr) * LDSS + lk * 8];
    frag_ab af1 = *(const frag_ab*)&As[(mw + 16 + lr) * LDSS + lk * 8];
    frag_ab bf0 = *(const frag_ab*)&Bs[(nw      + lr) * LDSS + lk * 8];
    frag_ab bf1 = *(const frag_ab*)&Bs[(nw + 16 + lr) * LDSS + lk * 8];
    acc[0][0] = __builtin_amdgcn_mfma_f32_16x16x32_bf16(af0, bf0, acc[0][0], 0, 0, 0);
    acc[0][1] = __builtin_amdgcn_mfma_f32_16x16x32_bf16(af0, bf1, acc[0][1], 0, 0, 0);
    acc[1][0] = __builtin_amdgcn_mfma_f32_16x16x32_bf16(af1, bf0, acc[1][0], 0, 0, 0);
    acc[1][1] = __builtin_amdgcn_mfma_f32_16x16x32_bf16(af1, bf1, acc[1][1], 0, 0, 0);
    __syncthreads();
  }

  const bool relu = flags & 1;
  const bool obf  = flags & 2;
  #pragma unroll
  for (int i = 0; i < 2; i++)
    #pragma unroll
    for (int j = 0; j < 2; j++) {
      int col = n0 + nw + j * 16 + lr;
      if (col >= N) continue;
      float badd = bz ? bz[col] : 0.f;
      #pragma unroll
      for (int r = 0; r < 4; r++) {
        int row = m0 + mw + i * 16 + lk * 4 + r;
        float v = acc[i][j][r] + badd;
        if (relu) v = fmaxf(v, 0.f);
        size_t idx = (size_t)z * sC + (size_t)row * ldc + col;
        if (obf) ((u16*)Cv)[idx] = f2b(v);
        else     ((float*)Cv)[idx] = v;
      }
    }
}

// ---------------------------------------------------------------------------
// Merged feat-consumer kernel: blocks [0,1152) = qkv GEMM (64x128 tile,
// implicit im2col A, glds-B (slot-swizzled), split-K(3), bf16 partials);
// blocks [1152,1664) = grouped 5x5 off1 conv (64x64 tile).
// ---------------------------------------------------------------------------
__global__ __launch_bounds__(256)
void gemm_feat(const u16* __restrict__ feat, const u16* __restrict__ Btqkv,
               u16* __restrict__ Pq, const u16* __restrict__ Btoff1,
               float* __restrict__ obuf, const float* __restrict__ b_off1)
{
  __shared__ u16 smem[6656];   // 13.3 KB: qkv As(2560)+Bs(4096); off1 uses 5120
  const int bid = blockIdx.x;
  const int tid = threadIdx.x;
  const int wave = tid >> 6, lane = tid & 63;
  const int lr = lane & 15, lk = lane >> 4;

  if (bid < NBLK_QKV) {
    // ----- qkv branch -----
    u16* As = smem;            // 64 * 40
    u16* Bs = smem + 64 * 40;  // 128 * 32, glds target (slot-swizzled)
    const int mz  = bid & 63;
    const int rest = bid >> 6;
    const int ny  = rest % 6;
    const int z   = rest / 6;
    const int m0  = mz * 64;
    const int n0  = ny * 128;
    const int kbeg = z * QCHUNK;
    const int kend = kbeg + QCHUNK;
    const int nw = wave * 32;
    const int arow = tid >> 2, acol = (tid & 3) * 8;
    const int p = m0 + arow, y = p >> 6, x = p & 63;

    frag_cd acc[4][2] = {};
    const int swl = swz_inv(tid);   // bijection on [0,256)
    const u16* bbase = Btqkv + (size_t)(n0 + (swl >> 2)) * KQ + (swl & 3) * 8 + kbeg;
    u16* bdst = &Bs[(size_t)tid * 8];

    auto stageA = [&](int k0) -> uint4 {
      int k = k0 + acol;
      int s = k >> 8, c = k & 255;
      int dy = s / 3, dx = s - dy * 3;
      int yy = y + dy - 1, xx = x + dx - 1;
      if (((unsigned)yy < 64u) && ((unsigned)xx < 64u))
        return *(const uint4*)&feat[(size_t)(yy * 64 + xx) * 256 + c];
      return uint4{0u, 0u, 0u, 0u};
    };

    uint4 av = stageA(kbeg);

    for (int k0 = kbeg; k0 < kend; k0 += BK) {
      glds16(bbase + (k0 - kbeg), bdst);
      glds16(bbase + (k0 - kbeg) + (size_t)64 * KQ, bdst + 2048);
      *(uint4*)&As[arow * LDSS + acol] = av;
      __syncthreads();
      if (k0 + BK < kend) av = stageA(k0 + BK);
      frag_ab af[4];
      #pragma unroll
      for (int i = 0; i < 4; i++)
        af[i] = *(const frag_ab*)&As[(i * 16 + lr) * LDSS + lk * 8];
      #pragma unroll
      for (int j = 0; j < 2; j++) {
        int n  = nw + j * 16 + lr;            // 0..127
        int nl = n & 63;                      // local row within half
        int sl = ((nl << 2) | lk) ^ (nl & 7); // swizzled 16B slot
        frag_ab bf = *(const frag_ab*)&Bs[((n & 64) << 5) + sl * 8];
        #pragma unroll
        for (int i = 0; i < 4; i++)
          acc[i][j] = __builtin_amdgcn_mfma_f32_16x16x32_bf16(af[i], bf, acc[i][j], 0, 0, 0);
      }
      __syncthreads();
    }

    #pragma unroll
    for (int i = 0; i < 4; i++)
      #pragma unroll
      for (int j = 0; j < 2; j++) {
        int col = n0 + nw + j * 16 + lr;
        #pragma unroll
        for (int r = 0; r < 4; r++) {
          int row = m0 + i * 16 + lk * 4 + r;
          Pq[(size_t)z * (NQ * 768) + (size_t)row * 768 + col] = f2b(acc[i][j][r]);
        }
      }
  } else {
    // ----- off1 grouped conv branch (5x5 pad2, 32 ch/group) -----
    u16* As = smem;            // 64 * 40
    u16* Bs = smem + 64 * 40;  // 64 * 40
    const int t  = bid - NBLK_QKV;
    const int m0 = (t & 63) * 64;
    const int g  = t >> 6;               // group 0..7
    const int cb = g * 32;
    const u16* Bt = Btoff1 + (size_t)g * 32 * 800;
    const float* bz = b_off1 + g * 32;
    const int mw = (wave & 1) * 32, nw = (wave >> 1) * 32;
    const int srow = tid >> 2, scol = (tid & 3) * 8;
    const int p = m0 + srow, y = p >> 6, x = p & 63;

    frag_cd acc[2][2] = {};
    const bool bok  = srow < 32;
    const u16* bptr = Bt + (size_t)srow * 800 + scol;

    auto stageA = [&](int k0) -> uint4 {
      int k = k0 + scol;
      int s = k >> 5;
      int c = k & 31;
      int dy = s / 5, dx = s - dy * 5;
      int yy = y + dy - 2, xx = x + dx - 2;
      if (((unsigned)yy < 64u) && ((unsigned)xx < 64u))
        return *(const uint4*)&feat[(size_t)(yy * 64 + xx) * 256 + cb + c];
      return uint4{0u, 0u, 0u, 0u};
    };

    uint4 av = stageA(0);
    uint4 bv = bok ? *(const uint4*)(bptr) : uint4{0u, 0u, 0u, 0u};

    for (int k0 = 0; k0 < 800; k0 += BK) {
      *(uint4*)&As[srow * LDSS + scol] = av;
      *(uint4*)&Bs[srow * LDSS + scol] = bv;
      __syncthreads();
      if (k0 + BK < 800) {
        av = stageA(k0 + BK);
        bv = bok ? *(const uint4*)(bptr + k0 + BK) : uint4{0u, 0u, 0u, 0u};
      }
      frag_ab af0 = *(const frag_ab*)&As[(mw      + lr) * LDSS + lk * 8];
      frag_ab af1 = *(const frag_ab*)&As[(mw + 16 + lr) * LDSS + lk * 8];
      frag_ab bf0 = *(const frag_ab*)&Bs[(nw      + lr) * LDSS + lk * 8];
      frag_ab bf1 = *(const frag_ab*)&Bs[(nw + 16 + lr) * LDSS + lk * 8];
      acc[0][0] = __builtin_amdgcn_mfma_f32_16x16x32_bf16(af0, bf0, acc[0][0], 0, 0, 0);
      acc[0][1] = __builtin_amdgcn_mfma_f32_16x16x32_bf16(af0, bf1, acc[0][1], 0, 0, 0);
      acc[1][0] = __builtin_amdgcn_mfma_f32_16x16x32_bf16(af1, bf0, acc[1][0], 0, 0, 0);
      acc[1][1] = __builtin_amdgcn_mfma_f32_16x16x32_bf16(af1, bf1, acc[1][1], 0, 0, 0);
      __syncthreads();
    }

    #pragma unroll
    for (int i = 0; i < 2; i++)
      #pragma unroll
      for (int j = 0; j < 2; j++) {
        int col = nw + j * 16 + lr;
        if (col >= 32) continue;
        float badd = bz[col];
        #pragma unroll
        for (int r = 0; r < 4; r++) {
          int row = m0 + mw + i * 16 + lk * 4 + r;
          obuf[(size_t)row * 256 + g * 32 + col] = acc[i][j][r] + badd;
        }
      }
  }
}

// sum QSPLIT bf16 qkv partials + bias -> fqkvb (bf16) and fqkvVb (bf16 V).
__global__ __launch_bounds__(256)
void reduce_qkv(const u16* __restrict__ P, const float* __restrict__ bias,
                u16* __restrict__ outb, u16* __restrict__ outV)
{
  int i8 = blockIdx.x * 256 + threadIdx.x;
  if (i8 >= NQ * 96) return;
  size_t i = (size_t)i8 * 8;
  int row = (int)(i / 768);
  int c = (int)(i % 768);
  float v[8];
  #pragma unroll
  for (int t = 0; t < 8; t++) v[t] = bias[c + t];
  for (int z = 0; z < QSPLIT; z++) {
    uint4 a = *(const uint4*)&P[(size_t)z * (NQ * 768) + i];
    u32 aw[4] = {a.x, a.y, a.z, a.w};
    #pragma unroll
    for (int t = 0; t < 4; t++) {
      v[2 * t]     += __uint_as_float(aw[t] << 16);
      v[2 * t + 1] += __uint_as_float(aw[t] & 0xffff0000u);
    }
  }
  uint4 ob = {pk2(v[0], v[1]), pk2(v[2], v[3]), pk2(v[4], v[5]), pk2(v[6], v[7])};
  *(uint4*)&outb[i] = ob;
  if (c >= 512) {
    // bf16 V gather table: identical values to fqkvb's V section, but a
    // dense 2 MB (pos,256) layout -> one uint4 per gather in gemm_big.
    *(uint4*)&outV[(size_t)row * 256 + (c - 512)] = ob;
  }
}

// ---------------------------------------------------------------------------
// Big MLP GEMM: fused gather-A (bf16 V, weight-mul + repack), 128x256 tile,
// BOTH tiles double-buffered, ONE barrier per K-iter, counted vmcnt, glds-B
// (slot-swizzled), split-K(16), bf16 partials. block 512 (8 waves),
// grid (32,16) = 2/CU (reg-capped: ~60 VGPR + 64 AGPR; (512,4) — do NOT
// raise min-waves, r15 spilled). BYTE-IDENTICAL to round 18.
// ---------------------------------------------------------------------------
__global__ __launch_bounds__(512, 4)
void gemm_big(const u16* __restrict__ Bt, const u16* __restrict__ fqkvV,
              const float* __restrict__ attnval, const int* __restrict__ vidx,
              u16* __restrict__ P)
{
  __shared__ u16 As[2 * 128 * LDSS];        // 20 KB double-buffered gather tile
  __shared__ u16 Bs[2 * 256 * 32];          // 32 KB double-buffered glds target
  __shared__ short s_vidx[JMAX * 128];      // 1.25 KB (ids < 4096 fit short)
  const int tid  = threadIdx.x;
  const int m0   = blockIdx.x * 128;
  const int z    = blockIdx.y;
  const int kbeg = z * KCHUNK;
  const int kend = min(KBIG, kbeg + KCHUNK);
  const int jbeg = kbeg >> 8;
  const int jcnt = ((kend - 1) >> 8) - jbeg + 1;   // <= 5
  const int wave = tid >> 6, lane = tid & 63;
  const int mw = (wave & 1) * 64, nwv = (wave >> 1) * 64;
  const int lr = lane & 15, lk = lane >> 4;
  const int arow = tid >> 2, acol = (tid & 3) * 8;  // 128 rows x 4x8
  const int q = m0 + arow;

  for (int t = tid; t < 128 * jcnt; t += 512) {
    int r = t & 127, jj = t >> 7;
    int j = jbeg + jj;
    s_vidx[t] = (short)((j < 49) ? vidx[(m0 + r) * 49 + j] : -1);
  }
  __syncthreads();   // s_vidx visible before pipeline starts

  // Unconditional gather: always issues exactly 2 VMEM loads (w then kv),
  // so per-wave vmcnt bookkeeping is exact. id<0 / j>=49 zeroed via select.
  auto loadA = [&](int k0, uint4& kv, float& w) {
    const int k = k0 + acol;
    const int j = k >> 8, c = k & 255;
    const int jj = j - jbeg;
    const int id = (int)s_vidx[jj * 128 + arow];
    const int jmin = min(j, 48);
    const int idc = (id >= 0) ? id : 0;
    float wraw = attnval[((size_t)(q * 49 + jmin)) * 8 + (c >> 5)];
    kv = *(const uint4*)(fqkvV + (size_t)idc * 256 + c);
    w = (id >= 0 && j < 49) ? wraw : 0.f;
  };

  auto stage = [&](u16* dst, const uint4& kvv, float w) {
    u32 aw[4] = {kvv.x, kvv.y, kvv.z, kvv.w};
    uint4 av;
    u32 avw[4];
    #pragma unroll
    for (int t = 0; t < 4; t++) {
      float lo = __uint_as_float(aw[t] << 16) * w;
      float hi = __uint_as_float(aw[t] & 0xffff0000u) * w;
      avw[t] = pk2(lo, hi);
    }
    av.x = avw[0]; av.y = avw[1]; av.z = avw[2]; av.w = avw[3];
    *(uint4*)&dst[arow * LDSS + acol] = av;
  };

  frag_cd acc[4][4] = {};
  uint4 kvc; float wc_;
  const int swl = swz_inv(tid);   // bijection on [0,512)
  const u16* bbase = Bt + (size_t)(swl >> 2) * KBIG + (swl & 3) * 8 + kbeg;
  const int nt = (kend - kbeg + BK - 1) / BK;

  // ---- prologue: A(0) gather -> stage As[0]; glds B(0) -> Bs[0];
  //      A(1) gather in flight; one convergence. ----
  loadA(kbeg, kvc, wc_);                       // A(0): 2 loads (oldest)
  glds16(bbase, &Bs[(size_t)tid * 8]);         // B(0): 2 glds (newer)
  glds16(bbase + (size_t)128 * KBIG, &Bs[(size_t)tid * 8 + 4096]);
  stage(As, kvc, wc_);                         // compiler waits A(0) loads
  loadA(kbeg + BK, kvc, wc_);                  // A(1) in flight
  asm volatile("s_waitcnt vmcnt(2) lgkmcnt(0)" ::: "memory");  // B(0) landed
  __builtin_amdgcn_s_barrier();

  int par = 0;
  for (int t = 0; t < nt; ++t, par ^= 1) {
    const int k0 = kbeg + t * BK;
    const u16* Asr = As + par * (128 * LDSS);
    if (t + 1 < nt) {
      // B(t+1) glds into the other buffer (2 oldest of this body's issues)
      u16* bd = &Bs[(size_t)(par ^ 1) * 8192 + (size_t)tid * 8];
      glds16(bbase + (k0 + BK - kbeg), bd);
      glds16(bbase + (k0 + BK - kbeg) + (size_t)128 * KBIG, bd + 4096);
      // stage A(t+1) (compiler-counted wait leaves the glds in flight)
      stage(As + (par ^ 1) * (128 * LDSS), kvc, wc_);
      // A(t+2) gather (clamped at the tail; surplus data never staged)
      loadA(min(k0 + 2 * BK, kend - BK), kvc, wc_);
    }
    // MFMA on buffers [par]
    const u16* bsrc = &Bs[(size_t)par * 8192 + ((nwv & 128) << 5)];
    const int nb = nwv & 127;
    frag_ab af[4];
    #pragma unroll
    for (int i = 0; i < 4; i++)
      af[i] = *(const frag_ab*)&Asr[(mw + i * 16 + lr) * LDSS + lk * 8];
    #pragma unroll
    for (int j = 0; j < 4; j++) {
      int nl = nb + j * 16 + lr;            // local row 0..127
      int sl = ((nl << 2) | lk) ^ (nl & 7); // swizzled 16B slot
      frag_ab bf = *(const frag_ab*)&bsrc[sl * 8];
      #pragma unroll
      for (int i = 0; i < 4; i++)
        acc[i][j] = __builtin_amdgcn_mfma_f32_16x16x32_bf16(af[i], bf, acc[i][j], 0, 0, 0);
    }
    // Single convergence: ds_reads retired + this body's glds landed
    // (outstanding afterwards: exactly the 2 A-gather loads).
    asm volatile("s_waitcnt vmcnt(2) lgkmcnt(0)" ::: "memory");
    __builtin_amdgcn_s_barrier();
  }

  #pragma unroll
  for (int i = 0; i < 4; i++)
    #pragma unroll
    for (int j = 0; j < 4; j++) {
      int col = nwv + j * 16 + lr;
      #pragma unroll
      for (int r = 0; r < 4; r++) {
        int row = m0 + mw + i * 16 + lk * 4 + r;
        P[(size_t)z * (NQ * 256) + (size_t)row * 256 + col] = f2b(acc[i][j][r]);
      }
    }
}

// ---------------------------------------------------------------------------
// Fused: hid2 = relu(sum_z Pb + bi1 + cell-tail); out = bi2 + skip + hid2.Wi2^T
// (cell tail = K cols 12544/5 of Wi1, moved out of gemm_big).
// ---------------------------------------------------------------------------
__global__ __launch_bounds__(256)
void reduce_final(const u16* __restrict__ Pb, const float* __restrict__ bi1,
                  const float* __restrict__ Wi2, const float* __restrict__ bi2,
                  const float* __restrict__ skipb, const float* __restrict__ cell,
                  const u16* __restrict__ Wi1p, float* __restrict__ out)
{
  const int q = blockIdx.x, c = threadIdx.x;
  float s = 0.f;
  #pragma unroll
  for (int z = 0; z < SPLITK; z++)
    s += b2f(Pb[(size_t)z * (NQ * 256) + (size_t)q * 256 + c]);
  s += bi1[c];
  // cell tail: rel_cell = cell * [H, W] = cell * 64
  {
    float cx = cell[q * 2] * 64.f, cy = cell[q * 2 + 1] * 64.f;
    const u16* wrow = Wi1p + (size_t)c * KBIG + 12544;
    s += b2f(wrow[0]) * cx + b2f(wrow[1]) * cy;
  }
  s = fmaxf(s, 0.f);

  __shared__ float part[3][4];
  float p0 = s * Wi2[c], p1 = s * Wi2[256 + c], p2 = s * Wi2[512 + c];
  #pragma unroll
  for (int off = 32; off; off >>= 1) {
    p0 += __shfl_xor(p0, off);
    p1 += __shfl_xor(p1, off);
    p2 += __shfl_xor(p2, off);
  }
  if ((c & 63) == 0) {
    int w = c >> 6;
    part[0][w] = p0; part[1][w] = p1; part[2][w] = p2;
  }
  __syncthreads();
  if (c < 3)
    out[q * 3 + c] = bi2[c] + skipb[q * 3 + c]
                   + part[c][0] + part[c][1] + part[c][2] + part[c][3];
}

// ---------------------------------------------------------------------------
// Weight packing — single launch for everything.
// ---------------------------------------------------------------------------
static __device__ __forceinline__
void packconv(const float* __restrict__ W, u16* __restrict__ Bt,
              int Cin, int K2, int idx)
{
  int o  = idx / (Cin * K2);
  int r  = idx - o * (Cin * K2);
  int ci = r / K2;
  int s  = r - ci * K2;
  Bt[(size_t)o * (Cin * K2) + s * Cin + ci] = f2b(W[idx]);
}
static __device__ __forceinline__
void packcast(const float* __restrict__ W, u16* __restrict__ Bt,
              int Kin, int Kout, int idx)
{
  int n = idx / Kout, k = idx - n * Kout;
  Bt[idx] = f2b(k < Kin ? W[(size_t)n * Kin + k] : 0.f);
}

#define SZ_CH   147456   // 256*64*9
#define SZ_QKV  589824   // 256*256*9
#define SZ_OFF1 204800   // 256*32*25
#define SZ_OFF2 25088    // 98*256
#define SZ_C1   32768    // 256*128
#define SZ_C2   12544    // 49*256
#define SZ_WI1  3219456  // 256*12576
#define SZ_PACK (SZ_CH + 3*SZ_QKV + SZ_OFF1 + SZ_OFF2 + SZ_C1 + SZ_C2 + 768 + SZ_WI1)

__global__ void pack_all(const float* W_ch, const float* W_q, const float* W_k,
                         const float* W_v, const float* W_off1, const float* W_off2,
                         const float* Wc1, const float* Wc2, const float* Wi1,
                         const float* b_q, const float* b_k, const float* b_v,
                         u16* Btch, u16* Btqkv, u16* Btoff1, u16* Btoff2,
                         u16* Btc1, u16* Btc2, u16* Wi1p, float* bqkv)
{
  int i = blockIdx.x * 256 + threadIdx.x;
  if (i < SZ_CH) { packconv(W_ch, Btch, 64, 9, i); return; }
  i -= SZ_CH;
  if (i < SZ_QKV) { packconv(W_q, Btqkv, 256, 9, i); return; }
  i -= SZ_QKV;
  if (i < SZ_QKV) { packconv(W_k, Btqkv + (size_t)256 * 2304, 256, 9, i); return; }
  i -= SZ_QKV;
  if (i < SZ_QKV) { packconv(W_v, Btqkv + (size_t)512 * 2304, 256, 9, i); return; }
  i -= SZ_QKV;
  if (i < SZ_OFF1) { packconv(W_off1, Btoff1, 32, 25, i); return; }
  i -= SZ_OFF1;
  if (i < SZ_OFF2) { packcast(W_off2, Btoff2, 256, 256, i); return; }
  i -= SZ_OFF2;
  if (i < SZ_C1) {
    // Wc1 (256 x 98) -> ROW-major padded: Btc1[c][k], k in [0,104) (13x16B
    // rows). Vectorized per-thread row reads in the fused sampler MLP.
    int c = i >> 7, k = i & 127;
    if (k < 104) Btc1[(size_t)c * 104 + k] = f2b(k < 98 ? Wc1[c * 98 + k] : 0.f);
    return;
  }
  i -= SZ_C1;
  if (i < SZ_C2) { packcast(Wc2, Btc2, 256, 256, i); return; }
  i -= SZ_C2;
  if (i < 768) {
    bqkv[i] = (i < 256) ? b_q[i] : (i < 512) ? b_k[i - 256] : b_v[i - 512];
    return;
  }
  i -= 768;
  if (i < SZ_WI1) { packcast(Wi1, Wi1p, 12546, 12576, i); }
}

// ---------------------------------------------------------------------------
// Encoder conv: 3->64, 3x3 pad1, +bias, relu -> feat1 (HW,64) bf16
// ---------------------------------------------------------------------------
__global__ __launch_bounds__(64)
void conv_enc(const float* __restrict__ inp, const float* __restrict__ W,
              const float* __restrict__ b, u16* __restrict__ feat1)
{
  const int p = blockIdx.x, c = threadIdx.x;
  const int y = p >> 6, x = p & 63;
  float s = b[c];
  #pragma unroll
  for (int ci = 0; ci < 3; ci++)
    #pragma unroll
    for (int dy = 0; dy < 3; dy++) {
      int yy = y + dy - 1;
      if ((unsigned)yy >= 64u) continue;
      #pragma unroll
      for (int dx = 0; dx < 3; dx++) {
        int xx = x + dx - 1;
        if ((unsigned)xx >= 64u) continue;
        s += inp[ci * HW + yy * 64 + xx] * W[((c * 3 + ci) * 3 + dy) * 3 + dx];
      }
    }
  feat1[(size_t)p * 64 + c] = f2b(fmaxf(s, 0.f));
}

// ---------------------------------------------------------------------------
// LayerNorm(channel) + exact GELU
// ---------------------------------------------------------------------------
__global__ __launch_bounds__(256)
void ln_gelu(const float* __restrict__ x, const float* __restrict__ g,
             const float* __restrict__ b, u16* __restrict__ y)
{
  const int p = blockIdx.x, c = threadIdx.x;
  __shared__ float r1[4], r2[4];
  float v = x[(size_t)p * 256 + c];
  float s1 = v, s2 = v * v;
  #pragma unroll
  for (int off = 32; off; off >>= 1) {
    s1 += __shfl_xor(s1, off);
    s2 += __shfl_xor(s2, off);
  }
  if ((c & 63) == 0) { r1[c >> 6] = s1; r2[c >> 6] = s2; }
  __syncthreads();
  float t1 = r1[0] + r1[1] + r1[2] + r1[3];
  float t2 = r2[0] + r2[1] + r2[2] + r2[3];
  float mu  = t1 * (1.f / 256.f);
  float var = t2 * (1.f / 256.f) - mu * mu;
  float xn = (v - mu) * rsqrtf(var + 1e-5f) * g[c] + b[c];
  float ge = 0.5f * xn * (1.f + erff(xn * 0.70710678118654752f));
  y[(size_t)p * 256 + c] = f2b(ge);
}

// ---------------------------------------------------------------------------
// Per-query sampler — FUSED attention-weight path (vectorized MLP loads):
// phase 0: hoist Wc1 row (13 uint4) into regs — latency hides under phase 1
// phase 1: offsets/tap coords/q-sample/skip (rel kept in LDS f32, 104-pad)
// phase 2: c1 MLP (reg-resident weights x LDS rel) ; q.k dots -> s_att
// phase 3: c2 (256->49, 4 lanes/output, 8 uint4 each)
// phase 4: per-head softmax -> attnval (final)
// ---------------------------------------------------------------------------
__global__ __launch_bounds__(256)
void sampler(const float* __restrict__ coord, const u16* __restrict__ fqkvb,
             const float* __restrict__ offs, const float* __restrict__ inp,
             float* __restrict__ attnval, int* __restrict__ vidx,
             float* __restrict__ skipb, const u16* __restrict__ Btc1,
             const u16* __restrict__ Btc2, const float* __restrict__ bc1,
             const float* __restrict__ bc2)
{
  const int q = blockIdx.x;
  const int tid = threadIdx.x;
  __shared__ float s_off[98];
  __shared__ int   s_idx[49];
  __shared__ float s_q[256];
  __shared__ float s_rel[104];
  __shared__ float s_att[49 * 8];
  __shared__ float s_hid[256];
  __shared__ float s_wc[49];

  // ---- phase 0: hoist this thread's Wc1 row (13 x uint4 = 104 bf16) ----
  uint4 wc1r[13];
  {
    const u16* wrow = Btc1 + (size_t)tid * 104;
    #pragma unroll
    for (int kb = 0; kb < 13; kb++)
      wc1r[kb] = *(const uint4*)(wrow + kb * 8);
  }

  const float c0 = coord[q * 2], c1 = coord[q * 2 + 1];
  const float gxp = ((c1 + 1.f) * 64.f - 1.f) * 0.5f;
  const float gyp = ((c0 + 1.f) * 64.f - 1.f) * 0.5f;
  const int ixn = (int)rintf(gxp), iyn = (int)rintf(gyp);
  const bool inn = ((unsigned)ixn < 64u) && ((unsigned)iyn < 64u);

  if (tid < 98) {
    float v = inn ? offs[(size_t)(iyn * 64 + ixn) * 98 + tid] : 0.f;
    s_off[tid] = tanhf(v) * (2.f / 63.f);
  }
  __syncthreads();

  const float scky = inn ? (-1.f + (float)(2 * iyn + 1) * (1.f / 64.f)) : 0.f;
  const float sckx = inn ? (-1.f + (float)(2 * ixn + 1) * (1.f / 64.f)) : 0.f;

  if (tid < 49) {
    const int a = tid / 7, bb = tid - a * 7;
    float sy = scky + (float)(a - 3) * (2.f / 64.f) + s_off[2 * tid];
    float sx = sckx + (float)(bb - 3) * (2.f / 64.f) + s_off[2 * tid + 1];
    s_rel[2 * tid]     = (c0 - sy) * 64.f;
    s_rel[2 * tid + 1] = (c1 - sx) * 64.f;
    float gx2 = ((sx + 1.f) * 64.f - 1.f) * 0.5f;
    float gy2 = ((sy + 1.f) * 64.f - 1.f) * 0.5f;
    int ix2 = (int)rintf(gx2), iy2 = (int)rintf(gy2);
    int id = (((unsigned)ix2 < 64u) && ((unsigned)iy2 < 64u)) ? (iy2 * 64 + ix2) : -1;
    s_idx[tid] = id;
    vidx[q * 49 + tid] = id;
  } else if (tid >= 98 && tid < 104) {
    s_rel[tid] = 0.f;   // zero-pad K 98->104
  }

  {
    const float x0f = floorf(gxp), y0f = floorf(gyp);
    const float wx = gxp - x0f, wy = gyp - y0f;
    const int x0 = (int)x0f, y0 = (int)y0f;
    float qc = 0.f;
    #pragma unroll
    for (int t = 0; t < 4; t++) {
      int xi = x0 + (t & 1), yi = y0 + (t >> 1);
      if (((unsigned)xi < 64u) && ((unsigned)yi < 64u)) {
        float w = ((t & 1) ? wx : 1.f - wx) * ((t >> 1) ? wy : 1.f - wy);
        qc += w * b2f(fqkvb[(size_t)(yi * 64 + xi) * 768 + tid]);
      }
    }
    s_q[tid] = qc * 0.17677669529663687f;
  }

  if (tid < 3) {
    float gx = fminf(fmaxf(gxp, 0.f), 63.f);
    float gy = fminf(fmaxf(gyp, 0.f), 63.f);
    float xf = floorf(gx), yf = floorf(gy);
    float wxs = gx - xf, wys = gy - yf;
    int xa = (int)xf, ya = (int)yf;
    int xb = min(xa + 1, 63), yb = min(ya + 1, 63);
    const float* ch = inp + tid * HW;
    float v = (1.f - wxs) * (1.f - wys) * ch[ya * 64 + xa]
            + wxs * (1.f - wys) * ch[ya * 64 + xb]
            + (1.f - wxs) * wys * ch[yb * 64 + xa]
            + wxs * wys * ch[yb * 64 + xb];
    skipb[q * 3 + tid] = v;
  }
  __syncthreads();

  // ---- c1 MLP: hid[c] = relu(bc1[c] + sum_k Wc1[c,k]*rel[k]) ----
  // weights reg-resident (phase 0), rel broadcast from LDS.
  {
    float h1 = bc1[tid];
    #pragma unroll
    for (int kb = 0; kb < 13; kb++) {
      u32 ws[4] = {wc1r[kb].x, wc1r[kb].y, wc1r[kb].z, wc1r[kb].w};
      #pragma unroll
      for (int t = 0; t < 4; t++) {
        h1 += __uint_as_float(ws[t] << 16)        * s_rel[kb * 8 + 2 * t];
        h1 += __uint_as_float(ws[t] & 0xffff0000u) * s_rel[kb * 8 + 2 * t + 1];
      }
    }
    s_hid[tid] = fmaxf(h1, 0.f);
  }

  // ---- q.k dots -> s_att ----
  const int wave = tid >> 6, lane = tid & 63;
  const int half = lane >> 5, sub = lane & 31;
  const int ch0 = sub * 8;
  const int h = sub >> 2;
  float qv[8];
  #pragma unroll
  for (int i = 0; i < 8; i++) qv[i] = s_q[ch0 + i];

  for (int it = 0; it < 7; it++) {
    int j = it * 8 + wave * 2 + half;
    if (j >= 49) break;
    int id = s_idx[j];
    float p = 0.f;
    if (id >= 0) {
      uint4 kv = *(const uint4*)&fqkvb[(size_t)id * 768 + 256 + ch0];
      u32 w0 = kv.x, w1 = kv.y, w2 = kv.z, w3 = kv.w;
      p = fmaf(qv[0], __uint_as_float(w0 << 16), p);
      p = fmaf(qv[1], __uint_as_float(w0 & 0xffff0000u), p);
      p = fmaf(qv[2], __uint_as_float(w1 << 16), p);
      p = fmaf(qv[3], __uint_as_float(w1 & 0xffff0000u), p);
      p = fmaf(qv[4], __uint_as_float(w2 << 16), p);
      p = fmaf(qv[5], __uint_as_float(w2 & 0xffff0000u), p);
      p = fmaf(qv[6], __uint_as_float(w3 << 16), p);
      p = fmaf(qv[7], __uint_as_float(w3 & 0xffff0000u), p);
    }
    p += __shfl_down(p, 2, 4);
    p += __shfl_down(p, 1, 4);
    if ((sub & 3) == 0) s_att[j * 8 + h] = p;
  }
  __syncthreads();   // s_hid + s_att ready

  // ---- c2: wc[j] = bc2[j] + sum_c Wc2[j,c]*hid[c], 4 lanes per j,
  //      8 x uint4 vector loads per lane ----
  if (tid < 196) {
    const int j = tid >> 2, p4 = tid & 3;
    float s2 = 0.f;
    const u16* w2 = Btc2 + (size_t)j * 256 + p4 * 64;
    const float* hsrc = s_hid + p4 * 64;
    #pragma unroll
    for (int kb = 0; kb < 8; kb++) {
      uint4 wv = *(const uint4*)(w2 + kb * 8);
      u32 ws[4] = {wv.x, wv.y, wv.z, wv.w};
      #pragma unroll
      for (int t = 0; t < 4; t++) {
        s2 += __uint_as_float(ws[t] << 16)        * hsrc[kb * 8 + 2 * t];
        s2 += __uint_as_float(ws[t] & 0xffff0000u) * hsrc[kb * 8 + 2 * t + 1];
      }
    }
    s2 += __shfl_down(s2, 2, 4);
    s2 += __shfl_down(s2, 1, 4);
    if (p4 == 0) s_wc[j] = s2 + bc2[j];
  }
  __syncthreads();   // s_wc ready

  // ---- softmax over j per head (identical math to old softmax_k) ----
  const int l = lane;
  #pragma unroll
  for (int pass = 0; pass < 2; pass++) {
    const int hh = wave + pass * 4;
    float v = (l < 49) ? s_wc[l] + s_att[l * 8 + hh] : -1e30f;
    float m = v;
    #pragma unroll
    for (int off = 32; off; off >>= 1) m = fmaxf(m, __shfl_xor(m, off));
    float e = (l < 49) ? expf(v - m) : 0.f;
    float ssum = e;
    #pragma unroll
    for (int off = 32; off; off >>= 1) ssum += __shfl_xor(ssum, off);
    if (l < 49) attnval[((size_t)q * 49 + l) * 8 + hh] = e / ssum;
  }
}

// ===========================================================================
extern "C" void kernel_launch(void* const* d_in, const int* in_sizes, int n_in,
                              void* d_out, int out_size, void* d_ws, size_t ws_size,
                              hipStream_t stream)
{
  const float* inp    = (const float*)d_in[0];
  const float* coord  = (const float*)d_in[1];
  const float* cell   = (const float*)d_in[2];
  const float* W_enc  = (const float*)d_in[3];
  const float* b_enc  = (const float*)d_in[4];
  const float* W_ch   = (const float*)d_in[5];
  const float* b_ch   = (const float*)d_in[6];
  const float* W_q    = (const float*)d_in[7];
  const float* b_q    = (const float*)d_in[8];
  const float* W_k    = (const float*)d_in[9];
  const float* b_k    = (const float*)d_in[10];
  const float* W_v    = (const float*)d_in[11];
  const float* b_v    = (const float*)d_in[12];
  const float* W_off1 = (const float*)d_in[13];
  const float* b_off1 = (const float*)d_in[14];
  const float* ln_g   = (const float*)d_in[15];
  const float* ln_b   = (const float*)d_in[16];
  const float* W_off2 = (const float*)d_in[17];
  const float* Wc1    = (const float*)d_in[18];
  const float* bc1    = (const float*)d_in[19];
  const float* Wc2    = (const float*)d_in[20];
  const float* bc2    = (const float*)d_in[21];
  const float* Wi1    = (const float*)d_in[22];
  const float* bi1    = (const float*)d_in[23];
  const float* Wi2    = (const float*)d_in[24];
  const float* bi2    = (const float*)d_in[25];

  char* base = (char*)d_ws;
  size_t off = 0;
  auto alloc = [&](size_t bytes) -> char* {
    char* r = base + off;
    off = (off + bytes + 255) & ~(size_t)255;
    return r;
  };

  // --- scratch region (dead before gemm_big runs; Pb aliases it) ---
  float* obuf   = (float*)alloc((size_t)HW * 256 * 4);
  u16*   ocg    = (u16*)  alloc((size_t)HW * 256 * 2);
  float* offsb  = (float*)alloc((size_t)HW * 98 * 4);
  u16*   feat1  = (u16*)  alloc((size_t)HW * 64 * 2);
  u16*   feat   = (u16*)  alloc((size_t)HW * 256 * 2);
  u16*   Btqkv  = (u16*)  alloc((size_t)768 * 2304 * 2);
  u16*   Btch   = (u16*)  alloc((size_t)256 * 576 * 2);
  u16*   Btoff1 = (u16*)  alloc((size_t)256 * 800 * 2);
  u16*   Btoff2 = (u16*)  alloc((size_t)98 * 256 * 2);
  u16*   Btc1   = (u16*)  alloc((size_t)256 * 104 * 2);
  u16*   Btc2   = (u16*)  alloc((size_t)49 * 256 * 2);
  // gemm_big bf16 partials alias scratch: 16 x 2MB = 33.6MB at base+0.
  u16* Pb = (u16*)base;
  // qkv bf16 partials at [36MB, 54.9MB): past live scratch (~14MB),
  // disjoint from Pb's 33.6MB, dead before gemm_big.
  u16* Pqb = (u16*)(base + ((size_t)36 << 20));
  {
    size_t need = ((size_t)36 << 20) + (size_t)QSPLIT * NQ * 768 * 2;
    if (off < need) off = (need + 255) & ~(size_t)255;
  }
  // --- persistent buffers ---
  u16*   fqkvb   = (u16*)  alloc((size_t)HW * 768 * 2);
  u16*   fqkvVb  = (u16*)  alloc((size_t)HW * 256 * 2);
  float* attnval = (float*)alloc((size_t)NQ * 49 * 8 * 4);
  int*   vidxb   = (int*)  alloc((size_t)NQ * 49 * 4);
  float* skipb   = (float*)alloc((size_t)NQ * 3 * 4);
  u16*   Wi1p    = (u16*)  alloc((size_t)256 * KBIG * 2);
  float* bqkv    = (float*)alloc(768 * 4);
  (void)ws_size; (void)in_sizes; (void)n_in; (void)out_size;

  // --- weight packing (single launch) ---
  pack_all<<<(SZ_PACK + 255) / 256, 256, 0, stream>>>(
      W_ch, W_q, W_k, W_v, W_off1, W_off2, Wc1, Wc2, Wi1, b_q, b_k, b_v,
      Btch, Btqkv, Btoff1, Btoff2, Btc1, Btc2, Wi1p, bqkv);

  // --- conv stack ---
  conv_enc<<<HW, 64, 0, stream>>>(inp, W_enc, b_enc, feat1);
  gemm_conv<3, 6, 1><<<dim3(64, 4, 1), 256, 0, stream>>>(
      feat1, Btch, feat, b_ch, 256, 576, 256, /*bf16*/2, 64, 0, 0, 0, 0);
  // merged qkv + off1 (overlap)
  gemm_feat<<<NBLK_QKV + NBLK_OFF1, 256, 0, stream>>>(
      feat, Btqkv, Pqb, Btoff1, obuf, b_off1);
  reduce_qkv<<<(NQ * 96 + 255) / 256, 256, 0, stream>>>(Pqb, bqkv, fqkvb, fqkvVb);
  ln_gelu<<<HW, 256, 0, stream>>>(obuf, ln_g, ln_b, ocg);
  gemm_bt<<<dim3(64, 2, 1), 256, 0, stream>>>(ocg, Btoff2, offsb, nullptr,
      98, 256, 98, 0, 0, 0, 0, 0);

  // --- per-query attention path (FUSED: q.k + wcoord MLP + softmax) ---
  sampler<<<NQ, 256, 0, stream>>>(coord, fqkvb, offsb, inp, attnval,
                                  vidxb, skipb, Btc1, Btc2, bc1, bc2);

  // --- big MLP: 128x256 tile, dbuf As+Bs, ONE barrier/iter, counted vmcnt,
  //     split-K(16), bf16 partials ---
  gemm_big<<<dim3(32, SPLITK), 512, 0, stream>>>(
      Wi1p, fqkvVb, attnval, vidxb, Pb);
  reduce_final<<<NQ, 256, 0, stream>>>(Pb, bi1, Wi2, bi2, skipb, cell, Wi1p,
                                       (float*)d_out);
}

// Round 7
// 275.047 us; speedup vs baseline: 1.1157x; 1.0808x over previous
//
#include <hip/hip_runtime.h>
#include <hip/hip_bf16.h>

// ============================================================================
// IDASR pipeline on gfx950 — round 21.
// Post-mortem r19/r20: fused sampler bottomed at 48.4us — 10us WORSE at
// pipeline level than the split path (r20 297.3 vs r18 287.1; best r16
// 281.3). Fusion reverted. r18's gemm_big restructure was also pipeline-
// negative (reduce_final strided tail) — reverted. Base = r16 wholesale.
// Single new lever (one technique, two instances — launch-merge of
// INDEPENDENT kernels, the pattern gemm_feat already validated):
//  * pack_enc: pack_all ∥ conv_enc in one launch (both consume only raw
//    inputs; conv blocks first so they start alongside the pack wavefront).
//  * post_feat: reduce_qkv ∥ ln_gelu in one launch (both depend only on
//    gemm_feat, not on each other).
// Removes 2 launches + overlaps ~10-20us of independent work.
// ============================================================================

typedef unsigned short u16;
typedef unsigned int u32;
using frag_ab = __attribute__((ext_vector_type(8))) short;  // 8 x bf16
using frag_cd = __attribute__((ext_vector_type(4))) float;  // 4 x f32 acc

#define HW 4096
#define NQ 4096
#define KBIG 12576
#define SPLITK 16
#define KCHUNK 800
#define JMAX 5
#define KQ 2304
#define QSPLIT 3
#define QCHUNK 768
#define NBLK_QKV (64 * 6 * QSPLIT)   // 1152
#define NBLK_OFF1 (64 * 8)           // 512

static __device__ __forceinline__ u16 f2b(float f) {
  union { __hip_bfloat16 h; u16 u; } c; c.h = __float2bfloat16(f); return c.u;
}
static __device__ __forceinline__ float b2f(u16 v) {
  return __uint_as_float((u32)v << 16);
}
static __device__ __forceinline__ u32 pk2(float a, float b) {
  union { __hip_bfloat162 h; u32 u; } c;
  c.h = __float22bfloat162_rn(float2{a, b});
  return c.u;
}
// async global->LDS, 16B per lane. LDS dest is wave-uniform base + lane*16.
static __device__ __forceinline__ void glds16(const u16* g, u16* l) {
  __builtin_amdgcn_global_load_lds(
      (const __attribute__((address_space(1))) u32*)(g),
      (__attribute__((address_space(3))) u32*)(l), 16, 0, 0);
}

#define BM 64
#define BN 64
#define BK 32
#define LDSS 40   // padded lds row stride for reg-staged tiles

// ---------------------------------------------------------------------------
// Generic bf16 GEMM (64x64 tile): off2, c1, c2 layers.
// ---------------------------------------------------------------------------
__global__ __launch_bounds__(256)
void gemm_bt(const u16* __restrict__ A, const u16* __restrict__ Bt,
             void* __restrict__ Cv, const float* __restrict__ bias,
             int N, int K, int ldc, int flags,   // 1=relu, 2=bf16 out
             long sA, long sB, long sC, int sBias)
{
  __shared__ u16 As[BM * LDSS];
  __shared__ u16 Bs[BN * LDSS];
  const int z = blockIdx.z;
  A  += (long)z * sA;
  Bt += (long)z * sB;
  const float* bz = bias ? bias + (long)z * sBias : nullptr;

  const int tid  = threadIdx.x;
  const int m0   = blockIdx.x * BM;
  const int n0   = blockIdx.y * BN;
  const int wave = tid >> 6, lane = tid & 63;
  const int mw = (wave & 1) * 32, nw = (wave >> 1) * 32;
  const int lr = lane & 15, lk = lane >> 4;
  const int srow = tid >> 2, scol = (tid & 3) * 8;

  frag_cd acc[2][2] = {};
  const u16* aptr = A + (size_t)(m0 + srow) * K + scol;
  const bool bok  = (n0 + srow) < N;
  const u16* bptr = Bt + (size_t)(n0 + srow) * K + scol;

  uint4 av = *(const uint4*)(aptr);
  uint4 bv = bok ? *(const uint4*)(bptr) : uint4{0u, 0u, 0u, 0u};

  for (int k0 = 0; k0 < K; k0 += BK) {
    *(uint4*)&As[srow * LDSS + scol] = av;
    *(uint4*)&Bs[srow * LDSS + scol] = bv;
    __syncthreads();
    if (k0 + BK < K) {
      av = *(const uint4*)(aptr + k0 + BK);
      bv = bok ? *(const uint4*)(bptr + k0 + BK) : uint4{0u, 0u, 0u, 0u};
    }
    frag_ab af0 = *(const frag_ab*)&As[(mw      + lr) * LDSS + lk * 8];
    frag_ab af1 = *(const frag_ab*)&As[(mw + 16 + lr) * LDSS + lk * 8];
    frag_ab bf0 = *(const frag_ab*)&Bs[(nw      + lr) * LDSS + lk * 8];
    frag_ab bf1 = *(const frag_ab*)&Bs[(nw + 16 + lr) * LDSS + lk * 8];
    acc[0][0] = __builtin_amdgcn_mfma_f32_16x16x32_bf16(af0, bf0, acc[0][0], 0, 0, 0);
    acc[0][1] = __builtin_amdgcn_mfma_f32_16x16x32_bf16(af0, bf1, acc[0][1], 0, 0, 0);
    acc[1][0] = __builtin_amdgcn_mfma_f32_16x16x32_bf16(af1, bf0, acc[1][0], 0, 0, 0);
    acc[1][1] = __builtin_amdgcn_mfma_f32_16x16x32_bf16(af1, bf1, acc[1][1], 0, 0, 0);
    __syncthreads();
  }

  const bool relu = flags & 1;
  const bool obf  = flags & 2;
  #pragma unroll
  for (int i = 0; i < 2; i++)
    #pragma unroll
    for (int j = 0; j < 2; j++) {
      int col = n0 + nw + j * 16 + lr;
      if (col >= N) continue;
      float badd = bz ? bz[col] : 0.f;
      #pragma unroll
      for (int r = 0; r < 4; r++) {
        int row = m0 + mw + i * 16 + lk * 4 + r;
        float v = acc[i][j][r] + badd;
        if (relu) v = fmaxf(v, 0.f);
        size_t idx = (size_t)z * sC + (size_t)row * ldc + col;
        if (obf) ((u16*)Cv)[idx] = f2b(v);
        else     ((float*)Cv)[idx] = v;
      }
    }
}

// ---------------------------------------------------------------------------
// Implicit-im2col conv GEMM, 64x64 tile (ch conv only now).
// ---------------------------------------------------------------------------
template<int W3, int SH, int PAD>
__global__ __launch_bounds__(256)
void gemm_conv(const u16* __restrict__ feat, const u16* __restrict__ Bt,
               void* __restrict__ Cv, const float* __restrict__ bias,
               int N, int K, int ldc, int flags, int FC, int cbStride,
               long sB, long sC, int sBias)
{
  __shared__ u16 As[BM * LDSS];
  __shared__ u16 Bs[BN * LDSS];
  const int z = blockIdx.z;
  Bt += (long)z * sB;
  const float* bz = bias ? bias + (long)z * sBias : nullptr;
  const int cb = z * cbStride;

  const int tid  = threadIdx.x;
  const int m0   = blockIdx.x * BM;
  const int n0   = blockIdx.y * BN;
  const int wave = tid >> 6, lane = tid & 63;
  const int mw = (wave & 1) * 32, nw = (wave >> 1) * 32;
  const int lr = lane & 15, lk = lane >> 4;
  const int srow = tid >> 2, scol = (tid & 3) * 8;
  const int p = m0 + srow, y = p >> 6, x = p & 63;

  frag_cd acc[2][2] = {};
  const bool bok  = (n0 + srow) < N;
  const u16* bptr = Bt + (size_t)(n0 + srow) * K + scol;

  auto stageA = [&](int k0) -> uint4 {
    int k = k0 + scol;
    int s = k >> SH;
    int c = k & ((1 << SH) - 1);
    int dy = s / W3, dx = s - dy * W3;
    int yy = y + dy - PAD, xx = x + dx - PAD;
    if (((unsigned)yy < 64u) && ((unsigned)xx < 64u))
      return *(const uint4*)&feat[(size_t)(yy * 64 + xx) * FC + cb + c];
    return uint4{0u, 0u, 0u, 0u};
  };

  uint4 av = stageA(0);
  uint4 bv = bok ? *(const uint4*)(bptr) : uint4{0u, 0u, 0u, 0u};

  for (int k0 = 0; k0 < K; k0 += BK) {
    *(uint4*)&As[srow * LDSS + scol] = av;
    *(uint4*)&Bs[srow * LDSS + scol] = bv;
    __syncthreads();
    if (k0 + BK < K) {
      av = stageA(k0 + BK);
      bv = bok ? *(const uint4*)(bptr + k0 + BK) : uint4{0u, 0u, 0u, 0u};
    }
    frag_ab af0 = *(const frag_ab*)&As[(mw      + lr) * LDSS + lk * 8];
    frag_ab af1 = *(const frag_ab*)&As[(mw + 16 + lr) * LDSS + lk * 8];
    frag_ab bf0 = *(const frag_ab*)&Bs[(nw      + lr) * LDSS + lk * 8];
    frag_ab bf1 = *(const frag_ab*)&Bs[(nw + 16 + lr) * LDSS + lk * 8];
    acc[0][0] = __builtin_amdgcn_mfma_f32_16x16x32_bf16(af0, bf0, acc[0][0], 0, 0, 0);
    acc[0][1] = __builtin_amdgcn_mfma_f32_16x16x32_bf16(af0, bf1, acc[0][1], 0, 0, 0);
    acc[1][0] = __builtin_amdgcn_mfma_f32_16x16x32_bf16(af1, bf0, acc[1][0], 0, 0, 0);
    acc[1][1] = __builtin_amdgcn_mfma_f32_16x16x32_bf16(af1, bf1, acc[1][1], 0, 0, 0);
    __syncthreads();
  }

  const bool relu = flags & 1;
  const bool obf  = flags & 2;
  #pragma unroll
  for (int i = 0; i < 2; i++)
    #pragma unroll
    for (int j = 0; j < 2; j++) {
      int col = n0 + nw + j * 16 + lr;
      if (col >= N) continue;
      float badd = bz ? bz[col] : 0.f;
      #pragma unroll
      for (int r = 0; r < 4; r++) {
        int row = m0 + mw + i * 16 + lk * 4 + r;
        float v = acc[i][j][r] + badd;
        if (relu) v = fmaxf(v, 0.f);
        size_t idx = (size_t)z * sC + (size_t)row * ldc + col;
        if (obf) ((u16*)Cv)[idx] = f2b(v);
        else     ((float*)Cv)[idx] = v;
      }
    }
}

// ---------------------------------------------------------------------------
// Merged feat-consumer kernel: blocks [0,1152) = qkv GEMM (64x128 tile,
// implicit im2col A, glds-B, split-K(3), bf16 partials); blocks
// [1152,1664) = grouped 5x5 off1 conv (64x64 tile). One launch -> overlap.
// ---------------------------------------------------------------------------
__global__ __launch_bounds__(256)
void gemm_feat(const u16* __restrict__ feat, const u16* __restrict__ Btqkv,
               u16* __restrict__ Pq, const u16* __restrict__ Btoff1,
               float* __restrict__ obuf, const float* __restrict__ b_off1)
{
  __shared__ u16 smem[6656];   // 13.3 KB: qkv As(2560)+Bs(4096); off1 uses 5120
  const int bid = blockIdx.x;
  const int tid = threadIdx.x;
  const int wave = tid >> 6, lane = tid & 63;
  const int lr = lane & 15, lk = lane >> 4;

  if (bid < NBLK_QKV) {
    // ----- qkv branch -----
    u16* As = smem;            // 64 * 40
    u16* Bs = smem + 64 * 40;  // 128 * 32, glds target
    const int mz  = bid & 63;
    const int rest = bid >> 6;
    const int ny  = rest % 6;
    const int z   = rest / 6;
    const int m0  = mz * 64;
    const int n0  = ny * 128;
    const int kbeg = z * QCHUNK;
    const int kend = kbeg + QCHUNK;
    const int nw = wave * 32;
    const int arow = tid >> 2, acol = (tid & 3) * 8;
    const int p = m0 + arow, y = p >> 6, x = p & 63;

    frag_cd acc[4][2] = {};
    const u16* bbase = Btqkv + (size_t)(n0 + (tid >> 2)) * KQ + (tid & 3) * 8 + kbeg;
    u16* bdst = &Bs[(size_t)tid * 8];

    auto stageA = [&](int k0) -> uint4 {
      int k = k0 + acol;
      int s = k >> 8, c = k & 255;
      int dy = s / 3, dx = s - dy * 3;
      int yy = y + dy - 1, xx = x + dx - 1;
      if (((unsigned)yy < 64u) && ((unsigned)xx < 64u))
        return *(const uint4*)&feat[(size_t)(yy * 64 + xx) * 256 + c];
      return uint4{0u, 0u, 0u, 0u};
    };

    uint4 av = stageA(kbeg);

    for (int k0 = kbeg; k0 < kend; k0 += BK) {
      glds16(bbase + (k0 - kbeg), bdst);
      glds16(bbase + (k0 - kbeg) + (size_t)64 * KQ, bdst + 2048);
      *(uint4*)&As[arow * LDSS + acol] = av;
      __syncthreads();
      if (k0 + BK < kend) av = stageA(k0 + BK);
      frag_ab af[4];
      #pragma unroll
      for (int i = 0; i < 4; i++)
        af[i] = *(const frag_ab*)&As[(i * 16 + lr) * LDSS + lk * 8];
      #pragma unroll
      for (int j = 0; j < 2; j++) {
        frag_ab bf = *(const frag_ab*)&Bs[(nw + j * 16 + lr) * 32 + lk * 8];
        #pragma unroll
        for (int i = 0; i < 4; i++)
          acc[i][j] = __builtin_amdgcn_mfma_f32_16x16x32_bf16(af[i], bf, acc[i][j], 0, 0, 0);
      }
      __syncthreads();
    }

    #pragma unroll
    for (int i = 0; i < 4; i++)
      #pragma unroll
      for (int j = 0; j < 2; j++) {
        int col = n0 + nw + j * 16 + lr;
        #pragma unroll
        for (int r = 0; r < 4; r++) {
          int row = m0 + i * 16 + lk * 4 + r;
          Pq[(size_t)z * (NQ * 768) + (size_t)row * 768 + col] = f2b(acc[i][j][r]);
        }
      }
  } else {
    // ----- off1 grouped conv branch (5x5 pad2, 32 ch/group) -----
    u16* As = smem;            // 64 * 40
    u16* Bs = smem + 64 * 40;  // 64 * 40
    const int t  = bid - NBLK_QKV;
    const int m0 = (t & 63) * 64;
    const int g  = t >> 6;               // group 0..7
    const int cb = g * 32;
    const u16* Bt = Btoff1 + (size_t)g * 32 * 800;
    const float* bz = b_off1 + g * 32;
    const int mw = (wave & 1) * 32, nw = (wave >> 1) * 32;
    const int srow = tid >> 2, scol = (tid & 3) * 8;
    const int p = m0 + srow, y = p >> 6, x = p & 63;

    frag_cd acc[2][2] = {};
    const bool bok  = srow < 32;
    const u16* bptr = Bt + (size_t)srow * 800 + scol;

    auto stageA = [&](int k0) -> uint4 {
      int k = k0 + scol;
      int s = k >> 5;
      int c = k & 31;
      int dy = s / 5, dx = s - dy * 5;
      int yy = y + dy - 2, xx = x + dx - 2;
      if (((unsigned)yy < 64u) && ((unsigned)xx < 64u))
        return *(const uint4*)&feat[(size_t)(yy * 64 + xx) * 256 + cb + c];
      return uint4{0u, 0u, 0u, 0u};
    };

    uint4 av = stageA(0);
    uint4 bv = bok ? *(const uint4*)(bptr) : uint4{0u, 0u, 0u, 0u};

    for (int k0 = 0; k0 < 800; k0 += BK) {
      *(uint4*)&As[srow * LDSS + scol] = av;
      *(uint4*)&Bs[srow * LDSS + scol] = bv;
      __syncthreads();
      if (k0 + BK < 800) {
        av = stageA(k0 + BK);
        bv = bok ? *(const uint4*)(bptr + k0 + BK) : uint4{0u, 0u, 0u, 0u};
      }
      frag_ab af0 = *(const frag_ab*)&As[(mw      + lr) * LDSS + lk * 8];
      frag_ab af1 = *(const frag_ab*)&As[(mw + 16 + lr) * LDSS + lk * 8];
      frag_ab bf0 = *(const frag_ab*)&Bs[(nw      + lr) * LDSS + lk * 8];
      frag_ab bf1 = *(const frag_ab*)&Bs[(nw + 16 + lr) * LDSS + lk * 8];
      acc[0][0] = __builtin_amdgcn_mfma_f32_16x16x32_bf16(af0, bf0, acc[0][0], 0, 0, 0);
      acc[0][1] = __builtin_amdgcn_mfma_f32_16x16x32_bf16(af0, bf1, acc[0][1], 0, 0, 0);
      acc[1][0] = __builtin_amdgcn_mfma_f32_16x16x32_bf16(af1, bf0, acc[1][0], 0, 0, 0);
      acc[1][1] = __builtin_amdgcn_mfma_f32_16x16x32_bf16(af1, bf1, acc[1][1], 0, 0, 0);
      __syncthreads();
    }

    #pragma unroll
    for (int i = 0; i < 2; i++)
      #pragma unroll
      for (int j = 0; j < 2; j++) {
        int col = nw + j * 16 + lr;
        if (col >= 32) continue;
        float badd = bz[col];
        #pragma unroll
        for (int r = 0; r < 4; r++) {
          int row = m0 + mw + i * 16 + lk * 4 + r;
          obuf[(size_t)row * 256 + g * 32 + col] = acc[i][j][r] + badd;
        }
      }
  }
}

// ---------------------------------------------------------------------------
// Merged post-gemm_feat kernel: blocks [0,1536) = reduce_qkv (sum QSPLIT
// bf16 qkv partials + bias -> fqkvb + fqkvVb); blocks [1536, 1536+4096) =
// ln_gelu (LayerNorm + exact GELU on obuf). The two are independent — both
// depend only on gemm_feat.
// ---------------------------------------------------------------------------
#define RQ_BLKS 1536   // NQ*96/256
__global__ __launch_bounds__(256)
void post_feat(const u16* __restrict__ P, const float* __restrict__ bias,
               u16* __restrict__ outb, u16* __restrict__ outV,
               const float* __restrict__ x, const float* __restrict__ g,
               const float* __restrict__ b, u16* __restrict__ y)
{
  const int bid = blockIdx.x;
  const int tid = threadIdx.x;
  if (bid < RQ_BLKS) {
    // ----- reduce_qkv -----
    int i8 = bid * 256 + tid;
    size_t i = (size_t)i8 * 8;
    int row = (int)(i / 768);
    int c = (int)(i % 768);
    float v[8];
    #pragma unroll
    for (int t = 0; t < 8; t++) v[t] = bias[c + t];
    for (int z = 0; z < QSPLIT; z++) {
      uint4 a = *(const uint4*)&P[(size_t)z * (NQ * 768) + i];
      u32 aw[4] = {a.x, a.y, a.z, a.w};
      #pragma unroll
      for (int t = 0; t < 4; t++) {
        v[2 * t]     += __uint_as_float(aw[t] << 16);
        v[2 * t + 1] += __uint_as_float(aw[t] & 0xffff0000u);
      }
    }
    uint4 ob = {pk2(v[0], v[1]), pk2(v[2], v[3]), pk2(v[4], v[5]), pk2(v[6], v[7])};
    *(uint4*)&outb[i] = ob;
    if (c >= 512) {
      // bf16 V gather table: dense 2 MB (pos,256) layout for gemm_big.
      *(uint4*)&outV[(size_t)row * 256 + (c - 512)] = ob;
    }
  } else {
    // ----- ln_gelu -----
    const int p = bid - RQ_BLKS, c = tid;
    __shared__ float r1[4], r2[4];
    float v = x[(size_t)p * 256 + c];
    float s1 = v, s2 = v * v;
    #pragma unroll
    for (int off = 32; off; off >>= 1) {
      s1 += __shfl_xor(s1, off);
      s2 += __shfl_xor(s2, off);
    }
    if ((c & 63) == 0) { r1[c >> 6] = s1; r2[c >> 6] = s2; }
    __syncthreads();
    float t1 = r1[0] + r1[1] + r1[2] + r1[3];
    float t2 = r2[0] + r2[1] + r2[2] + r2[3];
    float mu  = t1 * (1.f / 256.f);
    float var = t2 * (1.f / 256.f) - mu * mu;
    float xn = (v - mu) * rsqrtf(var + 1e-5f) * g[c] + b[c];
    float ge = 0.5f * xn * (1.f + erff(xn * 0.70710678118654752f));
    y[(size_t)p * 256 + c] = f2b(ge);
  }
}

// ---------------------------------------------------------------------------
// Big MLP GEMM: fused gather-A (bf16 V, weight-mul + repack), 128x256 tile,
// double-buffered glds-B with counted-vmcnt pipeline, split-K(16), bf16
// partials. block 512 (8 waves), grid (32, 16) = 2/CU (reg-capped: ~60 VGPR
// + 64 AGPR unified; (512,4) — do NOT raise min-waves, r15 spilled).
// r16 version (proven best pipeline).
// ---------------------------------------------------------------------------
__global__ __launch_bounds__(512, 4)
void gemm_big(const u16* __restrict__ Bt, const u16* __restrict__ fqkvV,
              const float* __restrict__ attnval, const int* __restrict__ vidx,
              const float* __restrict__ cell, u16* __restrict__ P)
{
  __shared__ u16 As[128 * LDSS];            // 10 KB padded, reg-staged gather
  __shared__ u16 Bs[2 * 256 * 32];          // 32 KB double-buffered glds target
  __shared__ short s_vidx[JMAX * 128];      // 1.25 KB (ids < 4096 fit short)
  __shared__ float s_attn[JMAX * 128 * 8];  // 20 KB
  const int tid  = threadIdx.x;
  const int m0   = blockIdx.x * 128;
  const int z    = blockIdx.y;
  const int kbeg = z * KCHUNK;
  const int kend = min(KBIG, kbeg + KCHUNK);
  const int jbeg = kbeg >> 8;
  const int jcnt = ((kend - 1) >> 8) - jbeg + 1;   // <= 5
  const int wave = tid >> 6, lane = tid & 63;
  const int mw = (wave & 1) * 64, nwv = (wave >> 1) * 64;
  const int lr = lane & 15, lk = lane >> 4;
  const int arow = tid >> 2, acol = (tid & 3) * 8;  // 128 rows x 4x8
  const int q = m0 + arow;

  for (int t = tid; t < 128 * jcnt; t += 512) {
    int r = t & 127, jj = t >> 7;
    int j = jbeg + jj;
    s_vidx[t] = (short)((j < 49) ? vidx[(m0 + r) * 49 + j] : -1);
  }
  for (int t = tid; t < 128 * 8 * jcnt; t += 512) {
    int h = t & 7, rr = (t >> 3) & 127, jj = t >> 10;
    int j = jbeg + jj;
    s_attn[t] = (j < 49) ? attnval[((size_t)((m0 + rr) * 49 + j)) * 8 + h] : 0.f;
  }
  __syncthreads();   // full drain: preload loads retired before pipeline starts

  auto loadA = [&](int k0, uint4& kv, float& w) {
    const int k = k0 + acol;
    const int j = k >> 8, c = k & 255;
    kv = uint4{0u, 0u, 0u, 0u};
    w = 0.f;
    if (j < 49) {
      const int jj = j - jbeg;
      int id = s_vidx[jj * 128 + arow];
      if (id >= 0) {
        w = s_attn[(jj * 128 + arow) * 8 + (c >> 5)];
        kv = *(const uint4*)(fqkvV + (size_t)id * 256 + c);   // 8 bf16
      }
    } else if (c == 0) {
      kv.x = pk2(cell[q * 2], cell[q * 2 + 1]);  // cell = 1/64, exact in bf16
      w = 64.f;
    }
  };

  frag_cd acc[4][4] = {};
  uint4 kvc; float wc_;
  const u16* bbase = Bt + (size_t)(tid >> 2) * KBIG + (tid & 3) * 8 + kbeg;

  // prologue: B tile 0 -> buffer 0 (2 glds in flight), A(0) -> regs
  glds16(bbase, &Bs[(size_t)tid * 8]);
  glds16(bbase + (size_t)128 * KBIG, &Bs[(size_t)tid * 8 + 4096]);
  loadA(kbeg, kvc, wc_);

  int par = 0;
  for (int k0 = kbeg; k0 < kend; k0 += BK, par ^= 1) {
    // stage A(t): unpack bf16 pair -> f32, scale by attn weight, repack.
    {
      u32 aw[4] = {kvc.x, kvc.y, kvc.z, kvc.w};
      uint4 av;
      u32 avw[4];
      #pragma unroll
      for (int t = 0; t < 4; t++) {
        float lo = __uint_as_float(aw[t] << 16) * wc_;
        float hi = __uint_as_float(aw[t] & 0xffff0000u) * wc_;
        avw[t] = pk2(lo, hi);
      }
      av.x = avw[0]; av.y = avw[1]; av.z = avw[2]; av.w = avw[3];
      *(uint4*)&As[arow * LDSS + acol] = av;
    }
    if (k0 + BK < kend) {
      // issue B(t+1) into the other buffer; keep it in flight across the
      // barrier — only the 2 newest VMEM ops may remain outstanding, so
      // vmcnt(2) guarantees B(t) (older) has landed.
      u16* bd = &Bs[(size_t)(par ^ 1) * 8192 + (size_t)tid * 8];
      glds16(bbase + (k0 + BK - kbeg), bd);
      glds16(bbase + (k0 + BK - kbeg) + (size_t)128 * KBIG, bd + 4096);
      asm volatile("s_waitcnt vmcnt(2) lgkmcnt(0)" ::: "memory");
    } else {
      asm volatile("s_waitcnt vmcnt(0) lgkmcnt(0)" ::: "memory");
    }
    __builtin_amdgcn_s_barrier();
    if (k0 + BK < kend) loadA(k0 + BK, kvc, wc_);   // A prefetch (compiler-waited)
    const u16* bsrc = &Bs[(size_t)par * 8192];
    frag_ab af[4];
    #pragma unroll
    for (int i = 0; i < 4; i++)
      af[i] = *(const frag_ab*)&As[(mw + i * 16 + lr) * LDSS + lk * 8];
    #pragma unroll
    for (int j = 0; j < 4; j++) {
      frag_ab bf = *(const frag_ab*)&bsrc[(nwv + j * 16 + lr) * 32 + lk * 8];
      #pragma unroll
      for (int i = 0; i < 4; i++)
        acc[i][j] = __builtin_amdgcn_mfma_f32_16x16x32_bf16(af[i], bf, acc[i][j], 0, 0, 0);
    }
    asm volatile("s_waitcnt lgkmcnt(0)" ::: "memory");
    __builtin_amdgcn_s_barrier();
  }

  #pragma unroll
  for (int i = 0; i < 4; i++)
    #pragma unroll
    for (int j = 0; j < 4; j++) {
      int col = nwv + j * 16 + lr;
      #pragma unroll
      for (int r = 0; r < 4; r++) {
        int row = m0 + mw + i * 16 + lk * 4 + r;
        P[(size_t)z * (NQ * 256) + (size_t)row * 256 + col] = f2b(acc[i][j][r]);
      }
    }
}

// ---------------------------------------------------------------------------
// Fused: hid2 = relu(sum_z Pb + bi1); out = bi2 + skip + hid2 . Wi2^T.
// ---------------------------------------------------------------------------
__global__ __launch_bounds__(256)
void reduce_final(const u16* __restrict__ Pb, const float* __restrict__ bi1,
                  const float* __restrict__ Wi2, const float* __restrict__ bi2,
                  const float* __restrict__ skipb, float* __restrict__ out)
{
  const int q = blockIdx.x, c = threadIdx.x;
  float s = 0.f;
  #pragma unroll
  for (int z = 0; z < SPLITK; z++)
    s += b2f(Pb[(size_t)z * (NQ * 256) + (size_t)q * 256 + c]);
  s += bi1[c];
  s = fmaxf(s, 0.f);

  __shared__ float part[3][4];
  float p0 = s * Wi2[c], p1 = s * Wi2[256 + c], p2 = s * Wi2[512 + c];
  #pragma unroll
  for (int off = 32; off; off >>= 1) {
    p0 += __shfl_xor(p0, off);
    p1 += __shfl_xor(p1, off);
    p2 += __shfl_xor(p2, off);
  }
  if ((c & 63) == 0) {
    int w = c >> 6;
    part[0][w] = p0; part[1][w] = p1; part[2][w] = p2;
  }
  __syncthreads();
  if (c < 3)
    out[q * 3 + c] = bi2[c] + skipb[q * 3 + c]
                   + part[c][0] + part[c][1] + part[c][2] + part[c][3];
}

// ---------------------------------------------------------------------------
// softmax over 49 taps per head. block 512 (8 waves = 8 heads), grid NQ.
// ---------------------------------------------------------------------------
__global__ __launch_bounds__(512)
void softmax_k(const float* __restrict__ wc, float* __restrict__ attnval)
{
  const int q = blockIdx.x;
  const int tid = threadIdx.x;
  const int hh = tid >> 6, l = tid & 63;
  float v = (l < 49) ? wc[(size_t)q * 49 + l] + attnval[((size_t)q * 49 + l) * 8 + hh]
                     : -1e30f;
  float m = v;
  #pragma unroll
  for (int off = 32; off; off >>= 1) m = fmaxf(m, __shfl_xor(m, off));
  float e = (l < 49) ? expf(v - m) : 0.f;
  float s = e;
  #pragma unroll
  for (int off = 32; off; off >>= 1) s += __shfl_xor(s, off);
  if (l < 49) attnval[((size_t)q * 49 + l) * 8 + hh] = e / s;
}

// ---------------------------------------------------------------------------
// Merged weight-packing + encoder-conv kernel. Blocks [0, CONV_BLKS) run the
// encoder conv (independent of packing — both consume only raw inputs; conv
// first so it starts alongside the pack wavefront). Remaining blocks pack.
// ---------------------------------------------------------------------------
static __device__ __forceinline__
void packconv(const float* __restrict__ W, u16* __restrict__ Bt,
              int Cin, int K2, int idx)
{
  int o  = idx / (Cin * K2);
  int r  = idx - o * (Cin * K2);
  int ci = r / K2;
  int s  = r - ci * K2;
  Bt[(size_t)o * (Cin * K2) + s * Cin + ci] = f2b(W[idx]);
}
static __device__ __forceinline__
void packcast(const float* __restrict__ W, u16* __restrict__ Bt,
              int Kin, int Kout, int idx)
{
  int n = idx / Kout, k = idx - n * Kout;
  Bt[idx] = f2b(k < Kin ? W[(size_t)n * Kin + k] : 0.f);
}

#define SZ_CH   147456   // 256*64*9
#define SZ_QKV  589824   // 256*256*9
#define SZ_OFF1 204800   // 256*32*25
#define SZ_OFF2 25088    // 98*256
#define SZ_C1   32768    // 256*128
#define SZ_C2   12544    // 49*256
#define SZ_WI1  3219456  // 256*12576
#define SZ_PACK (SZ_CH + 3*SZ_QKV + SZ_OFF1 + SZ_OFF2 + SZ_C1 + SZ_C2 + 768 + SZ_WI1)
#define CONV_BLKS 1024   // 4096 pixels, 4 per 256-thread block

__global__ __launch_bounds__(256)
void pack_enc(const float* W_ch, const float* W_q, const float* W_k,
              const float* W_v, const float* W_off1, const float* W_off2,
              const float* Wc1, const float* Wc2, const float* Wi1,
              const float* b_q, const float* b_k, const float* b_v,
              u16* Btch, u16* Btqkv, u16* Btoff1, u16* Btoff2,
              u16* Btc1, u16* Btc2, u16* Wi1p, float* bqkv,
              const float* __restrict__ inp, const float* __restrict__ W_enc,
              const float* __restrict__ b_enc, u16* __restrict__ feat1)
{
  const int bid = blockIdx.x;
  const int tid = threadIdx.x;
  if (bid < CONV_BLKS) {
    // ----- encoder conv: 3->64, 3x3 pad1, +bias, relu -----
    const int p = bid * 4 + (tid >> 6), c = tid & 63;
    const int y = p >> 6, x = p & 63;
    float s = b_enc[c];
    #pragma unroll
    for (int ci = 0; ci < 3; ci++)
      #pragma unroll
      for (int dy = 0; dy < 3; dy++) {
        int yy = y + dy - 1;
        if ((unsigned)yy >= 64u) continue;
        #pragma unroll
        for (int dx = 0; dx < 3; dx++) {
          int xx = x + dx - 1;
          if ((unsigned)xx >= 64u) continue;
          s += inp[ci * HW + yy * 64 + xx] * W_enc[((c * 3 + ci) * 3 + dy) * 3 + dx];
        }
      }
    feat1[(size_t)p * 64 + c] = f2b(fmaxf(s, 0.f));
    return;
  }
  int i = (bid - CONV_BLKS) * 256 + tid;
  if (i < SZ_CH) { packconv(W_ch, Btch, 64, 9, i); return; }
  i -= SZ_CH;
  if (i < SZ_QKV) { packconv(W_q, Btqkv, 256, 9, i); return; }
  i -= SZ_QKV;
  if (i < SZ_QKV) { packconv(W_k, Btqkv + (size_t)256 * 2304, 256, 9, i); return; }
  i -= SZ_QKV;
  if (i < SZ_QKV) { packconv(W_v, Btqkv + (size_t)512 * 2304, 256, 9, i); return; }
  i -= SZ_QKV;
  if (i < SZ_OFF1) { packconv(W_off1, Btoff1, 32, 25, i); return; }
  i -= SZ_OFF1;
  if (i < SZ_OFF2) { packcast(W_off2, Btoff2, 256, 256, i); return; }
  i -= SZ_OFF2;
  if (i < SZ_C1) { packcast(Wc1, Btc1, 98, 128, i); return; }
  i -= SZ_C1;
  if (i < SZ_C2) { packcast(Wc2, Btc2, 256, 256, i); return; }
  i -= SZ_C2;
  if (i < 768) {
    bqkv[i] = (i < 256) ? b_q[i] : (i < 512) ? b_k[i - 256] : b_v[i - 512];
    return;
  }
  i -= 768;
  if (i < SZ_WI1) { packcast(Wi1, Wi1p, 12546, 12576, i); }
}

// ---------------------------------------------------------------------------
// Per-query sampler (writes raw q.k dots to attnval; softmax_k finalizes).
// ---------------------------------------------------------------------------
__global__ __launch_bounds__(256)
void sampler(const float* __restrict__ coord, const u16* __restrict__ fqkvb,
             const float* __restrict__ offs, const float* __restrict__ inp,
             float* __restrict__ attnval, u16* __restrict__ relbuf,
             int* __restrict__ vidx, float* __restrict__ skipb)
{
  const int q = blockIdx.x;
  const int tid = threadIdx.x;
  __shared__ float s_off[98];
  __shared__ int s_idx[49];
  __shared__ float s_q[256];

  const float c0 = coord[q * 2], c1 = coord[q * 2 + 1];
  const float gxp = ((c1 + 1.f) * 64.f - 1.f) * 0.5f;
  const float gyp = ((c0 + 1.f) * 64.f - 1.f) * 0.5f;
  const int ixn = (int)rintf(gxp), iyn = (int)rintf(gyp);
  const bool inn = ((unsigned)ixn < 64u) && ((unsigned)iyn < 64u);

  if (tid < 98) {
    float v = inn ? offs[(size_t)(iyn * 64 + ixn) * 98 + tid] : 0.f;
    s_off[tid] = tanhf(v) * (2.f / 63.f);
  }
  __syncthreads();

  const float scky = inn ? (-1.f + (float)(2 * iyn + 1) * (1.f / 64.f)) : 0.f;
  const float sckx = inn ? (-1.f + (float)(2 * ixn + 1) * (1.f / 64.f)) : 0.f;

  if (tid < 49) {
    const int a = tid / 7, bb = tid - a * 7;
    float sy = scky + (float)(a - 3) * (2.f / 64.f) + s_off[2 * tid];
    float sx = sckx + (float)(bb - 3) * (2.f / 64.f) + s_off[2 * tid + 1];
    relbuf[(size_t)q * 128 + 2 * tid]     = f2b((c0 - sy) * 64.f);
    relbuf[(size_t)q * 128 + 2 * tid + 1] = f2b((c1 - sx) * 64.f);
    float gx2 = ((sx + 1.f) * 64.f - 1.f) * 0.5f;
    float gy2 = ((sy + 1.f) * 64.f - 1.f) * 0.5f;
    int ix2 = (int)rintf(gx2), iy2 = (int)rintf(gy2);
    int id = (((unsigned)ix2 < 64u) && ((unsigned)iy2 < 64u)) ? (iy2 * 64 + ix2) : -1;
    s_idx[tid] = id;
    vidx[q * 49 + tid] = id;
  } else if (tid >= 98 && tid < 128) {
    relbuf[(size_t)q * 128 + tid] = 0;
  }

  {
    const float x0f = floorf(gxp), y0f = floorf(gyp);
    const float wx = gxp - x0f, wy = gyp - y0f;
    const int x0 = (int)x0f, y0 = (int)y0f;
    float qc = 0.f;
    #pragma unroll
    for (int t = 0; t < 4; t++) {
      int xi = x0 + (t & 1), yi = y0 + (t >> 1);
      if (((unsigned)xi < 64u) && ((unsigned)yi < 64u)) {
        float w = ((t & 1) ? wx : 1.f - wx) * ((t >> 1) ? wy : 1.f - wy);
        qc += w * b2f(fqkvb[(size_t)(yi * 64 + xi) * 768 + tid]);
      }
    }
    s_q[tid] = qc * 0.17677669529663687f;
  }

  if (tid < 3) {
    float gx = fminf(fmaxf(gxp, 0.f), 63.f);
    float gy = fminf(fmaxf(gyp, 0.f), 63.f);
    float xf = floorf(gx), yf = floorf(gy);
    float wxs = gx - xf, wys = gy - yf;
    int xa = (int)xf, ya = (int)yf;
    int xb = min(xa + 1, 63), yb = min(ya + 1, 63);
    const float* ch = inp + tid * HW;
    float v = (1.f - wxs) * (1.f - wys) * ch[ya * 64 + xa]
            + wxs * (1.f - wys) * ch[ya * 64 + xb]
            + (1.f - wxs) * wys * ch[yb * 64 + xa]
            + wxs * wys * ch[yb * 64 + xb];
    skipb[q * 3 + tid] = v;
  }
  __syncthreads();

  const int wave = tid >> 6, lane = tid & 63;
  const int half = lane >> 5, sub = lane & 31;
  const int ch0 = sub * 8;
  const int h = sub >> 2;
  float qv[8];
  #pragma unroll
  for (int i = 0; i < 8; i++) qv[i] = s_q[ch0 + i];

  for (int it = 0; it < 7; it++) {
    int j = it * 8 + wave * 2 + half;
    if (j >= 49) break;
    int id = s_idx[j];
    float p = 0.f;
    if (id >= 0) {
      uint4 kv = *(const uint4*)&fqkvb[(size_t)id * 768 + 256 + ch0];
      u32 w0 = kv.x, w1 = kv.y, w2 = kv.z, w3 = kv.w;
      p = fmaf(qv[0], __uint_as_float(w0 << 16), p);
      p = fmaf(qv[1], __uint_as_float(w0 & 0xffff0000u), p);
      p = fmaf(qv[2], __uint_as_float(w1 << 16), p);
      p = fmaf(qv[3], __uint_as_float(w1 & 0xffff0000u), p);
      p = fmaf(qv[4], __uint_as_float(w2 << 16), p);
      p = fmaf(qv[5], __uint_as_float(w2 & 0xffff0000u), p);
      p = fmaf(qv[6], __uint_as_float(w3 << 16), p);
      p = fmaf(qv[7], __uint_as_float(w3 & 0xffff0000u), p);
    }
    p += __shfl_down(p, 2, 4);
    p += __shfl_down(p, 1, 4);
    if ((sub & 3) == 0) attnval[((size_t)q * 49 + j) * 8 + h] = p;
  }
}

// ===========================================================================
extern "C" void kernel_launch(void* const* d_in, const int* in_sizes, int n_in,
                              void* d_out, int out_size, void* d_ws, size_t ws_size,
                              hipStream_t stream)
{
  const float* inp    = (const float*)d_in[0];
  const float* coord  = (const float*)d_in[1];
  const float* cell   = (const float*)d_in[2];
  const float* W_enc  = (const float*)d_in[3];
  const float* b_enc  = (const float*)d_in[4];
  const float* W_ch   = (const float*)d_in[5];
  const float* b_ch   = (const float*)d_in[6];
  const float* W_q    = (const float*)d_in[7];
  const float* b_q    = (const float*)d_in[8];
  const float* W_k    = (const float*)d_in[9];
  const float* b_k    = (const float*)d_in[10];
  const float* W_v    = (const float*)d_in[11];
  const float* b_v    = (const float*)d_in[12];
  const float* W_off1 = (const float*)d_in[13];
  const float* b_off1 = (const float*)d_in[14];
  const float* ln_g   = (const float*)d_in[15];
  const float* ln_b   = (const float*)d_in[16];
  const float* W_off2 = (const float*)d_in[17];
  const float* Wc1    = (const float*)d_in[18];
  const float* bc1    = (const float*)d_in[19];
  const float* Wc2    = (const float*)d_in[20];
  const float* bc2    = (const float*)d_in[21];
  const float* Wi1    = (const float*)d_in[22];
  const float* bi1    = (const float*)d_in[23];
  const float* Wi2    = (const float*)d_in[24];
  const float* bi2    = (const float*)d_in[25];

  char* base = (char*)d_ws;
  size_t off = 0;
  auto alloc = [&](size_t bytes) -> char* {
    char* r = base + off;
    off = (off + bytes + 255) & ~(size_t)255;
    return r;
  };

  // --- scratch region (dead before gemm_big runs; Pb aliases it) ---
  float* obuf   = (float*)alloc((size_t)HW * 256 * 4);
  u16*   ocg    = (u16*)  alloc((size_t)HW * 256 * 2);
  float* offsb  = (float*)alloc((size_t)HW * 98 * 4);
  u16*   feat1  = (u16*)  alloc((size_t)HW * 64 * 2);
  u16*   feat   = (u16*)  alloc((size_t)HW * 256 * 2);
  u16*   hid1   = (u16*)  alloc((size_t)NQ * 256 * 2);
  float* wcb    = (float*)alloc((size_t)NQ * 49 * 4);
  u16*   relbuf = (u16*)  alloc((size_t)NQ * 128 * 2);
  u16*   Btqkv  = (u16*)  alloc((size_t)768 * 2304 * 2);
  u16*   Btch   = (u16*)  alloc((size_t)256 * 576 * 2);
  u16*   Btoff1 = (u16*)  alloc((size_t)256 * 800 * 2);
  u16*   Btoff2 = (u16*)  alloc((size_t)98 * 256 * 2);
  u16*   Btc1   = (u16*)  alloc((size_t)256 * 128 * 2);
  u16*   Btc2   = (u16*)  alloc((size_t)49 * 256 * 2);
  // gemm_big bf16 partials alias scratch: 16 x 2MB = 33.6MB at base+0.
  u16* Pb = (u16*)base;
  // qkv bf16 partials at [36MB, 54.9MB): past live scratch (~19MB),
  // disjoint from Pb's 33.6MB, dead before gemm_big.
  u16* Pqb = (u16*)(base + ((size_t)36 << 20));
  {
    size_t need = ((size_t)36 << 20) + (size_t)QSPLIT * NQ * 768 * 2;
    if (off < need) off = (need + 255) & ~(size_t)255;
  }
  // --- persistent buffers ---
  u16*   fqkvb   = (u16*)  alloc((size_t)HW * 768 * 2);
  u16*   fqkvVb  = (u16*)  alloc((size_t)HW * 256 * 2);
  float* attnval = (float*)alloc((size_t)NQ * 49 * 8 * 4);
  int*   vidxb   = (int*)  alloc((size_t)NQ * 49 * 4);
  float* skipb   = (float*)alloc((size_t)NQ * 3 * 4);
  u16*   Wi1p    = (u16*)  alloc((size_t)256 * KBIG * 2);
  float* bqkv    = (float*)alloc(768 * 4);
  (void)ws_size; (void)in_sizes; (void)n_in; (void)out_size;

  // --- weight packing ∥ encoder conv (merged: both input-only) ---
  pack_enc<<<CONV_BLKS + (SZ_PACK + 255) / 256, 256, 0, stream>>>(
      W_ch, W_q, W_k, W_v, W_off1, W_off2, Wc1, Wc2, Wi1, b_q, b_k, b_v,
      Btch, Btqkv, Btoff1, Btoff2, Btc1, Btc2, Wi1p, bqkv,
      inp, W_enc, b_enc, feat1);

  // --- conv stack ---
  gemm_conv<3, 6, 1><<<dim3(64, 4, 1), 256, 0, stream>>>(
      feat1, Btch, feat, b_ch, 256, 576, 256, /*bf16*/2, 64, 0, 0, 0, 0);
  // merged qkv + off1 (overlap)
  gemm_feat<<<NBLK_QKV + NBLK_OFF1, 256, 0, stream>>>(
      feat, Btqkv, Pqb, Btoff1, obuf, b_off1);
  // merged reduce_qkv ∥ ln_gelu (both depend only on gemm_feat)
  post_feat<<<RQ_BLKS + HW, 256, 0, stream>>>(
      Pqb, bqkv, fqkvb, fqkvVb, obuf, ln_g, ln_b, ocg);
  gemm_bt<<<dim3(64, 2, 1), 256, 0, stream>>>(ocg, Btoff2, offsb, nullptr,
      98, 256, 98, 0, 0, 0, 0, 0);

  // --- per-query attention path ---
  sampler<<<NQ, 256, 0, stream>>>(coord, fqkvb, offsb, inp,
                                  attnval, relbuf, vidxb, skipb);
  gemm_bt<<<dim3(64, 4, 1), 256, 0, stream>>>(relbuf, Btc1, hid1, bc1,
      256, 128, 256, /*relu+bf16*/3, 0, 0, 0, 0);
  gemm_bt<<<dim3(64, 1, 1), 256, 0, stream>>>(hid1, Btc2, wcb, bc2,
      49, 256, 49, 0, 0, 0, 0, 0);
  softmax_k<<<NQ, 512, 0, stream>>>(wcb, attnval);

  // --- big MLP: 128x256 tile, bf16 gather-A, dbuf glds-B + counted vmcnt,
  //     split-K(16), bf16 partials ---
  gemm_big<<<dim3(32, SPLITK), 512, 0, stream>>>(
      Wi1p, fqkvVb, attnval, vidxb, cell, Pb);
  reduce_final<<<NQ, 256, 0, stream>>>(Pb, bi1, Wi2, bi2, skipb, (float*)d_out);
}

// Round 8
// 268.361 us; speedup vs baseline: 1.1435x; 1.0249x over previous
//
#include <hip/hip_runtime.h>
#include <hip/hip_bf16.h>

// ============================================================================
// IDASR pipeline on gfx950 — round 22.
// r21 post-mortem: launch-merge of independent kernels gained 6us (275.0,
// best). Continue compressing the serial launch chain.
// Change (single structural variable): the attention-weight chain
// gemm_bt(c1) -> gemm_bt(c2) -> softmax_k (3 launches + hid1/wcb glue
// buffers) is FUSED into one MFMA kernel attn_wc (grid 256 x 16 q-rows):
//  * c1: 16x256x128 MFMA, A=rel tile in LDS, B-frags direct from L2-hot
//    Btc1 (no staging/barrier; r19's failure was scalar loads in a
//    latency-bound per-q block — here the GEMM structure is preserved).
//  * c2: 16x64x256 MFMA on block-local hid (bf16 in LDS, same rounding as
//    the old hid1 path); Btc2 zero-padded to 64 rows at pack time.
//  * softmax: thread-local per (q,h) pair, register v[49] (same math).
// 11 -> 9 launches, -5.6MB glue traffic. Everything else r21-identical.
// ============================================================================

typedef unsigned short u16;
typedef unsigned int u32;
using frag_ab = __attribute__((ext_vector_type(8))) short;  // 8 x bf16
using frag_cd = __attribute__((ext_vector_type(4))) float;  // 4 x f32 acc

#define HW 4096
#define NQ 4096
#define KBIG 12576
#define SPLITK 16
#define KCHUNK 800
#define JMAX 5
#define KQ 2304
#define QSPLIT 3
#define QCHUNK 768
#define NBLK_QKV (64 * 6 * QSPLIT)   // 1152
#define NBLK_OFF1 (64 * 8)           // 512

static __device__ __forceinline__ u16 f2b(float f) {
  union { __hip_bfloat16 h; u16 u; } c; c.h = __float2bfloat16(f); return c.u;
}
static __device__ __forceinline__ float b2f(u16 v) {
  return __uint_as_float((u32)v << 16);
}
static __device__ __forceinline__ u32 pk2(float a, float b) {
  union { __hip_bfloat162 h; u32 u; } c;
  c.h = __float22bfloat162_rn(float2{a, b});
  return c.u;
}
// async global->LDS, 16B per lane. LDS dest is wave-uniform base + lane*16.
static __device__ __forceinline__ void glds16(const u16* g, u16* l) {
  __builtin_amdgcn_global_load_lds(
      (const __attribute__((address_space(1))) u32*)(g),
      (__attribute__((address_space(3))) u32*)(l), 16, 0, 0);
}

#define BM 64
#define BN 64
#define BK 32
#define LDSS 40   // padded lds row stride for reg-staged tiles

// ---------------------------------------------------------------------------
// Generic bf16 GEMM (64x64 tile): off2 layer only now.
// ---------------------------------------------------------------------------
__global__ __launch_bounds__(256)
void gemm_bt(const u16* __restrict__ A, const u16* __restrict__ Bt,
             void* __restrict__ Cv, const float* __restrict__ bias,
             int N, int K, int ldc, int flags,   // 1=relu, 2=bf16 out
             long sA, long sB, long sC, int sBias)
{
  __shared__ u16 As[BM * LDSS];
  __shared__ u16 Bs[BN * LDSS];
  const int z = blockIdx.z;
  A  += (long)z * sA;
  Bt += (long)z * sB;
  const float* bz = bias ? bias + (long)z * sBias : nullptr;

  const int tid  = threadIdx.x;
  const int m0   = blockIdx.x * BM;
  const int n0   = blockIdx.y * BN;
  const int wave = tid >> 6, lane = tid & 63;
  const int mw = (wave & 1) * 32, nw = (wave >> 1) * 32;
  const int lr = lane & 15, lk = lane >> 4;
  const int srow = tid >> 2, scol = (tid & 3) * 8;

  frag_cd acc[2][2] = {};
  const u16* aptr = A + (size_t)(m0 + srow) * K + scol;
  const bool bok  = (n0 + srow) < N;
  const u16* bptr = Bt + (size_t)(n0 + srow) * K + scol;

  uint4 av = *(const uint4*)(aptr);
  uint4 bv = bok ? *(const uint4*)(bptr) : uint4{0u, 0u, 0u, 0u};

  for (int k0 = 0; k0 < K; k0 += BK) {
    *(uint4*)&As[srow * LDSS + scol] = av;
    *(uint4*)&Bs[srow * LDSS + scol] = bv;
    __syncthreads();
    if (k0 + BK < K) {
      av = *(const uint4*)(aptr + k0 + BK);
      bv = bok ? *(const uint4*)(bptr + k0 + BK) : uint4{0u, 0u, 0u, 0u};
    }
    frag_ab af0 = *(const frag_ab*)&As[(mw      + lr) * LDSS + lk * 8];
    frag_ab af1 = *(const frag_ab*)&As[(mw + 16 + lr) * LDSS + lk * 8];
    frag_ab bf0 = *(const frag_ab*)&Bs[(nw      + lr) * LDSS + lk * 8];
    frag_ab bf1 = *(const frag_ab*)&Bs[(nw + 16 + lr) * LDSS + lk * 8];
    acc[0][0] = __builtin_amdgcn_mfma_f32_16x16x32_bf16(af0, bf0, acc[0][0], 0, 0, 0);
    acc[0][1] = __builtin_amdgcn_mfma_f32_16x16x32_bf16(af0, bf1, acc[0][1], 0, 0, 0);
    acc[1][0] = __builtin_amdgcn_mfma_f32_16x16x32_bf16(af1, bf0, acc[1][0], 0, 0, 0);
    acc[1][1] = __builtin_amdgcn_mfma_f32_16x16x32_bf16(af1, bf1, acc[1][1], 0, 0, 0);
    __syncthreads();
  }

  const bool relu = flags & 1;
  const bool obf  = flags & 2;
  #pragma unroll
  for (int i = 0; i < 2; i++)
    #pragma unroll
    for (int j = 0; j < 2; j++) {
      int col = n0 + nw + j * 16 + lr;
      if (col >= N) continue;
      float badd = bz ? bz[col] : 0.f;
      #pragma unroll
      for (int r = 0; r < 4; r++) {
        int row = m0 + mw + i * 16 + lk * 4 + r;
        float v = acc[i][j][r] + badd;
        if (relu) v = fmaxf(v, 0.f);
        size_t idx = (size_t)z * sC + (size_t)row * ldc + col;
        if (obf) ((u16*)Cv)[idx] = f2b(v);
        else     ((float*)Cv)[idx] = v;
      }
    }
}

// ---------------------------------------------------------------------------
// Implicit-im2col conv GEMM, 64x64 tile (ch conv only now).
// ---------------------------------------------------------------------------
template<int W3, int SH, int PAD>
__global__ __launch_bounds__(256)
void gemm_conv(const u16* __restrict__ feat, const u16* __restrict__ Bt,
               void* __restrict__ Cv, const float* __restrict__ bias,
               int N, int K, int ldc, int flags, int FC, int cbStride,
               long sB, long sC, int sBias)
{
  __shared__ u16 As[BM * LDSS];
  __shared__ u16 Bs[BN * LDSS];
  const int z = blockIdx.z;
  Bt += (long)z * sB;
  const float* bz = bias ? bias + (long)z * sBias : nullptr;
  const int cb = z * cbStride;

  const int tid  = threadIdx.x;
  const int m0   = blockIdx.x * BM;
  const int n0   = blockIdx.y * BN;
  const int wave = tid >> 6, lane = tid & 63;
  const int mw = (wave & 1) * 32, nw = (wave >> 1) * 32;
  const int lr = lane & 15, lk = lane >> 4;
  const int srow = tid >> 2, scol = (tid & 3) * 8;
  const int p = m0 + srow, y = p >> 6, x = p & 63;

  frag_cd acc[2][2] = {};
  const bool bok  = (n0 + srow) < N;
  const u16* bptr = Bt + (size_t)(n0 + srow) * K + scol;

  auto stageA = [&](int k0) -> uint4 {
    int k = k0 + scol;
    int s = k >> SH;
    int c = k & ((1 << SH) - 1);
    int dy = s / W3, dx = s - dy * W3;
    int yy = y + dy - PAD, xx = x + dx - PAD;
    if (((unsigned)yy < 64u) && ((unsigned)xx < 64u))
      return *(const uint4*)&feat[(size_t)(yy * 64 + xx) * FC + cb + c];
    return uint4{0u, 0u, 0u, 0u};
  };

  uint4 av = stageA(0);
  uint4 bv = bok ? *(const uint4*)(bptr) : uint4{0u, 0u, 0u, 0u};

  for (int k0 = 0; k0 < K; k0 += BK) {
    *(uint4*)&As[srow * LDSS + scol] = av;
    *(uint4*)&Bs[srow * LDSS + scol] = bv;
    __syncthreads();
    if (k0 + BK < K) {
      av = stageA(k0 + BK);
      bv = bok ? *(const uint4*)(bptr + k0 + BK) : uint4{0u, 0u, 0u, 0u};
    }
    frag_ab af0 = *(const frag_ab*)&As[(mw      + lr) * LDSS + lk * 8];
    frag_ab af1 = *(const frag_ab*)&As[(mw + 16 + lr) * LDSS + lk * 8];
    frag_ab bf0 = *(const frag_ab*)&Bs[(nw      + lr) * LDSS + lk * 8];
    frag_ab bf1 = *(const frag_ab*)&Bs[(nw + 16 + lr) * LDSS + lk * 8];
    acc[0][0] = __builtin_amdgcn_mfma_f32_16x16x32_bf16(af0, bf0, acc[0][0], 0, 0, 0);
    acc[0][1] = __builtin_amdgcn_mfma_f32_16x16x32_bf16(af0, bf1, acc[0][1], 0, 0, 0);
    acc[1][0] = __builtin_amdgcn_mfma_f32_16x16x32_bf16(af1, bf0, acc[1][0], 0, 0, 0);
    acc[1][1] = __builtin_amdgcn_mfma_f32_16x16x32_bf16(af1, bf1, acc[1][1], 0, 0, 0);
    __syncthreads();
  }

  const bool relu = flags & 1;
  const bool obf  = flags & 2;
  #pragma unroll
  for (int i = 0; i < 2; i++)
    #pragma unroll
    for (int j = 0; j < 2; j++) {
      int col = n0 + nw + j * 16 + lr;
      if (col >= N) continue;
      float badd = bz ? bz[col] : 0.f;
      #pragma unroll
      for (int r = 0; r < 4; r++) {
        int row = m0 + mw + i * 16 + lk * 4 + r;
        float v = acc[i][j][r] + badd;
        if (relu) v = fmaxf(v, 0.f);
        size_t idx = (size_t)z * sC + (size_t)row * ldc + col;
        if (obf) ((u16*)Cv)[idx] = f2b(v);
        else     ((float*)Cv)[idx] = v;
      }
    }
}

// ---------------------------------------------------------------------------
// Merged feat-consumer kernel: blocks [0,1152) = qkv GEMM (64x128 tile,
// implicit im2col A, glds-B, split-K(3), bf16 partials); blocks
// [1152,1664) = grouped 5x5 off1 conv (64x64 tile). One launch -> overlap.
// ---------------------------------------------------------------------------
__global__ __launch_bounds__(256)
void gemm_feat(const u16* __restrict__ feat, const u16* __restrict__ Btqkv,
               u16* __restrict__ Pq, const u16* __restrict__ Btoff1,
               float* __restrict__ obuf, const float* __restrict__ b_off1)
{
  __shared__ u16 smem[6656];   // 13.3 KB: qkv As(2560)+Bs(4096); off1 uses 5120
  const int bid = blockIdx.x;
  const int tid = threadIdx.x;
  const int wave = tid >> 6, lane = tid & 63;
  const int lr = lane & 15, lk = lane >> 4;

  if (bid < NBLK_QKV) {
    // ----- qkv branch -----
    u16* As = smem;            // 64 * 40
    u16* Bs = smem + 64 * 40;  // 128 * 32, glds target
    const int mz  = bid & 63;
    const int rest = bid >> 6;
    const int ny  = rest % 6;
    const int z   = rest / 6;
    const int m0  = mz * 64;
    const int n0  = ny * 128;
    const int kbeg = z * QCHUNK;
    const int kend = kbeg + QCHUNK;
    const int nw = wave * 32;
    const int arow = tid >> 2, acol = (tid & 3) * 8;
    const int p = m0 + arow, y = p >> 6, x = p & 63;

    frag_cd acc[4][2] = {};
    const u16* bbase = Btqkv + (size_t)(n0 + (tid >> 2)) * KQ + (tid & 3) * 8 + kbeg;
    u16* bdst = &Bs[(size_t)tid * 8];

    auto stageA = [&](int k0) -> uint4 {
      int k = k0 + acol;
      int s = k >> 8, c = k & 255;
      int dy = s / 3, dx = s - dy * 3;
      int yy = y + dy - 1, xx = x + dx - 1;
      if (((unsigned)yy < 64u) && ((unsigned)xx < 64u))
        return *(const uint4*)&feat[(size_t)(yy * 64 + xx) * 256 + c];
      return uint4{0u, 0u, 0u, 0u};
    };

    uint4 av = stageA(kbeg);

    for (int k0 = kbeg; k0 < kend; k0 += BK) {
      glds16(bbase + (k0 - kbeg), bdst);
      glds16(bbase + (k0 - kbeg) + (size_t)64 * KQ, bdst + 2048);
      *(uint4*)&As[arow * LDSS + acol] = av;
      __syncthreads();
      if (k0 + BK < kend) av = stageA(k0 + BK);
      frag_ab af[4];
      #pragma unroll
      for (int i = 0; i < 4; i++)
        af[i] = *(const frag_ab*)&As[(i * 16 + lr) * LDSS + lk * 8];
      #pragma unroll
      for (int j = 0; j < 2; j++) {
        frag_ab bf = *(const frag_ab*)&Bs[(nw + j * 16 + lr) * 32 + lk * 8];
        #pragma unroll
        for (int i = 0; i < 4; i++)
          acc[i][j] = __builtin_amdgcn_mfma_f32_16x16x32_bf16(af[i], bf, acc[i][j], 0, 0, 0);
      }
      __syncthreads();
    }

    #pragma unroll
    for (int i = 0; i < 4; i++)
      #pragma unroll
      for (int j = 0; j < 2; j++) {
        int col = n0 + nw + j * 16 + lr;
        #pragma unroll
        for (int r = 0; r < 4; r++) {
          int row = m0 + i * 16 + lk * 4 + r;
          Pq[(size_t)z * (NQ * 768) + (size_t)row * 768 + col] = f2b(acc[i][j][r]);
        }
      }
  } else {
    // ----- off1 grouped conv branch (5x5 pad2, 32 ch/group) -----
    u16* As = smem;            // 64 * 40
    u16* Bs = smem + 64 * 40;  // 64 * 40
    const int t  = bid - NBLK_QKV;
    const int m0 = (t & 63) * 64;
    const int g  = t >> 6;               // group 0..7
    const int cb = g * 32;
    const u16* Bt = Btoff1 + (size_t)g * 32 * 800;
    const float* bz = b_off1 + g * 32;
    const int mw = (wave & 1) * 32, nw = (wave >> 1) * 32;
    const int srow = tid >> 2, scol = (tid & 3) * 8;
    const int p = m0 + srow, y = p >> 6, x = p & 63;

    frag_cd acc[2][2] = {};
    const bool bok  = srow < 32;
    const u16* bptr = Bt + (size_t)srow * 800 + scol;

    auto stageA = [&](int k0) -> uint4 {
      int k = k0 + scol;
      int s = k >> 5;
      int c = k & 31;
      int dy = s / 5, dx = s - dy * 5;
      int yy = y + dy - 2, xx = x + dx - 2;
      if (((unsigned)yy < 64u) && ((unsigned)xx < 64u))
        return *(const uint4*)&feat[(size_t)(yy * 64 + xx) * 256 + cb + c];
      return uint4{0u, 0u, 0u, 0u};
    };

    uint4 av = stageA(0);
    uint4 bv = bok ? *(const uint4*)(bptr) : uint4{0u, 0u, 0u, 0u};

    for (int k0 = 0; k0 < 800; k0 += BK) {
      *(uint4*)&As[srow * LDSS + scol] = av;
      *(uint4*)&Bs[srow * LDSS + scol] = bv;
      __syncthreads();
      if (k0 + BK < 800) {
        av = stageA(k0 + BK);
        bv = bok ? *(const uint4*)(bptr + k0 + BK) : uint4{0u, 0u, 0u, 0u};
      }
      frag_ab af0 = *(const frag_ab*)&As[(mw      + lr) * LDSS + lk * 8];
      frag_ab af1 = *(const frag_ab*)&As[(mw + 16 + lr) * LDSS + lk * 8];
      frag_ab bf0 = *(const frag_ab*)&Bs[(nw      + lr) * LDSS + lk * 8];
      frag_ab bf1 = *(const frag_ab*)&Bs[(nw + 16 + lr) * LDSS + lk * 8];
      acc[0][0] = __builtin_amdgcn_mfma_f32_16x16x32_bf16(af0, bf0, acc[0][0], 0, 0, 0);
      acc[0][1] = __builtin_amdgcn_mfma_f32_16x16x32_bf16(af0, bf1, acc[0][1], 0, 0, 0);
      acc[1][0] = __builtin_amdgcn_mfma_f32_16x16x32_bf16(af1, bf0, acc[1][0], 0, 0, 0);
      acc[1][1] = __builtin_amdgcn_mfma_f32_16x16x32_bf16(af1, bf1, acc[1][1], 0, 0, 0);
      __syncthreads();
    }

    #pragma unroll
    for (int i = 0; i < 2; i++)
      #pragma unroll
      for (int j = 0; j < 2; j++) {
        int col = nw + j * 16 + lr;
        if (col >= 32) continue;
        float badd = bz[col];
        #pragma unroll
        for (int r = 0; r < 4; r++) {
          int row = m0 + mw + i * 16 + lk * 4 + r;
          obuf[(size_t)row * 256 + g * 32 + col] = acc[i][j][r] + badd;
        }
      }
  }
}

// ---------------------------------------------------------------------------
// Merged post-gemm_feat kernel: blocks [0,1536) = reduce_qkv; blocks
// [1536, 1536+4096) = ln_gelu. Both depend only on gemm_feat.
// ---------------------------------------------------------------------------
#define RQ_BLKS 1536   // NQ*96/256
__global__ __launch_bounds__(256)
void post_feat(const u16* __restrict__ P, const float* __restrict__ bias,
               u16* __restrict__ outb, u16* __restrict__ outV,
               const float* __restrict__ x, const float* __restrict__ g,
               const float* __restrict__ b, u16* __restrict__ y)
{
  const int bid = blockIdx.x;
  const int tid = threadIdx.x;
  if (bid < RQ_BLKS) {
    // ----- reduce_qkv -----
    int i8 = bid * 256 + tid;
    size_t i = (size_t)i8 * 8;
    int row = (int)(i / 768);
    int c = (int)(i % 768);
    float v[8];
    #pragma unroll
    for (int t = 0; t < 8; t++) v[t] = bias[c + t];
    for (int z = 0; z < QSPLIT; z++) {
      uint4 a = *(const uint4*)&P[(size_t)z * (NQ * 768) + i];
      u32 aw[4] = {a.x, a.y, a.z, a.w};
      #pragma unroll
      for (int t = 0; t < 4; t++) {
        v[2 * t]     += __uint_as_float(aw[t] << 16);
        v[2 * t + 1] += __uint_as_float(aw[t] & 0xffff0000u);
      }
    }
    uint4 ob = {pk2(v[0], v[1]), pk2(v[2], v[3]), pk2(v[4], v[5]), pk2(v[6], v[7])};
    *(uint4*)&outb[i] = ob;
    if (c >= 512) {
      // bf16 V gather table: dense 2 MB (pos,256) layout for gemm_big.
      *(uint4*)&outV[(size_t)row * 256 + (c - 512)] = ob;
    }
  } else {
    // ----- ln_gelu -----
    const int p = bid - RQ_BLKS, c = tid;
    __shared__ float r1[4], r2[4];
    float v = x[(size_t)p * 256 + c];
    float s1 = v, s2 = v * v;
    #pragma unroll
    for (int off = 32; off; off >>= 1) {
      s1 += __shfl_xor(s1, off);
      s2 += __shfl_xor(s2, off);
    }
    if ((c & 63) == 0) { r1[c >> 6] = s1; r2[c >> 6] = s2; }
    __syncthreads();
    float t1 = r1[0] + r1[1] + r1[2] + r1[3];
    float t2 = r2[0] + r2[1] + r2[2] + r2[3];
    float mu  = t1 * (1.f / 256.f);
    float var = t2 * (1.f / 256.f) - mu * mu;
    float xn = (v - mu) * rsqrtf(var + 1e-5f) * g[c] + b[c];
    float ge = 0.5f * xn * (1.f + erff(xn * 0.70710678118654752f));
    y[(size_t)p * 256 + c] = f2b(ge);
  }
}

// ---------------------------------------------------------------------------
// Big MLP GEMM: fused gather-A (bf16 V, weight-mul + repack), 128x256 tile,
// double-buffered glds-B with counted-vmcnt pipeline, split-K(16), bf16
// partials. block 512 (8 waves), grid (32, 16) = 2/CU (reg-capped: ~60 VGPR
// + 64 AGPR unified; (512,4) — do NOT raise min-waves, r15 spilled).
// r16 version (proven best pipeline).
// ---------------------------------------------------------------------------
__global__ __launch_bounds__(512, 4)
void gemm_big(const u16* __restrict__ Bt, const u16* __restrict__ fqkvV,
              const float* __restrict__ attnval, const int* __restrict__ vidx,
              const float* __restrict__ cell, u16* __restrict__ P)
{
  __shared__ u16 As[128 * LDSS];            // 10 KB padded, reg-staged gather
  __shared__ u16 Bs[2 * 256 * 32];          // 32 KB double-buffered glds target
  __shared__ short s_vidx[JMAX * 128];      // 1.25 KB (ids < 4096 fit short)
  __shared__ float s_attn[JMAX * 128 * 8];  // 20 KB
  const int tid  = threadIdx.x;
  const int m0   = blockIdx.x * 128;
  const int z    = blockIdx.y;
  const int kbeg = z * KCHUNK;
  const int kend = min(KBIG, kbeg + KCHUNK);
  const int jbeg = kbeg >> 8;
  const int jcnt = ((kend - 1) >> 8) - jbeg + 1;   // <= 5
  const int wave = tid >> 6, lane = tid & 63;
  const int mw = (wave & 1) * 64, nwv = (wave >> 1) * 64;
  const int lr = lane & 15, lk = lane >> 4;
  const int arow = tid >> 2, acol = (tid & 3) * 8;  // 128 rows x 4x8
  const int q = m0 + arow;

  for (int t = tid; t < 128 * jcnt; t += 512) {
    int r = t & 127, jj = t >> 7;
    int j = jbeg + jj;
    s_vidx[t] = (short)((j < 49) ? vidx[(m0 + r) * 49 + j] : -1);
  }
  for (int t = tid; t < 128 * 8 * jcnt; t += 512) {
    int h = t & 7, rr = (t >> 3) & 127, jj = t >> 10;
    int j = jbeg + jj;
    s_attn[t] = (j < 49) ? attnval[((size_t)((m0 + rr) * 49 + j)) * 8 + h] : 0.f;
  }
  __syncthreads();   // full drain: preload loads retired before pipeline starts

  auto loadA = [&](int k0, uint4& kv, float& w) {
    const int k = k0 + acol;
    const int j = k >> 8, c = k & 255;
    kv = uint4{0u, 0u, 0u, 0u};
    w = 0.f;
    if (j < 49) {
      const int jj = j - jbeg;
      int id = s_vidx[jj * 128 + arow];
      if (id >= 0) {
        w = s_attn[(jj * 128 + arow) * 8 + (c >> 5)];
        kv = *(const uint4*)(fqkvV + (size_t)id * 256 + c);   // 8 bf16
      }
    } else if (c == 0) {
      kv.x = pk2(cell[q * 2], cell[q * 2 + 1]);  // cell = 1/64, exact in bf16
      w = 64.f;
    }
  };

  frag_cd acc[4][4] = {};
  uint4 kvc; float wc_;
  const u16* bbase = Bt + (size_t)(tid >> 2) * KBIG + (tid & 3) * 8 + kbeg;

  // prologue: B tile 0 -> buffer 0 (2 glds in flight), A(0) -> regs
  glds16(bbase, &Bs[(size_t)tid * 8]);
  glds16(bbase + (size_t)128 * KBIG, &Bs[(size_t)tid * 8 + 4096]);
  loadA(kbeg, kvc, wc_);

  int par = 0;
  for (int k0 = kbeg; k0 < kend; k0 += BK, par ^= 1) {
    // stage A(t): unpack bf16 pair -> f32, scale by attn weight, repack.
    {
      u32 aw[4] = {kvc.x, kvc.y, kvc.z, kvc.w};
      uint4 av;
      u32 avw[4];
      #pragma unroll
      for (int t = 0; t < 4; t++) {
        float lo = __uint_as_float(aw[t] << 16) * wc_;
        float hi = __uint_as_float(aw[t] & 0xffff0000u) * wc_;
        avw[t] = pk2(lo, hi);
      }
      av.x = avw[0]; av.y = avw[1]; av.z = avw[2]; av.w = avw[3];
      *(uint4*)&As[arow * LDSS + acol] = av;
    }
    if (k0 + BK < kend) {
      // issue B(t+1) into the other buffer; keep it in flight across the
      // barrier — only the 2 newest VMEM ops may remain outstanding, so
      // vmcnt(2) guarantees B(t) (older) has landed.
      u16* bd = &Bs[(size_t)(par ^ 1) * 8192 + (size_t)tid * 8];
      glds16(bbase + (k0 + BK - kbeg), bd);
      glds16(bbase + (k0 + BK - kbeg) + (size_t)128 * KBIG, bd + 4096);
      asm volatile("s_waitcnt vmcnt(2) lgkmcnt(0)" ::: "memory");
    } else {
      asm volatile("s_waitcnt vmcnt(0) lgkmcnt(0)" ::: "memory");
    }
    __builtin_amdgcn_s_barrier();
    if (k0 + BK < kend) loadA(k0 + BK, kvc, wc_);   // A prefetch (compiler-waited)
    const u16* bsrc = &Bs[(size_t)par * 8192];
    frag_ab af[4];
    #pragma unroll
    for (int i = 0; i < 4; i++)
      af[i] = *(const frag_ab*)&As[(mw + i * 16 + lr) * LDSS + lk * 8];
    #pragma unroll
    for (int j = 0; j < 4; j++) {
      frag_ab bf = *(const frag_ab*)&bsrc[(nwv + j * 16 + lr) * 32 + lk * 8];
      #pragma unroll
      for (int i = 0; i < 4; i++)
        acc[i][j] = __builtin_amdgcn_mfma_f32_16x16x32_bf16(af[i], bf, acc[i][j], 0, 0, 0);
    }
    asm volatile("s_waitcnt lgkmcnt(0)" ::: "memory");
    __builtin_amdgcn_s_barrier();
  }

  #pragma unroll
  for (int i = 0; i < 4; i++)
    #pragma unroll
    for (int j = 0; j < 4; j++) {
      int col = nwv + j * 16 + lr;
      #pragma unroll
      for (int r = 0; r < 4; r++) {
        int row = m0 + mw + i * 16 + lk * 4 + r;
        P[(size_t)z * (NQ * 256) + (size_t)row * 256 + col] = f2b(acc[i][j][r]);
      }
    }
}

// ---------------------------------------------------------------------------
// Fused: hid2 = relu(sum_z Pb + bi1); out = bi2 + skip + hid2 . Wi2^T.
// ---------------------------------------------------------------------------
__global__ __launch_bounds__(256)
void reduce_final(const u16* __restrict__ Pb, const float* __restrict__ bi1,
                  const float* __restrict__ Wi2, const float* __restrict__ bi2,
                  const float* __restrict__ skipb, float* __restrict__ out)
{
  const int q = blockIdx.x, c = threadIdx.x;
  float s = 0.f;
  #pragma unroll
  for (int z = 0; z < SPLITK; z++)
    s += b2f(Pb[(size_t)z * (NQ * 256) + (size_t)q * 256 + c]);
  s += bi1[c];
  s = fmaxf(s, 0.f);

  __shared__ float part[3][4];
  float p0 = s * Wi2[c], p1 = s * Wi2[256 + c], p2 = s * Wi2[512 + c];
  #pragma unroll
  for (int off = 32; off; off >>= 1) {
    p0 += __shfl_xor(p0, off);
    p1 += __shfl_xor(p1, off);
    p2 += __shfl_xor(p2, off);
  }
  if ((c & 63) == 0) {
    int w = c >> 6;
    part[0][w] = p0; part[1][w] = p1; part[2][w] = p2;
  }
  __syncthreads();
  if (c < 3)
    out[q * 3 + c] = bi2[c] + skipb[q * 3 + c]
                   + part[c][0] + part[c][1] + part[c][2] + part[c][3];
}

// ---------------------------------------------------------------------------
// FUSED attention-weight chain: c1 MLP + c2 + softmax in one kernel.
// grid 256 blocks x 256 threads; each block owns 16 q rows.
//  c1: 16x256x128 MFMA — A = rel tile (LDS), B-frags direct from L2-hot Btc1.
//  c2: 16x64x256 MFMA — A = block-local hid (bf16 LDS), B = Btc2p (64-row
//      zero-padded). acc across 4 col-chunks? No: full K=256 in 8 MFMA.
//  softmax: per-(q,h) thread-local over 49 taps (reads raw attnval, writes
//      final weights in place — same math as old softmax_k).
// ---------------------------------------------------------------------------
__global__ __launch_bounds__(256)
void attn_wc(const u16* __restrict__ relbuf, const u16* __restrict__ Btc1,
             const float* __restrict__ bc1, const u16* __restrict__ Btc2,
             const float* __restrict__ bc2, float* __restrict__ attnval)
{
  __shared__ u16 s_rel[16 * 136];    // A: 16 q-rows x 128 (pad 136)
  __shared__ u16 s_hid[16 * 264];    // hid bf16: 16 x 256 (pad 264)
  __shared__ float s_wc[16 * 52];    // wc: 16 x 49 (pad 52)
  const int tid = threadIdx.x;
  const int m0 = blockIdx.x * 16;
  const int wave = tid >> 6, lane = tid & 63;
  const int lr = lane & 15, lk = lane >> 4;

  // load rel A tile: 16 rows x 128 = 256 uint4, one per thread
  {
    int r = tid >> 4, kc = (tid & 15) * 8;
    uint4 v = *(const uint4*)&relbuf[(size_t)(m0 + r) * 128 + kc];
    *(uint4*)&s_rel[r * 136 + kc] = v;
  }
  __syncthreads();

  // ---- c1: hid = relu(rel x Btc1^T + bc1); wave w covers cols w*64..+63
  frag_cd acc1[4] = {};
  #pragma unroll
  for (int k0 = 0; k0 < 128; k0 += 32) {
    frag_ab af = *(const frag_ab*)&s_rel[lr * 136 + k0 + lk * 8];
    #pragma unroll
    for (int j = 0; j < 4; j++) {
      int col = wave * 64 + j * 16 + lr;
      frag_ab bf = *(const frag_ab*)&Btc1[(size_t)col * 128 + k0 + lk * 8];
      acc1[j] = __builtin_amdgcn_mfma_f32_16x16x32_bf16(af, bf, acc1[j], 0, 0, 0);
    }
  }
  #pragma unroll
  for (int j = 0; j < 4; j++) {
    int col = wave * 64 + j * 16 + lr;
    float badd = bc1[col];
    #pragma unroll
    for (int r = 0; r < 4; r++) {
      int row = lk * 4 + r;
      s_hid[row * 264 + col] = f2b(fmaxf(acc1[j][r] + badd, 0.f));
    }
  }
  __syncthreads();

  // ---- c2: wc = hid x Btc2p^T + bc2; wave w covers cols w*16..+15
  frag_cd acc2 = {};
  #pragma unroll
  for (int k0 = 0; k0 < 256; k0 += 32) {
    frag_ab af = *(const frag_ab*)&s_hid[lr * 264 + k0 + lk * 8];
    frag_ab bf = *(const frag_ab*)&Btc2[(size_t)(wave * 16 + lr) * 256 + k0 + lk * 8];
    acc2 = __builtin_amdgcn_mfma_f32_16x16x32_bf16(af, bf, acc2, 0, 0, 0);
  }
  {
    int col = wave * 16 + lr;
    if (col < 49) {
      float badd = bc2[col];
      #pragma unroll
      for (int r = 0; r < 4; r++) {
        int row = lk * 4 + r;
        s_wc[row * 52 + col] = acc2[r] + badd;
      }
    }
  }
  __syncthreads();

  // ---- softmax per (q, h): threads 0..127, one pair each (same math as
  //      the old softmax_k: max-sub, exp, normalize)
  if (tid < 128) {
    const int qq = tid >> 3, h = tid & 7;
    float* avp = attnval + ((size_t)(m0 + qq) * 49) * 8 + h;
    float v[49];
    float m = -1e30f;
    #pragma unroll
    for (int l = 0; l < 49; l++) {
      v[l] = s_wc[qq * 52 + l] + avp[(size_t)l * 8];
      m = fmaxf(m, v[l]);
    }
    float ssum = 0.f;
    #pragma unroll
    for (int l = 0; l < 49; l++) { v[l] = expf(v[l] - m); ssum += v[l]; }
    float inv = 1.f / ssum;
    #pragma unroll
    for (int l = 0; l < 49; l++) avp[(size_t)l * 8] = v[l] * inv;
  }
}

// ---------------------------------------------------------------------------
// Merged weight-packing + encoder-conv kernel (r21). Blocks [0, CONV_BLKS)
// run the encoder conv; remaining blocks pack weights.
// ---------------------------------------------------------------------------
static __device__ __forceinline__
void packconv(const float* __restrict__ W, u16* __restrict__ Bt,
              int Cin, int K2, int idx)
{
  int o  = idx / (Cin * K2);
  int r  = idx - o * (Cin * K2);
  int ci = r / K2;
  int s  = r - ci * K2;
  Bt[(size_t)o * (Cin * K2) + s * Cin + ci] = f2b(W[idx]);
}
static __device__ __forceinline__
void packcast(const float* __restrict__ W, u16* __restrict__ Bt,
              int Kin, int Kout, int idx)
{
  int n = idx / Kout, k = idx - n * Kout;
  Bt[idx] = f2b(k < Kin ? W[(size_t)n * Kin + k] : 0.f);
}

#define SZ_CH   147456   // 256*64*9
#define SZ_QKV  589824   // 256*256*9
#define SZ_OFF1 204800   // 256*32*25
#define SZ_OFF2 25088    // 98*256
#define SZ_C1   32768    // 256*128
#define SZ_C2P  16384    // 64*256 (Wc2 zero-padded to 64 rows for attn_wc)
#define SZ_WI1  3219456  // 256*12576
#define SZ_PACK (SZ_CH + 3*SZ_QKV + SZ_OFF1 + SZ_OFF2 + SZ_C1 + SZ_C2P + 768 + SZ_WI1)
#define CONV_BLKS 1024   // 4096 pixels, 4 per 256-thread block

__global__ __launch_bounds__(256)
void pack_enc(const float* W_ch, const float* W_q, const float* W_k,
              const float* W_v, const float* W_off1, const float* W_off2,
              const float* Wc1, const float* Wc2, const float* Wi1,
              const float* b_q, const float* b_k, const float* b_v,
              u16* Btch, u16* Btqkv, u16* Btoff1, u16* Btoff2,
              u16* Btc1, u16* Btc2, u16* Wi1p, float* bqkv,
              const float* __restrict__ inp, const float* __restrict__ W_enc,
              const float* __restrict__ b_enc, u16* __restrict__ feat1)
{
  const int bid = blockIdx.x;
  const int tid = threadIdx.x;
  if (bid < CONV_BLKS) {
    // ----- encoder conv: 3->64, 3x3 pad1, +bias, relu -----
    const int p = bid * 4 + (tid >> 6), c = tid & 63;
    const int y = p >> 6, x = p & 63;
    float s = b_enc[c];
    #pragma unroll
    for (int ci = 0; ci < 3; ci++)
      #pragma unroll
      for (int dy = 0; dy < 3; dy++) {
        int yy = y + dy - 1;
        if ((unsigned)yy >= 64u) continue;
        #pragma unroll
        for (int dx = 0; dx < 3; dx++) {
          int xx = x + dx - 1;
          if ((unsigned)xx >= 64u) continue;
          s += inp[ci * HW + yy * 64 + xx] * W_enc[((c * 3 + ci) * 3 + dy) * 3 + dx];
        }
      }
    feat1[(size_t)p * 64 + c] = f2b(fmaxf(s, 0.f));
    return;
  }
  int i = (bid - CONV_BLKS) * 256 + tid;
  if (i < SZ_CH) { packconv(W_ch, Btch, 64, 9, i); return; }
  i -= SZ_CH;
  if (i < SZ_QKV) { packconv(W_q, Btqkv, 256, 9, i); return; }
  i -= SZ_QKV;
  if (i < SZ_QKV) { packconv(W_k, Btqkv + (size_t)256 * 2304, 256, 9, i); return; }
  i -= SZ_QKV;
  if (i < SZ_QKV) { packconv(W_v, Btqkv + (size_t)512 * 2304, 256, 9, i); return; }
  i -= SZ_QKV;
  if (i < SZ_OFF1) { packconv(W_off1, Btoff1, 32, 25, i); return; }
  i -= SZ_OFF1;
  if (i < SZ_OFF2) { packcast(W_off2, Btoff2, 256, 256, i); return; }
  i -= SZ_OFF2;
  if (i < SZ_C1) { packcast(Wc1, Btc1, 98, 128, i); return; }
  i -= SZ_C1;
  if (i < SZ_C2P) {
    // Wc2 (49x256) -> 64-row zero-padded row-major (for attn_wc B-frags)
    int n = i >> 8, k = i & 255;
    Btc2[i] = f2b(n < 49 ? Wc2[n * 256 + k] : 0.f);
    return;
  }
  i -= SZ_C2P;
  if (i < 768) {
    bqkv[i] = (i < 256) ? b_q[i] : (i < 512) ? b_k[i - 256] : b_v[i - 512];
    return;
  }
  i -= 768;
  if (i < SZ_WI1) { packcast(Wi1, Wi1p, 12546, 12576, i); }
}

// ---------------------------------------------------------------------------
// Per-query sampler (writes raw q.k dots to attnval; attn_wc finalizes).
// ---------------------------------------------------------------------------
__global__ __launch_bounds__(256)
void sampler(const float* __restrict__ coord, const u16* __restrict__ fqkvb,
             const float* __restrict__ offs, const float* __restrict__ inp,
             float* __restrict__ attnval, u16* __restrict__ relbuf,
             int* __restrict__ vidx, float* __restrict__ skipb)
{
  const int q = blockIdx.x;
  const int tid = threadIdx.x;
  __shared__ float s_off[98];
  __shared__ int s_idx[49];
  __shared__ float s_q[256];

  const float c0 = coord[q * 2], c1 = coord[q * 2 + 1];
  const float gxp = ((c1 + 1.f) * 64.f - 1.f) * 0.5f;
  const float gyp = ((c0 + 1.f) * 64.f - 1.f) * 0.5f;
  const int ixn = (int)rintf(gxp), iyn = (int)rintf(gyp);
  const bool inn = ((unsigned)ixn < 64u) && ((unsigned)iyn < 64u);

  if (tid < 98) {
    float v = inn ? offs[(size_t)(iyn * 64 + ixn) * 98 + tid] : 0.f;
    s_off[tid] = tanhf(v) * (2.f / 63.f);
  }
  __syncthreads();

  const float scky = inn ? (-1.f + (float)(2 * iyn + 1) * (1.f / 64.f)) : 0.f;
  const float sckx = inn ? (-1.f + (float)(2 * ixn + 1) * (1.f / 64.f)) : 0.f;

  if (tid < 49) {
    const int a = tid / 7, bb = tid - a * 7;
    float sy = scky + (float)(a - 3) * (2.f / 64.f) + s_off[2 * tid];
    float sx = sckx + (float)(bb - 3) * (2.f / 64.f) + s_off[2 * tid + 1];
    relbuf[(size_t)q * 128 + 2 * tid]     = f2b((c0 - sy) * 64.f);
    relbuf[(size_t)q * 128 + 2 * tid + 1] = f2b((c1 - sx) * 64.f);
    float gx2 = ((sx + 1.f) * 64.f - 1.f) * 0.5f;
    float gy2 = ((sy + 1.f) * 64.f - 1.f) * 0.5f;
    int ix2 = (int)rintf(gx2), iy2 = (int)rintf(gy2);
    int id = (((unsigned)ix2 < 64u) && ((unsigned)iy2 < 64u)) ? (iy2 * 64 + ix2) : -1;
    s_idx[tid] = id;
    vidx[q * 49 + tid] = id;
  } else if (tid >= 98 && tid < 128) {
    relbuf[(size_t)q * 128 + tid] = 0;
  }

  {
    const float x0f = floorf(gxp), y0f = floorf(gyp);
    const float wx = gxp - x0f, wy = gyp - y0f;
    const int x0 = (int)x0f, y0 = (int)y0f;
    float qc = 0.f;
    #pragma unroll
    for (int t = 0; t < 4; t++) {
      int xi = x0 + (t & 1), yi = y0 + (t >> 1);
      if (((unsigned)xi < 64u) && ((unsigned)yi < 64u)) {
        float w = ((t & 1) ? wx : 1.f - wx) * ((t >> 1) ? wy : 1.f - wy);
        qc += w * b2f(fqkvb[(size_t)(yi * 64 + xi) * 768 + tid]);
      }
    }
    s_q[tid] = qc * 0.17677669529663687f;
  }

  if (tid < 3) {
    float gx = fminf(fmaxf(gxp, 0.f), 63.f);
    float gy = fminf(fmaxf(gyp, 0.f), 63.f);
    float xf = floorf(gx), yf = floorf(gy);
    float wxs = gx - xf, wys = gy - yf;
    int xa = (int)xf, ya = (int)yf;
    int xb = min(xa + 1, 63), yb = min(ya + 1, 63);
    const float* ch = inp + tid * HW;
    float v = (1.f - wxs) * (1.f - wys) * ch[ya * 64 + xa]
            + wxs * (1.f - wys) * ch[ya * 64 + xb]
            + (1.f - wxs) * wys * ch[yb * 64 + xa]
            + wxs * wys * ch[yb * 64 + xb];
    skipb[q * 3 + tid] = v;
  }
  __syncthreads();

  const int wave = tid >> 6, lane = tid & 63;
  const int half = lane >> 5, sub = lane & 31;
  const int ch0 = sub * 8;
  const int h = sub >> 2;
  float qv[8];
  #pragma unroll
  for (int i = 0; i < 8; i++) qv[i] = s_q[ch0 + i];

  for (int it = 0; it < 7; it++) {
    int j = it * 8 + wave * 2 + half;
    if (j >= 49) break;
    int id = s_idx[j];
    float p = 0.f;
    if (id >= 0) {
      uint4 kv = *(const uint4*)&fqkvb[(size_t)id * 768 + 256 + ch0];
      u32 w0 = kv.x, w1 = kv.y, w2 = kv.z, w3 = kv.w;
      p = fmaf(qv[0], __uint_as_float(w0 << 16), p);
      p = fmaf(qv[1], __uint_as_float(w0 & 0xffff0000u), p);
      p = fmaf(qv[2], __uint_as_float(w1 << 16), p);
      p = fmaf(qv[3], __uint_as_float(w1 & 0xffff0000u), p);
      p = fmaf(qv[4], __uint_as_float(w2 << 16), p);
      p = fmaf(qv[5], __uint_as_float(w2 & 0xffff0000u), p);
      p = fmaf(qv[6], __uint_as_float(w3 << 16), p);
      p = fmaf(qv[7], __uint_as_float(w3 & 0xffff0000u), p);
    }
    p += __shfl_down(p, 2, 4);
    p += __shfl_down(p, 1, 4);
    if ((sub & 3) == 0) attnval[((size_t)q * 49 + j) * 8 + h] = p;
  }
}

// ===========================================================================
extern "C" void kernel_launch(void* const* d_in, const int* in_sizes, int n_in,
                              void* d_out, int out_size, void* d_ws, size_t ws_size,
                              hipStream_t stream)
{
  const float* inp    = (const float*)d_in[0];
  const float* coord  = (const float*)d_in[1];
  const float* cell   = (const float*)d_in[2];
  const float* W_enc  = (const float*)d_in[3];
  const float* b_enc  = (const float*)d_in[4];
  const float* W_ch   = (const float*)d_in[5];
  const float* b_ch   = (const float*)d_in[6];
  const float* W_q    = (const float*)d_in[7];
  const float* b_q    = (const float*)d_in[8];
  const float* W_k    = (const float*)d_in[9];
  const float* b_k    = (const float*)d_in[10];
  const float* W_v    = (const float*)d_in[11];
  const float* b_v    = (const float*)d_in[12];
  const float* W_off1 = (const float*)d_in[13];
  const float* b_off1 = (const float*)d_in[14];
  const float* ln_g   = (const float*)d_in[15];
  const float* ln_b   = (const float*)d_in[16];
  const float* W_off2 = (const float*)d_in[17];
  const float* Wc1    = (const float*)d_in[18];
  const float* bc1    = (const float*)d_in[19];
  const float* Wc2    = (const float*)d_in[20];
  const float* bc2    = (const float*)d_in[21];
  const float* Wi1    = (const float*)d_in[22];
  const float* bi1    = (const float*)d_in[23];
  const float* Wi2    = (const float*)d_in[24];
  const float* bi2    = (const float*)d_in[25];

  char* base = (char*)d_ws;
  size_t off = 0;
  auto alloc = [&](size_t bytes) -> char* {
    char* r = base + off;
    off = (off + bytes + 255) & ~(size_t)255;
    return r;
  };

  // --- scratch region (dead before gemm_big runs; Pb aliases it) ---
  float* obuf   = (float*)alloc((size_t)HW * 256 * 4);
  u16*   ocg    = (u16*)  alloc((size_t)HW * 256 * 2);
  float* offsb  = (float*)alloc((size_t)HW * 98 * 4);
  u16*   feat1  = (u16*)  alloc((size_t)HW * 64 * 2);
  u16*   feat   = (u16*)  alloc((size_t)HW * 256 * 2);
  u16*   relbuf = (u16*)  alloc((size_t)NQ * 128 * 2);
  u16*   Btqkv  = (u16*)  alloc((size_t)768 * 2304 * 2);
  u16*   Btch   = (u16*)  alloc((size_t)256 * 576 * 2);
  u16*   Btoff1 = (u16*)  alloc((size_t)256 * 800 * 2);
  u16*   Btoff2 = (u16*)  alloc((size_t)98 * 256 * 2);
  u16*   Btc1   = (u16*)  alloc((size_t)256 * 128 * 2);
  u16*   Btc2   = (u16*)  alloc((size_t)64 * 256 * 2);
  // gemm_big bf16 partials alias scratch: 16 x 2MB = 33.6MB at base+0.
  u16* Pb = (u16*)base;
  // qkv bf16 partials at [36MB, 54.9MB): past live scratch (~18MB),
  // disjoint from Pb's 33.6MB, dead before gemm_big.
  u16* Pqb = (u16*)(base + ((size_t)36 << 20));
  {
    size_t need = ((size_t)36 << 20) + (size_t)QSPLIT * NQ * 768 * 2;
    if (off < need) off = (need + 255) & ~(size_t)255;
  }
  // --- persistent buffers ---
  u16*   fqkvb   = (u16*)  alloc((size_t)HW * 768 * 2);
  u16*   fqkvVb  = (u16*)  alloc((size_t)HW * 256 * 2);
  float* attnval = (float*)alloc((size_t)NQ * 49 * 8 * 4);
  int*   vidxb   = (int*)  alloc((size_t)NQ * 49 * 4);
  float* skipb   = (float*)alloc((size_t)NQ * 3 * 4);
  u16*   Wi1p    = (u16*)  alloc((size_t)256 * KBIG * 2);
  float* bqkv    = (float*)alloc(768 * 4);
  (void)ws_size; (void)in_sizes; (void)n_in; (void)out_size;

  // --- weight packing ∥ encoder conv (merged: both input-only) ---
  pack_enc<<<CONV_BLKS + (SZ_PACK + 255) / 256, 256, 0, stream>>>(
      W_ch, W_q, W_k, W_v, W_off1, W_off2, Wc1, Wc2, Wi1, b_q, b_k, b_v,
      Btch, Btqkv, Btoff1, Btoff2, Btc1, Btc2, Wi1p, bqkv,
      inp, W_enc, b_enc, feat1);

  // --- conv stack ---
  gemm_conv<3, 6, 1><<<dim3(64, 4, 1), 256, 0, stream>>>(
      feat1, Btch, feat, b_ch, 256, 576, 256, /*bf16*/2, 64, 0, 0, 0, 0);
  // merged qkv + off1 (overlap)
  gemm_feat<<<NBLK_QKV + NBLK_OFF1, 256, 0, stream>>>(
      feat, Btqkv, Pqb, Btoff1, obuf, b_off1);
  // merged reduce_qkv ∥ ln_gelu (both depend only on gemm_feat)
  post_feat<<<RQ_BLKS + HW, 256, 0, stream>>>(
      Pqb, bqkv, fqkvb, fqkvVb, obuf, ln_g, ln_b, ocg);
  gemm_bt<<<dim3(64, 2, 1), 256, 0, stream>>>(ocg, Btoff2, offsb, nullptr,
      98, 256, 98, 0, 0, 0, 0, 0);

  // --- per-query attention path ---
  sampler<<<NQ, 256, 0, stream>>>(coord, fqkvb, offsb, inp,
                                  attnval, relbuf, vidxb, skipb);
  // fused c1 + c2 + softmax (was 3 launches + hid1/wcb glue buffers)
  attn_wc<<<NQ / 16, 256, 0, stream>>>(relbuf, Btc1, bc1, Btc2, bc2, attnval);

  // --- big MLP: 128x256 tile, bf16 gather-A, dbuf glds-B + counted vmcnt,
  //     split-K(16), bf16 partials ---
  gemm_big<<<dim3(32, SPLITK), 512, 0, stream>>>(
      Wi1p, fqkvVb, attnval, vidxb, cell, Pb);
  reduce_final<<<NQ, 256, 0, stream>>>(Pb, bi1, Wi2, bi2, skipb, (float*)d_out);
}

// Round 9
// 262.418 us; speedup vs baseline: 1.1694x; 1.0226x over previous
//
#include <hip/hip_runtime.h>
#include <hip/hip_bf16.h>

// ============================================================================
// IDASR pipeline on gfx950 — round 23.
// r22 post-mortem: attn_wc MFMA-fusion gained 7us (268.4, best). Same
// pattern, next instance:
//  * off2 is a 1x1 conv (98x256) -> per-pixel local. ln_gelu + off2 FUSED
//    into post_feat as 256 blocks x 16 pixels: LN+GELU -> LDS bf16 ->
//    16x112x256 MFMA vs 112-row zero-padded Btoff2 -> offsb (f32).
//  * Removes the half-occupancy 128-block gemm_bt(off2) launch + the 4MB
//    ocg round-trip; gemm_bt kernel deleted (no remaining users).
//  * 9 -> 8 launches. Same rounding points (LN f32 sum order differs by
//    last-ulp only — far under bf16 tolerance).
// Everything else r22-identical.
// ============================================================================

typedef unsigned short u16;
typedef unsigned int u32;
using frag_ab = __attribute__((ext_vector_type(8))) short;  // 8 x bf16
using frag_cd = __attribute__((ext_vector_type(4))) float;  // 4 x f32 acc

#define HW 4096
#define NQ 4096
#define KBIG 12576
#define SPLITK 16
#define KCHUNK 800
#define JMAX 5
#define KQ 2304
#define QSPLIT 3
#define QCHUNK 768
#define NBLK_QKV (64 * 6 * QSPLIT)   // 1152
#define NBLK_OFF1 (64 * 8)           // 512

static __device__ __forceinline__ u16 f2b(float f) {
  union { __hip_bfloat16 h; u16 u; } c; c.h = __float2bfloat16(f); return c.u;
}
static __device__ __forceinline__ float b2f(u16 v) {
  return __uint_as_float((u32)v << 16);
}
static __device__ __forceinline__ u32 pk2(float a, float b) {
  union { __hip_bfloat162 h; u32 u; } c;
  c.h = __float22bfloat162_rn(float2{a, b});
  return c.u;
}
// async global->LDS, 16B per lane. LDS dest is wave-uniform base + lane*16.
static __device__ __forceinline__ void glds16(const u16* g, u16* l) {
  __builtin_amdgcn_global_load_lds(
      (const __attribute__((address_space(1))) u32*)(g),
      (__attribute__((address_space(3))) u32*)(l), 16, 0, 0);
}

#define BM 64
#define BN 64
#define BK 32
#define LDSS 40   // padded lds row stride for reg-staged tiles

// ---------------------------------------------------------------------------
// Implicit-im2col conv GEMM, 64x64 tile (ch conv only now).
// ---------------------------------------------------------------------------
template<int W3, int SH, int PAD>
__global__ __launch_bounds__(256)
void gemm_conv(const u16* __restrict__ feat, const u16* __restrict__ Bt,
               void* __restrict__ Cv, const float* __restrict__ bias,
               int N, int K, int ldc, int flags, int FC, int cbStride,
               long sB, long sC, int sBias)
{
  __shared__ u16 As[BM * LDSS];
  __shared__ u16 Bs[BN * LDSS];
  const int z = blockIdx.z;
  Bt += (long)z * sB;
  const float* bz = bias ? bias + (long)z * sBias : nullptr;
  const int cb = z * cbStride;

  const int tid  = threadIdx.x;
  const int m0   = blockIdx.x * BM;
  const int n0   = blockIdx.y * BN;
  const int wave = tid >> 6, lane = tid & 63;
  const int mw = (wave & 1) * 32, nw = (wave >> 1) * 32;
  const int lr = lane & 15, lk = lane >> 4;
  const int srow = tid >> 2, scol = (tid & 3) * 8;
  const int p = m0 + srow, y = p >> 6, x = p & 63;

  frag_cd acc[2][2] = {};
  const bool bok  = (n0 + srow) < N;
  const u16* bptr = Bt + (size_t)(n0 + srow) * K + scol;

  auto stageA = [&](int k0) -> uint4 {
    int k = k0 + scol;
    int s = k >> SH;
    int c = k & ((1 << SH) - 1);
    int dy = s / W3, dx = s - dy * W3;
    int yy = y + dy - PAD, xx = x + dx - PAD;
    if (((unsigned)yy < 64u) && ((unsigned)xx < 64u))
      return *(const uint4*)&feat[(size_t)(yy * 64 + xx) * FC + cb + c];
    return uint4{0u, 0u, 0u, 0u};
  };

  uint4 av = stageA(0);
  uint4 bv = bok ? *(const uint4*)(bptr) : uint4{0u, 0u, 0u, 0u};

  for (int k0 = 0; k0 < K; k0 += BK) {
    *(uint4*)&As[srow * LDSS + scol] = av;
    *(uint4*)&Bs[srow * LDSS + scol] = bv;
    __syncthreads();
    if (k0 + BK < K) {
      av = stageA(k0 + BK);
      bv = bok ? *(const uint4*)(bptr + k0 + BK) : uint4{0u, 0u, 0u, 0u};
    }
    frag_ab af0 = *(const frag_ab*)&As[(mw      + lr) * LDSS + lk * 8];
    frag_ab af1 = *(const frag_ab*)&As[(mw + 16 + lr) * LDSS + lk * 8];
    frag_ab bf0 = *(const frag_ab*)&Bs[(nw      + lr) * LDSS + lk * 8];
    frag_ab bf1 = *(const frag_ab*)&Bs[(nw + 16 + lr) * LDSS + lk * 8];
    acc[0][0] = __builtin_amdgcn_mfma_f32_16x16x32_bf16(af0, bf0, acc[0][0], 0, 0, 0);
    acc[0][1] = __builtin_amdgcn_mfma_f32_16x16x32_bf16(af0, bf1, acc[0][1], 0, 0, 0);
    acc[1][0] = __builtin_amdgcn_mfma_f32_16x16x32_bf16(af1, bf0, acc[1][0], 0, 0, 0);
    acc[1][1] = __builtin_amdgcn_mfma_f32_16x16x32_bf16(af1, bf1, acc[1][1], 0, 0, 0);
    __syncthreads();
  }

  const bool relu = flags & 1;
  const bool obf  = flags & 2;
  #pragma unroll
  for (int i = 0; i < 2; i++)
    #pragma unroll
    for (int j = 0; j < 2; j++) {
      int col = n0 + nw + j * 16 + lr;
      if (col >= N) continue;
      float badd = bz ? bz[col] : 0.f;
      #pragma unroll
      for (int r = 0; r < 4; r++) {
        int row = m0 + mw + i * 16 + lk * 4 + r;
        float v = acc[i][j][r] + badd;
        if (relu) v = fmaxf(v, 0.f);
        size_t idx = (size_t)z * sC + (size_t)row * ldc + col;
        if (obf) ((u16*)Cv)[idx] = f2b(v);
        else     ((float*)Cv)[idx] = v;
      }
    }
}

// ---------------------------------------------------------------------------
// Merged feat-consumer kernel: blocks [0,1152) = qkv GEMM (64x128 tile,
// implicit im2col A, glds-B, split-K(3), bf16 partials); blocks
// [1152,1664) = grouped 5x5 off1 conv (64x64 tile). One launch -> overlap.
// ---------------------------------------------------------------------------
__global__ __launch_bounds__(256)
void gemm_feat(const u16* __restrict__ feat, const u16* __restrict__ Btqkv,
               u16* __restrict__ Pq, const u16* __restrict__ Btoff1,
               float* __restrict__ obuf, const float* __restrict__ b_off1)
{
  __shared__ u16 smem[6656];   // 13.3 KB: qkv As(2560)+Bs(4096); off1 uses 5120
  const int bid = blockIdx.x;
  const int tid = threadIdx.x;
  const int wave = tid >> 6, lane = tid & 63;
  const int lr = lane & 15, lk = lane >> 4;

  if (bid < NBLK_QKV) {
    // ----- qkv branch -----
    u16* As = smem;            // 64 * 40
    u16* Bs = smem + 64 * 40;  // 128 * 32, glds target
    const int mz  = bid & 63;
    const int rest = bid >> 6;
    const int ny  = rest % 6;
    const int z   = rest / 6;
    const int m0  = mz * 64;
    const int n0  = ny * 128;
    const int kbeg = z * QCHUNK;
    const int kend = kbeg + QCHUNK;
    const int nw = wave * 32;
    const int arow = tid >> 2, acol = (tid & 3) * 8;
    const int p = m0 + arow, y = p >> 6, x = p & 63;

    frag_cd acc[4][2] = {};
    const u16* bbase = Btqkv + (size_t)(n0 + (tid >> 2)) * KQ + (tid & 3) * 8 + kbeg;
    u16* bdst = &Bs[(size_t)tid * 8];

    auto stageA = [&](int k0) -> uint4 {
      int k = k0 + acol;
      int s = k >> 8, c = k & 255;
      int dy = s / 3, dx = s - dy * 3;
      int yy = y + dy - 1, xx = x + dx - 1;
      if (((unsigned)yy < 64u) && ((unsigned)xx < 64u))
        return *(const uint4*)&feat[(size_t)(yy * 64 + xx) * 256 + c];
      return uint4{0u, 0u, 0u, 0u};
    };

    uint4 av = stageA(kbeg);

    for (int k0 = kbeg; k0 < kend; k0 += BK) {
      glds16(bbase + (k0 - kbeg), bdst);
      glds16(bbase + (k0 - kbeg) + (size_t)64 * KQ, bdst + 2048);
      *(uint4*)&As[arow * LDSS + acol] = av;
      __syncthreads();
      if (k0 + BK < kend) av = stageA(k0 + BK);
      frag_ab af[4];
      #pragma unroll
      for (int i = 0; i < 4; i++)
        af[i] = *(const frag_ab*)&As[(i * 16 + lr) * LDSS + lk * 8];
      #pragma unroll
      for (int j = 0; j < 2; j++) {
        frag_ab bf = *(const frag_ab*)&Bs[(nw + j * 16 + lr) * 32 + lk * 8];
        #pragma unroll
        for (int i = 0; i < 4; i++)
          acc[i][j] = __builtin_amdgcn_mfma_f32_16x16x32_bf16(af[i], bf, acc[i][j], 0, 0, 0);
      }
      __syncthreads();
    }

    #pragma unroll
    for (int i = 0; i < 4; i++)
      #pragma unroll
      for (int j = 0; j < 2; j++) {
        int col = n0 + nw + j * 16 + lr;
        #pragma unroll
        for (int r = 0; r < 4; r++) {
          int row = m0 + i * 16 + lk * 4 + r;
          Pq[(size_t)z * (NQ * 768) + (size_t)row * 768 + col] = f2b(acc[i][j][r]);
        }
      }
  } else {
    // ----- off1 grouped conv branch (5x5 pad2, 32 ch/group) -----
    u16* As = smem;            // 64 * 40
    u16* Bs = smem + 64 * 40;  // 64 * 40
    const int t  = bid - NBLK_QKV;
    const int m0 = (t & 63) * 64;
    const int g  = t >> 6;               // group 0..7
    const int cb = g * 32;
    const u16* Bt = Btoff1 + (size_t)g * 32 * 800;
    const float* bz = b_off1 + g * 32;
    const int mw = (wave & 1) * 32, nw = (wave >> 1) * 32;
    const int srow = tid >> 2, scol = (tid & 3) * 8;
    const int p = m0 + srow, y = p >> 6, x = p & 63;

    frag_cd acc[2][2] = {};
    const bool bok  = srow < 32;
    const u16* bptr = Bt + (size_t)srow * 800 + scol;

    auto stageA = [&](int k0) -> uint4 {
      int k = k0 + scol;
      int s = k >> 5;
      int c = k & 31;
      int dy = s / 5, dx = s - dy * 5;
      int yy = y + dy - 2, xx = x + dx - 2;
      if (((unsigned)yy < 64u) && ((unsigned)xx < 64u))
        return *(const uint4*)&feat[(size_t)(yy * 64 + xx) * 256 + cb + c];
      return uint4{0u, 0u, 0u, 0u};
    };

    uint4 av = stageA(0);
    uint4 bv = bok ? *(const uint4*)(bptr) : uint4{0u, 0u, 0u, 0u};

    for (int k0 = 0; k0 < 800; k0 += BK) {
      *(uint4*)&As[srow * LDSS + scol] = av;
      *(uint4*)&Bs[srow * LDSS + scol] = bv;
      __syncthreads();
      if (k0 + BK < 800) {
        av = stageA(k0 + BK);
        bv = bok ? *(const uint4*)(bptr + k0 + BK) : uint4{0u, 0u, 0u, 0u};
      }
      frag_ab af0 = *(const frag_ab*)&As[(mw      + lr) * LDSS + lk * 8];
      frag_ab af1 = *(const frag_ab*)&As[(mw + 16 + lr) * LDSS + lk * 8];
      frag_ab bf0 = *(const frag_ab*)&Bs[(nw      + lr) * LDSS + lk * 8];
      frag_ab bf1 = *(const frag_ab*)&Bs[(nw + 16 + lr) * LDSS + lk * 8];
      acc[0][0] = __builtin_amdgcn_mfma_f32_16x16x32_bf16(af0, bf0, acc[0][0], 0, 0, 0);
      acc[0][1] = __builtin_amdgcn_mfma_f32_16x16x32_bf16(af0, bf1, acc[0][1], 0, 0, 0);
      acc[1][0] = __builtin_amdgcn_mfma_f32_16x16x32_bf16(af1, bf0, acc[1][0], 0, 0, 0);
      acc[1][1] = __builtin_amdgcn_mfma_f32_16x16x32_bf16(af1, bf1, acc[1][1], 0, 0, 0);
      __syncthreads();
    }

    #pragma unroll
    for (int i = 0; i < 2; i++)
      #pragma unroll
      for (int j = 0; j < 2; j++) {
        int col = nw + j * 16 + lr;
        if (col >= 32) continue;
        float badd = bz[col];
        #pragma unroll
        for (int r = 0; r < 4; r++) {
          int row = m0 + mw + i * 16 + lk * 4 + r;
          obuf[(size_t)row * 256 + g * 32 + col] = acc[i][j][r] + badd;
        }
      }
  }
}

// ---------------------------------------------------------------------------
// Merged post-gemm_feat kernel:
//  blocks [0, RQ_BLKS)          : reduce_qkv (sum partials + bias)
//  blocks [RQ_BLKS, +LNO_BLKS)  : ln_gelu + off2 1x1-conv fused MFMA
//    (16 pixels/block: LN+GELU -> LDS bf16 -> 16x112x256 MFMA vs padded
//     Btoff2 -> offsb f32). Both branches depend only on gemm_feat.
// ---------------------------------------------------------------------------
#define RQ_BLKS 1536   // NQ*96/256
#define LNO_BLKS 256   // 4096 pixels / 16
__global__ __launch_bounds__(256)
void post_feat(const u16* __restrict__ P, const float* __restrict__ bias,
               u16* __restrict__ outb, u16* __restrict__ outV,
               const float* __restrict__ x, const float* __restrict__ g,
               const float* __restrict__ b, const u16* __restrict__ Btoff2,
               float* __restrict__ offsb)
{
  __shared__ u16 s_oc[16 * 264];   // lnoff2 branch only (8.25 KB)
  const int bid = blockIdx.x;
  const int tid = threadIdx.x;
  if (bid < RQ_BLKS) {
    // ----- reduce_qkv -----
    int i8 = bid * 256 + tid;
    size_t i = (size_t)i8 * 8;
    int row = (int)(i / 768);
    int c = (int)(i % 768);
    float v[8];
    #pragma unroll
    for (int t = 0; t < 8; t++) v[t] = bias[c + t];
    for (int z = 0; z < QSPLIT; z++) {
      uint4 a = *(const uint4*)&P[(size_t)z * (NQ * 768) + i];
      u32 aw[4] = {a.x, a.y, a.z, a.w};
      #pragma unroll
      for (int t = 0; t < 4; t++) {
        v[2 * t]     += __uint_as_float(aw[t] << 16);
        v[2 * t + 1] += __uint_as_float(aw[t] & 0xffff0000u);
      }
    }
    uint4 ob = {pk2(v[0], v[1]), pk2(v[2], v[3]), pk2(v[4], v[5]), pk2(v[6], v[7])};
    *(uint4*)&outb[i] = ob;
    if (c >= 512) {
      // bf16 V gather table: dense 2 MB (pos,256) layout for gemm_big.
      *(uint4*)&outV[(size_t)row * 256 + (c - 512)] = ob;
    }
  } else {
    // ----- ln_gelu + off2 (1x1 conv) fused, 16 pixels per block -----
    const int p0 = (bid - RQ_BLKS) * 16;
    const int p = tid >> 4, gl = tid & 15;   // pixel 0..15, 16-lane group
    // load 16 channels, LN stats within 16-lane group
    float v[16];
    {
      const float* src = x + (size_t)(p0 + p) * 256 + gl * 16;
      #pragma unroll
      for (int t = 0; t < 4; t++) {
        float4 f = *(const float4*)(src + t * 4);
        v[4 * t] = f.x; v[4 * t + 1] = f.y; v[4 * t + 2] = f.z; v[4 * t + 3] = f.w;
      }
    }
    float s1 = 0.f, s2 = 0.f;
    #pragma unroll
    for (int t = 0; t < 16; t++) { s1 += v[t]; s2 += v[t] * v[t]; }
    #pragma unroll
    for (int off = 8; off; off >>= 1) {
      s1 += __shfl_xor(s1, off, 16);
      s2 += __shfl_xor(s2, off, 16);
    }
    float mu   = s1 * (1.f / 256.f);
    float var  = s2 * (1.f / 256.f) - mu * mu;
    float rstd = rsqrtf(var + 1e-5f);
    #pragma unroll
    for (int t = 0; t < 16; t++) {
      int c = gl * 16 + t;
      float xn = (v[t] - mu) * rstd * g[c] + b[c];
      float ge = 0.5f * xn * (1.f + erff(xn * 0.70710678118654752f));
      s_oc[p * 264 + c] = f2b(ge);
    }
    __syncthreads();
    // MFMA: out(16 x 112) = A(16 x 256) x Btoff2^T (112 rows, zero-padded).
    // wave w covers j = w and j = w+4 (waves 0-2 only for the latter).
    const int wave = tid >> 6, lane = tid & 63;
    const int lr = lane & 15, lk = lane >> 4;
    frag_cd a0 = {}, a1 = {};
    #pragma unroll
    for (int k0 = 0; k0 < 256; k0 += 32) {
      frag_ab af = *(const frag_ab*)&s_oc[lr * 264 + k0 + lk * 8];
      frag_ab bf0 = *(const frag_ab*)&Btoff2[(size_t)(wave * 16 + lr) * 256 + k0 + lk * 8];
      a0 = __builtin_amdgcn_mfma_f32_16x16x32_bf16(af, bf0, a0, 0, 0, 0);
      if (wave < 3) {
        frag_ab bf1 = *(const frag_ab*)&Btoff2[(size_t)((wave + 4) * 16 + lr) * 256 + k0 + lk * 8];
        a1 = __builtin_amdgcn_mfma_f32_16x16x32_bf16(af, bf1, a1, 0, 0, 0);
      }
    }
    {
      const int col0 = wave * 16 + lr;
      const int col1 = (wave + 4) * 16 + lr;
      #pragma unroll
      for (int r = 0; r < 4; r++) {
        int row = lk * 4 + r;
        offsb[(size_t)(p0 + row) * 98 + col0] = a0[r];   // col0 <= 63 < 98
        if (wave < 3 && col1 < 98)
          offsb[(size_t)(p0 + row) * 98 + col1] = a1[r];
      }
    }
  }
}

// ---------------------------------------------------------------------------
// Big MLP GEMM: fused gather-A (bf16 V, weight-mul + repack), 128x256 tile,
// double-buffered glds-B with counted-vmcnt pipeline, split-K(16), bf16
// partials. block 512 (8 waves), grid (32, 16) = 2/CU (reg-capped: ~60 VGPR
// + 64 AGPR unified; (512,4) — do NOT raise min-waves, r15 spilled).
// r16 version (proven best pipeline).
// ---------------------------------------------------------------------------
__global__ __launch_bounds__(512, 4)
void gemm_big(const u16* __restrict__ Bt, const u16* __restrict__ fqkvV,
              const float* __restrict__ attnval, const int* __restrict__ vidx,
              const float* __restrict__ cell, u16* __restrict__ P)
{
  __shared__ u16 As[128 * LDSS];            // 10 KB padded, reg-staged gather
  __shared__ u16 Bs[2 * 256 * 32];          // 32 KB double-buffered glds target
  __shared__ short s_vidx[JMAX * 128];      // 1.25 KB (ids < 4096 fit short)
  __shared__ float s_attn[JMAX * 128 * 8];  // 20 KB
  const int tid  = threadIdx.x;
  const int m0   = blockIdx.x * 128;
  const int z    = blockIdx.y;
  const int kbeg = z * KCHUNK;
  const int kend = min(KBIG, kbeg + KCHUNK);
  const int jbeg = kbeg >> 8;
  const int jcnt = ((kend - 1) >> 8) - jbeg + 1;   // <= 5
  const int wave = tid >> 6, lane = tid & 63;
  const int mw = (wave & 1) * 64, nwv = (wave >> 1) * 64;
  const int lr = lane & 15, lk = lane >> 4;
  const int arow = tid >> 2, acol = (tid & 3) * 8;  // 128 rows x 4x8
  const int q = m0 + arow;

  for (int t = tid; t < 128 * jcnt; t += 512) {
    int r = t & 127, jj = t >> 7;
    int j = jbeg + jj;
    s_vidx[t] = (short)((j < 49) ? vidx[(m0 + r) * 49 + j] : -1);
  }
  for (int t = tid; t < 128 * 8 * jcnt; t += 512) {
    int h = t & 7, rr = (t >> 3) & 127, jj = t >> 10;
    int j = jbeg + jj;
    s_attn[t] = (j < 49) ? attnval[((size_t)((m0 + rr) * 49 + j)) * 8 + h] : 0.f;
  }
  __syncthreads();   // full drain: preload loads retired before pipeline starts

  auto loadA = [&](int k0, uint4& kv, float& w) {
    const int k = k0 + acol;
    const int j = k >> 8, c = k & 255;
    kv = uint4{0u, 0u, 0u, 0u};
    w = 0.f;
    if (j < 49) {
      const int jj = j - jbeg;
      int id = s_vidx[jj * 128 + arow];
      if (id >= 0) {
        w = s_attn[(jj * 128 + arow) * 8 + (c >> 5)];
        kv = *(const uint4*)(fqkvV + (size_t)id * 256 + c);   // 8 bf16
      }
    } else if (c == 0) {
      kv.x = pk2(cell[q * 2], cell[q * 2 + 1]);  // cell = 1/64, exact in bf16
      w = 64.f;
    }
  };

  frag_cd acc[4][4] = {};
  uint4 kvc; float wc_;
  const u16* bbase = Bt + (size_t)(tid >> 2) * KBIG + (tid & 3) * 8 + kbeg;

  // prologue: B tile 0 -> buffer 0 (2 glds in flight), A(0) -> regs
  glds16(bbase, &Bs[(size_t)tid * 8]);
  glds16(bbase + (size_t)128 * KBIG, &Bs[(size_t)tid * 8 + 4096]);
  loadA(kbeg, kvc, wc_);

  int par = 0;
  for (int k0 = kbeg; k0 < kend; k0 += BK, par ^= 1) {
    // stage A(t): unpack bf16 pair -> f32, scale by attn weight, repack.
    {
      u32 aw[4] = {kvc.x, kvc.y, kvc.z, kvc.w};
      uint4 av;
      u32 avw[4];
      #pragma unroll
      for (int t = 0; t < 4; t++) {
        float lo = __uint_as_float(aw[t] << 16) * wc_;
        float hi = __uint_as_float(aw[t] & 0xffff0000u) * wc_;
        avw[t] = pk2(lo, hi);
      }
      av.x = avw[0]; av.y = avw[1]; av.z = avw[2]; av.w = avw[3];
      *(uint4*)&As[arow * LDSS + acol] = av;
    }
    if (k0 + BK < kend) {
      // issue B(t+1) into the other buffer; keep it in flight across the
      // barrier — only the 2 newest VMEM ops may remain outstanding, so
      // vmcnt(2) guarantees B(t) (older) has landed.
      u16* bd = &Bs[(size_t)(par ^ 1) * 8192 + (size_t)tid * 8];
      glds16(bbase + (k0 + BK - kbeg), bd);
      glds16(bbase + (k0 + BK - kbeg) + (size_t)128 * KBIG, bd + 4096);
      asm volatile("s_waitcnt vmcnt(2) lgkmcnt(0)" ::: "memory");
    } else {
      asm volatile("s_waitcnt vmcnt(0) lgkmcnt(0)" ::: "memory");
    }
    __builtin_amdgcn_s_barrier();
    if (k0 + BK < kend) loadA(k0 + BK, kvc, wc_);   // A prefetch (compiler-waited)
    const u16* bsrc = &Bs[(size_t)par * 8192];
    frag_ab af[4];
    #pragma unroll
    for (int i = 0; i < 4; i++)
      af[i] = *(const frag_ab*)&As[(mw + i * 16 + lr) * LDSS + lk * 8];
    #pragma unroll
    for (int j = 0; j < 4; j++) {
      frag_ab bf = *(const frag_ab*)&bsrc[(nwv + j * 16 + lr) * 32 + lk * 8];
      #pragma unroll
      for (int i = 0; i < 4; i++)
        acc[i][j] = __builtin_amdgcn_mfma_f32_16x16x32_bf16(af[i], bf, acc[i][j], 0, 0, 0);
    }
    asm volatile("s_waitcnt lgkmcnt(0)" ::: "memory");
    __builtin_amdgcn_s_barrier();
  }

  #pragma unroll
  for (int i = 0; i < 4; i++)
    #pragma unroll
    for (int j = 0; j < 4; j++) {
      int col = nwv + j * 16 + lr;
      #pragma unroll
      for (int r = 0; r < 4; r++) {
        int row = m0 + mw + i * 16 + lk * 4 + r;
        P[(size_t)z * (NQ * 256) + (size_t)row * 256 + col] = f2b(acc[i][j][r]);
      }
    }
}

// ---------------------------------------------------------------------------
// Fused: hid2 = relu(sum_z Pb + bi1); out = bi2 + skip + hid2 . Wi2^T.
// ---------------------------------------------------------------------------
__global__ __launch_bounds__(256)
void reduce_final(const u16* __restrict__ Pb, const float* __restrict__ bi1,
                  const float* __restrict__ Wi2, const float* __restrict__ bi2,
                  const float* __restrict__ skipb, float* __restrict__ out)
{
  const int q = blockIdx.x, c = threadIdx.x;
  float s = 0.f;
  #pragma unroll
  for (int z = 0; z < SPLITK; z++)
    s += b2f(Pb[(size_t)z * (NQ * 256) + (size_t)q * 256 + c]);
  s += bi1[c];
  s = fmaxf(s, 0.f);

  __shared__ float part[3][4];
  float p0 = s * Wi2[c], p1 = s * Wi2[256 + c], p2 = s * Wi2[512 + c];
  #pragma unroll
  for (int off = 32; off; off >>= 1) {
    p0 += __shfl_xor(p0, off);
    p1 += __shfl_xor(p1, off);
    p2 += __shfl_xor(p2, off);
  }
  if ((c & 63) == 0) {
    int w = c >> 6;
    part[0][w] = p0; part[1][w] = p1; part[2][w] = p2;
  }
  __syncthreads();
  if (c < 3)
    out[q * 3 + c] = bi2[c] + skipb[q * 3 + c]
                   + part[c][0] + part[c][1] + part[c][2] + part[c][3];
}

// ---------------------------------------------------------------------------
// FUSED attention-weight chain: c1 MLP + c2 + softmax in one kernel.
// grid 256 blocks x 256 threads; each block owns 16 q rows.
// ---------------------------------------------------------------------------
__global__ __launch_bounds__(256)
void attn_wc(const u16* __restrict__ relbuf, const u16* __restrict__ Btc1,
             const float* __restrict__ bc1, const u16* __restrict__ Btc2,
             const float* __restrict__ bc2, float* __restrict__ attnval)
{
  __shared__ u16 s_rel[16 * 136];    // A: 16 q-rows x 128 (pad 136)
  __shared__ u16 s_hid[16 * 264];    // hid bf16: 16 x 256 (pad 264)
  __shared__ float s_wc[16 * 52];    // wc: 16 x 49 (pad 52)
  const int tid = threadIdx.x;
  const int m0 = blockIdx.x * 16;
  const int wave = tid >> 6, lane = tid & 63;
  const int lr = lane & 15, lk = lane >> 4;

  // load rel A tile: 16 rows x 128 = 256 uint4, one per thread
  {
    int r = tid >> 4, kc = (tid & 15) * 8;
    uint4 v = *(const uint4*)&relbuf[(size_t)(m0 + r) * 128 + kc];
    *(uint4*)&s_rel[r * 136 + kc] = v;
  }
  __syncthreads();

  // ---- c1: hid = relu(rel x Btc1^T + bc1); wave w covers cols w*64..+63
  frag_cd acc1[4] = {};
  #pragma unroll
  for (int k0 = 0; k0 < 128; k0 += 32) {
    frag_ab af = *(const frag_ab*)&s_rel[lr * 136 + k0 + lk * 8];
    #pragma unroll
    for (int j = 0; j < 4; j++) {
      int col = wave * 64 + j * 16 + lr;
      frag_ab bf = *(const frag_ab*)&Btc1[(size_t)col * 128 + k0 + lk * 8];
      acc1[j] = __builtin_amdgcn_mfma_f32_16x16x32_bf16(af, bf, acc1[j], 0, 0, 0);
    }
  }
  #pragma unroll
  for (int j = 0; j < 4; j++) {
    int col = wave * 64 + j * 16 + lr;
    float badd = bc1[col];
    #pragma unroll
    for (int r = 0; r < 4; r++) {
      int row = lk * 4 + r;
      s_hid[row * 264 + col] = f2b(fmaxf(acc1[j][r] + badd, 0.f));
    }
  }
  __syncthreads();

  // ---- c2: wc = hid x Btc2p^T + bc2; wave w covers cols w*16..+15
  frag_cd acc2 = {};
  #pragma unroll
  for (int k0 = 0; k0 < 256; k0 += 32) {
    frag_ab af = *(const frag_ab*)&s_hid[lr * 264 + k0 + lk * 8];
    frag_ab bf = *(const frag_ab*)&Btc2[(size_t)(wave * 16 + lr) * 256 + k0 + lk * 8];
    acc2 = __builtin_amdgcn_mfma_f32_16x16x32_bf16(af, bf, acc2, 0, 0, 0);
  }
  {
    int col = wave * 16 + lr;
    if (col < 49) {
      float badd = bc2[col];
      #pragma unroll
      for (int r = 0; r < 4; r++) {
        int row = lk * 4 + r;
        s_wc[row * 52 + col] = acc2[r] + badd;
      }
    }
  }
  __syncthreads();

  // ---- softmax per (q, h): threads 0..127, one pair each
  if (tid < 128) {
    const int qq = tid >> 3, h = tid & 7;
    float* avp = attnval + ((size_t)(m0 + qq) * 49) * 8 + h;
    float v[49];
    float m = -1e30f;
    #pragma unroll
    for (int l = 0; l < 49; l++) {
      v[l] = s_wc[qq * 52 + l] + avp[(size_t)l * 8];
      m = fmaxf(m, v[l]);
    }
    float ssum = 0.f;
    #pragma unroll
    for (int l = 0; l < 49; l++) { v[l] = expf(v[l] - m); ssum += v[l]; }
    float inv = 1.f / ssum;
    #pragma unroll
    for (int l = 0; l < 49; l++) avp[(size_t)l * 8] = v[l] * inv;
  }
}

// ---------------------------------------------------------------------------
// Merged weight-packing + encoder-conv kernel. Blocks [0, CONV_BLKS) run the
// encoder conv; remaining blocks pack weights.
// ---------------------------------------------------------------------------
static __device__ __forceinline__
void packconv(const float* __restrict__ W, u16* __restrict__ Bt,
              int Cin, int K2, int idx)
{
  int o  = idx / (Cin * K2);
  int r  = idx - o * (Cin * K2);
  int ci = r / K2;
  int s  = r - ci * K2;
  Bt[(size_t)o * (Cin * K2) + s * Cin + ci] = f2b(W[idx]);
}
static __device__ __forceinline__
void packcast(const float* __restrict__ W, u16* __restrict__ Bt,
              int Kin, int Kout, int idx)
{
  int n = idx / Kout, k = idx - n * Kout;
  Bt[idx] = f2b(k < Kin ? W[(size_t)n * Kin + k] : 0.f);
}

#define SZ_CH    147456   // 256*64*9
#define SZ_QKV   589824   // 256*256*9
#define SZ_OFF1  204800   // 256*32*25
#define SZ_OFF2P 28672    // 112*256 (W_off2 zero-padded to 112 rows)
#define SZ_C1    32768    // 256*128
#define SZ_C2P   16384    // 64*256 (Wc2 zero-padded to 64 rows)
#define SZ_WI1   3219456  // 256*12576
#define SZ_PACK (SZ_CH + 3*SZ_QKV + SZ_OFF1 + SZ_OFF2P + SZ_C1 + SZ_C2P + 768 + SZ_WI1)
#define CONV_BLKS 1024   // 4096 pixels, 4 per 256-thread block

__global__ __launch_bounds__(256)
void pack_enc(const float* W_ch, const float* W_q, const float* W_k,
              const float* W_v, const float* W_off1, const float* W_off2,
              const float* Wc1, const float* Wc2, const float* Wi1,
              const float* b_q, const float* b_k, const float* b_v,
              u16* Btch, u16* Btqkv, u16* Btoff1, u16* Btoff2,
              u16* Btc1, u16* Btc2, u16* Wi1p, float* bqkv,
              const float* __restrict__ inp, const float* __restrict__ W_enc,
              const float* __restrict__ b_enc, u16* __restrict__ feat1)
{
  const int bid = blockIdx.x;
  const int tid = threadIdx.x;
  if (bid < CONV_BLKS) {
    // ----- encoder conv: 3->64, 3x3 pad1, +bias, relu -----
    const int p = bid * 4 + (tid >> 6), c = tid & 63;
    const int y = p >> 6, x = p & 63;
    float s = b_enc[c];
    #pragma unroll
    for (int ci = 0; ci < 3; ci++)
      #pragma unroll
      for (int dy = 0; dy < 3; dy++) {
        int yy = y + dy - 1;
        if ((unsigned)yy >= 64u) continue;
        #pragma unroll
        for (int dx = 0; dx < 3; dx++) {
          int xx = x + dx - 1;
          if ((unsigned)xx >= 64u) continue;
          s += inp[ci * HW + yy * 64 + xx] * W_enc[((c * 3 + ci) * 3 + dy) * 3 + dx];
        }
      }
    feat1[(size_t)p * 64 + c] = f2b(fmaxf(s, 0.f));
    return;
  }
  int i = (bid - CONV_BLKS) * 256 + tid;
  if (i < SZ_CH) { packconv(W_ch, Btch, 64, 9, i); return; }
  i -= SZ_CH;
  if (i < SZ_QKV) { packconv(W_q, Btqkv, 256, 9, i); return; }
  i -= SZ_QKV;
  if (i < SZ_QKV) { packconv(W_k, Btqkv + (size_t)256 * 2304, 256, 9, i); return; }
  i -= SZ_QKV;
  if (i < SZ_QKV) { packconv(W_v, Btqkv + (size_t)512 * 2304, 256, 9, i); return; }
  i -= SZ_QKV;
  if (i < SZ_OFF1) { packconv(W_off1, Btoff1, 32, 25, i); return; }
  i -= SZ_OFF1;
  if (i < SZ_OFF2P) {
    // W_off2 (98x256 1x1 conv) -> 112-row zero-padded row-major
    int n = i >> 8, k = i & 255;
    Btoff2[i] = f2b(n < 98 ? W_off2[n * 256 + k] : 0.f);
    return;
  }
  i -= SZ_OFF2P;
  if (i < SZ_C1) { packcast(Wc1, Btc1, 98, 128, i); return; }
  i -= SZ_C1;
  if (i < SZ_C2P) {
    // Wc2 (49x256) -> 64-row zero-padded row-major (for attn_wc B-frags)
    int n = i >> 8, k = i & 255;
    Btc2[i] = f2b(n < 49 ? Wc2[n * 256 + k] : 0.f);
    return;
  }
  i -= SZ_C2P;
  if (i < 768) {
    bqkv[i] = (i < 256) ? b_q[i] : (i < 512) ? b_k[i - 256] : b_v[i - 512];
    return;
  }
  i -= 768;
  if (i < SZ_WI1) { packcast(Wi1, Wi1p, 12546, 12576, i); }
}

// ---------------------------------------------------------------------------
// Per-query sampler (writes raw q.k dots to attnval; attn_wc finalizes).
// ---------------------------------------------------------------------------
__global__ __launch_bounds__(256)
void sampler(const float* __restrict__ coord, const u16* __restrict__ fqkvb,
             const float* __restrict__ offs, const float* __restrict__ inp,
             float* __restrict__ attnval, u16* __restrict__ relbuf,
             int* __restrict__ vidx, float* __restrict__ skipb)
{
  const int q = blockIdx.x;
  const int tid = threadIdx.x;
  __shared__ float s_off[98];
  __shared__ int s_idx[49];
  __shared__ float s_q[256];

  const float c0 = coord[q * 2], c1 = coord[q * 2 + 1];
  const float gxp = ((c1 + 1.f) * 64.f - 1.f) * 0.5f;
  const float gyp = ((c0 + 1.f) * 64.f - 1.f) * 0.5f;
  const int ixn = (int)rintf(gxp), iyn = (int)rintf(gyp);
  const bool inn = ((unsigned)ixn < 64u) && ((unsigned)iyn < 64u);

  if (tid < 98) {
    float v = inn ? offs[(size_t)(iyn * 64 + ixn) * 98 + tid] : 0.f;
    s_off[tid] = tanhf(v) * (2.f / 63.f);
  }
  __syncthreads();

  const float scky = inn ? (-1.f + (float)(2 * iyn + 1) * (1.f / 64.f)) : 0.f;
  const float sckx = inn ? (-1.f + (float)(2 * ixn + 1) * (1.f / 64.f)) : 0.f;

  if (tid < 49) {
    const int a = tid / 7, bb = tid - a * 7;
    float sy = scky + (float)(a - 3) * (2.f / 64.f) + s_off[2 * tid];
    float sx = sckx + (float)(bb - 3) * (2.f / 64.f) + s_off[2 * tid + 1];
    relbuf[(size_t)q * 128 + 2 * tid]     = f2b((c0 - sy) * 64.f);
    relbuf[(size_t)q * 128 + 2 * tid + 1] = f2b((c1 - sx) * 64.f);
    float gx2 = ((sx + 1.f) * 64.f - 1.f) * 0.5f;
    float gy2 = ((sy + 1.f) * 64.f - 1.f) * 0.5f;
    int ix2 = (int)rintf(gx2), iy2 = (int)rintf(gy2);
    int id = (((unsigned)ix2 < 64u) && ((unsigned)iy2 < 64u)) ? (iy2 * 64 + ix2) : -1;
    s_idx[tid] = id;
    vidx[q * 49 + tid] = id;
  } else if (tid >= 98 && tid < 128) {
    relbuf[(size_t)q * 128 + tid] = 0;
  }

  {
    const float x0f = floorf(gxp), y0f = floorf(gyp);
    const float wx = gxp - x0f, wy = gyp - y0f;
    const int x0 = (int)x0f, y0 = (int)y0f;
    float qc = 0.f;
    #pragma unroll
    for (int t = 0; t < 4; t++) {
      int xi = x0 + (t & 1), yi = y0 + (t >> 1);
      if (((unsigned)xi < 64u) && ((unsigned)yi < 64u)) {
        float w = ((t & 1) ? wx : 1.f - wx) * ((t >> 1) ? wy : 1.f - wy);
        qc += w * b2f(fqkvb[(size_t)(yi * 64 + xi) * 768 + tid]);
      }
    }
    s_q[tid] = qc * 0.17677669529663687f;
  }

  if (tid < 3) {
    float gx = fminf(fmaxf(gxp, 0.f), 63.f);
    float gy = fminf(fmaxf(gyp, 0.f), 63.f);
    float xf = floorf(gx), yf = floorf(gy);
    float wxs = gx - xf, wys = gy - yf;
    int xa = (int)xf, ya = (int)yf;
    int xb = min(xa + 1, 63), yb = min(ya + 1, 63);
    const float* ch = inp + tid * HW;
    float v = (1.f - wxs) * (1.f - wys) * ch[ya * 64 + xa]
            + wxs * (1.f - wys) * ch[ya * 64 + xb]
            + (1.f - wxs) * wys * ch[yb * 64 + xa]
            + wxs * wys * ch[yb * 64 + xb];
    skipb[q * 3 + tid] = v;
  }
  __syncthreads();

  const int wave = tid >> 6, lane = tid & 63;
  const int half = lane >> 5, sub = lane & 31;
  const int ch0 = sub * 8;
  const int h = sub >> 2;
  float qv[8];
  #pragma unroll
  for (int i = 0; i < 8; i++) qv[i] = s_q[ch0 + i];

  for (int it = 0; it < 7; it++) {
    int j = it * 8 + wave * 2 + half;
    if (j >= 49) break;
    int id = s_idx[j];
    float p = 0.f;
    if (id >= 0) {
      uint4 kv = *(const uint4*)&fqkvb[(size_t)id * 768 + 256 + ch0];
      u32 w0 = kv.x, w1 = kv.y, w2 = kv.z, w3 = kv.w;
      p = fmaf(qv[0], __uint_as_float(w0 << 16), p);
      p = fmaf(qv[1], __uint_as_float(w0 & 0xffff0000u), p);
      p = fmaf(qv[2], __uint_as_float(w1 << 16), p);
      p = fmaf(qv[3], __uint_as_float(w1 & 0xffff0000u), p);
      p = fmaf(qv[4], __uint_as_float(w2 << 16), p);
      p = fmaf(qv[5], __uint_as_float(w2 & 0xffff0000u), p);
      p = fmaf(qv[6], __uint_as_float(w3 << 16), p);
      p = fmaf(qv[7], __uint_as_float(w3 & 0xffff0000u), p);
    }
    p += __shfl_down(p, 2, 4);
    p += __shfl_down(p, 1, 4);
    if ((sub & 3) == 0) attnval[((size_t)q * 49 + j) * 8 + h] = p;
  }
}

// ===========================================================================
extern "C" void kernel_launch(void* const* d_in, const int* in_sizes, int n_in,
                              void* d_out, int out_size, void* d_ws, size_t ws_size,
                              hipStream_t stream)
{
  const float* inp    = (const float*)d_in[0];
  const float* coord  = (const float*)d_in[1];
  const float* cell   = (const float*)d_in[2];
  const float* W_enc  = (const float*)d_in[3];
  const float* b_enc  = (const float*)d_in[4];
  const float* W_ch   = (const float*)d_in[5];
  const float* b_ch   = (const float*)d_in[6];
  const float* W_q    = (const float*)d_in[7];
  const float* b_q    = (const float*)d_in[8];
  const float* W_k    = (const float*)d_in[9];
  const float* b_k    = (const float*)d_in[10];
  const float* W_v    = (const float*)d_in[11];
  const float* b_v    = (const float*)d_in[12];
  const float* W_off1 = (const float*)d_in[13];
  const float* b_off1 = (const float*)d_in[14];
  const float* ln_g   = (const float*)d_in[15];
  const float* ln_b   = (const float*)d_in[16];
  const float* W_off2 = (const float*)d_in[17];
  const float* Wc1    = (const float*)d_in[18];
  const float* bc1    = (const float*)d_in[19];
  const float* Wc2    = (const float*)d_in[20];
  const float* bc2    = (const float*)d_in[21];
  const float* Wi1    = (const float*)d_in[22];
  const float* bi1    = (const float*)d_in[23];
  const float* Wi2    = (const float*)d_in[24];
  const float* bi2    = (const float*)d_in[25];

  char* base = (char*)d_ws;
  size_t off = 0;
  auto alloc = [&](size_t bytes) -> char* {
    char* r = base + off;
    off = (off + bytes + 255) & ~(size_t)255;
    return r;
  };

  // --- scratch region (dead before gemm_big runs; Pb aliases it) ---
  float* obuf   = (float*)alloc((size_t)HW * 256 * 4);
  float* offsb  = (float*)alloc((size_t)HW * 98 * 4);
  u16*   feat1  = (u16*)  alloc((size_t)HW * 64 * 2);
  u16*   feat   = (u16*)  alloc((size_t)HW * 256 * 2);
  u16*   relbuf = (u16*)  alloc((size_t)NQ * 128 * 2);
  u16*   Btqkv  = (u16*)  alloc((size_t)768 * 2304 * 2);
  u16*   Btch   = (u16*)  alloc((size_t)256 * 576 * 2);
  u16*   Btoff1 = (u16*)  alloc((size_t)256 * 800 * 2);
  u16*   Btoff2 = (u16*)  alloc((size_t)112 * 256 * 2);
  u16*   Btc1   = (u16*)  alloc((size_t)256 * 128 * 2);
  u16*   Btc2   = (u16*)  alloc((size_t)64 * 256 * 2);
  // gemm_big bf16 partials alias scratch: 16 x 2MB = 33.6MB at base+0.
  u16* Pb = (u16*)base;
  // qkv bf16 partials at [36MB, 54.9MB): past live scratch (~16MB),
  // disjoint from Pb's 33.6MB, dead before gemm_big.
  u16* Pqb = (u16*)(base + ((size_t)36 << 20));
  {
    size_t need = ((size_t)36 << 20) + (size_t)QSPLIT * NQ * 768 * 2;
    if (off < need) off = (need + 255) & ~(size_t)255;
  }
  // --- persistent buffers ---
  u16*   fqkvb   = (u16*)  alloc((size_t)HW * 768 * 2);
  u16*   fqkvVb  = (u16*)  alloc((size_t)HW * 256 * 2);
  float* attnval = (float*)alloc((size_t)NQ * 49 * 8 * 4);
  int*   vidxb   = (int*)  alloc((size_t)NQ * 49 * 4);
  float* skipb   = (float*)alloc((size_t)NQ * 3 * 4);
  u16*   Wi1p    = (u16*)  alloc((size_t)256 * KBIG * 2);
  float* bqkv    = (float*)alloc(768 * 4);
  (void)ws_size; (void)in_sizes; (void)n_in; (void)out_size;

  // --- weight packing ∥ encoder conv (merged: both input-only) ---
  pack_enc<<<CONV_BLKS + (SZ_PACK + 255) / 256, 256, 0, stream>>>(
      W_ch, W_q, W_k, W_v, W_off1, W_off2, Wc1, Wc2, Wi1, b_q, b_k, b_v,
      Btch, Btqkv, Btoff1, Btoff2, Btc1, Btc2, Wi1p, bqkv,
      inp, W_enc, b_enc, feat1);

  // --- conv stack ---
  gemm_conv<3, 6, 1><<<dim3(64, 4, 1), 256, 0, stream>>>(
      feat1, Btch, feat, b_ch, 256, 576, 256, /*bf16*/2, 64, 0, 0, 0, 0);
  // merged qkv + off1 (overlap)
  gemm_feat<<<NBLK_QKV + NBLK_OFF1, 256, 0, stream>>>(
      feat, Btqkv, Pqb, Btoff1, obuf, b_off1);
  // merged reduce_qkv ∥ (ln_gelu + off2 1x1-conv MFMA)
  post_feat<<<RQ_BLKS + LNO_BLKS, 256, 0, stream>>>(
      Pqb, bqkv, fqkvb, fqkvVb, obuf, ln_g, ln_b, Btoff2, offsb);

  // --- per-query attention path ---
  sampler<<<NQ, 256, 0, stream>>>(coord, fqkvb, offsb, inp,
                                  attnval, relbuf, vidxb, skipb);
  // fused c1 + c2 + softmax
  attn_wc<<<NQ / 16, 256, 0, stream>>>(relbuf, Btc1, bc1, Btc2, bc2, attnval);

  // --- big MLP: 128x256 tile, bf16 gather-A, dbuf glds-B + counted vmcnt,
  //     split-K(16), bf16 partials ---
  gemm_big<<<dim3(32, SPLITK), 512, 0, stream>>>(
      Wi1p, fqkvVb, attnval, vidxb, cell, Pb);
  reduce_final<<<NQ, 256, 0, stream>>>(Pb, bi1, Wi2, bi2, skipb, (float*)d_out);
}

// Round 10
// 259.793 us; speedup vs baseline: 1.1812x; 1.0101x over previous
//
#include <hip/hip_runtime.h>
#include <hip/hip_bf16.h>

// ============================================================================
// IDASR pipeline on gfx950 — round 24.
// r23 post-mortem: ln_gelu+off2 fusion gained 6us (262.4, best). The launch
// chain is now a true dependency chain EXCEPT one hidden split:
// gemm_conv needs only feat1+Btch, but waited on the FULL pack (Wi1/qkv/...
// = 95% of pack blocks) in pack_enc.
// Change (single structural variable, proven launch-merge pattern):
//  * pack split: pack_enc = conv_enc ∥ Btch-pack only (1600 blocks);
//    NEW conv_pack = ch-conv GEMM (256 blocks, first) ∥ ALL remaining
//    packing (20595 blocks) — nothing there is read before gemm_feat.
//  * gemm_conv template deleted (body inlined into conv_pack branch).
// Launch count stays 8; heavy pack moves off the critical path.
// ============================================================================

typedef unsigned short u16;
typedef unsigned int u32;
using frag_ab = __attribute__((ext_vector_type(8))) short;  // 8 x bf16
using frag_cd = __attribute__((ext_vector_type(4))) float;  // 4 x f32 acc

#define HW 4096
#define NQ 4096
#define KBIG 12576
#define SPLITK 16
#define KCHUNK 800
#define JMAX 5
#define KQ 2304
#define QSPLIT 3
#define QCHUNK 768
#define NBLK_QKV (64 * 6 * QSPLIT)   // 1152
#define NBLK_OFF1 (64 * 8)           // 512

static __device__ __forceinline__ u16 f2b(float f) {
  union { __hip_bfloat16 h; u16 u; } c; c.h = __float2bfloat16(f); return c.u;
}
static __device__ __forceinline__ float b2f(u16 v) {
  return __uint_as_float((u32)v << 16);
}
static __device__ __forceinline__ u32 pk2(float a, float b) {
  union { __hip_bfloat162 h; u32 u; } c;
  c.h = __float22bfloat162_rn(float2{a, b});
  return c.u;
}
// async global->LDS, 16B per lane. LDS dest is wave-uniform base + lane*16.
static __device__ __forceinline__ void glds16(const u16* g, u16* l) {
  __builtin_amdgcn_global_load_lds(
      (const __attribute__((address_space(1))) u32*)(g),
      (__attribute__((address_space(3))) u32*)(l), 16, 0, 0);
}

#define BM 64
#define BN 64
#define BK 32
#define LDSS 40   // padded lds row stride for reg-staged tiles

// ---------------------------------------------------------------------------
// Merged feat-consumer kernel: blocks [0,1152) = qkv GEMM (64x128 tile,
// implicit im2col A, glds-B, split-K(3), bf16 partials); blocks
// [1152,1664) = grouped 5x5 off1 conv (64x64 tile). One launch -> overlap.
// ---------------------------------------------------------------------------
__global__ __launch_bounds__(256)
void gemm_feat(const u16* __restrict__ feat, const u16* __restrict__ Btqkv,
               u16* __restrict__ Pq, const u16* __restrict__ Btoff1,
               float* __restrict__ obuf, const float* __restrict__ b_off1)
{
  __shared__ u16 smem[6656];   // 13.3 KB: qkv As(2560)+Bs(4096); off1 uses 5120
  const int bid = blockIdx.x;
  const int tid = threadIdx.x;
  const int wave = tid >> 6, lane = tid & 63;
  const int lr = lane & 15, lk = lane >> 4;

  if (bid < NBLK_QKV) {
    // ----- qkv branch -----
    u16* As = smem;            // 64 * 40
    u16* Bs = smem + 64 * 40;  // 128 * 32, glds target
    const int mz  = bid & 63;
    const int rest = bid >> 6;
    const int ny  = rest % 6;
    const int z   = rest / 6;
    const int m0  = mz * 64;
    const int n0  = ny * 128;
    const int kbeg = z * QCHUNK;
    const int kend = kbeg + QCHUNK;
    const int nw = wave * 32;
    const int arow = tid >> 2, acol = (tid & 3) * 8;
    const int p = m0 + arow, y = p >> 6, x = p & 63;

    frag_cd acc[4][2] = {};
    const u16* bbase = Btqkv + (size_t)(n0 + (tid >> 2)) * KQ + (tid & 3) * 8 + kbeg;
    u16* bdst = &Bs[(size_t)tid * 8];

    auto stageA = [&](int k0) -> uint4 {
      int k = k0 + acol;
      int s = k >> 8, c = k & 255;
      int dy = s / 3, dx = s - dy * 3;
      int yy = y + dy - 1, xx = x + dx - 1;
      if (((unsigned)yy < 64u) && ((unsigned)xx < 64u))
        return *(const uint4*)&feat[(size_t)(yy * 64 + xx) * 256 + c];
      return uint4{0u, 0u, 0u, 0u};
    };

    uint4 av = stageA(kbeg);

    for (int k0 = kbeg; k0 < kend; k0 += BK) {
      glds16(bbase + (k0 - kbeg), bdst);
      glds16(bbase + (k0 - kbeg) + (size_t)64 * KQ, bdst + 2048);
      *(uint4*)&As[arow * LDSS + acol] = av;
      __syncthreads();
      if (k0 + BK < kend) av = stageA(k0 + BK);
      frag_ab af[4];
      #pragma unroll
      for (int i = 0; i < 4; i++)
        af[i] = *(const frag_ab*)&As[(i * 16 + lr) * LDSS + lk * 8];
      #pragma unroll
      for (int j = 0; j < 2; j++) {
        frag_ab bf = *(const frag_ab*)&Bs[(nw + j * 16 + lr) * 32 + lk * 8];
        #pragma unroll
        for (int i = 0; i < 4; i++)
          acc[i][j] = __builtin_amdgcn_mfma_f32_16x16x32_bf16(af[i], bf, acc[i][j], 0, 0, 0);
      }
      __syncthreads();
    }

    #pragma unroll
    for (int i = 0; i < 4; i++)
      #pragma unroll
      for (int j = 0; j < 2; j++) {
        int col = n0 + nw + j * 16 + lr;
        #pragma unroll
        for (int r = 0; r < 4; r++) {
          int row = m0 + i * 16 + lk * 4 + r;
          Pq[(size_t)z * (NQ * 768) + (size_t)row * 768 + col] = f2b(acc[i][j][r]);
        }
      }
  } else {
    // ----- off1 grouped conv branch (5x5 pad2, 32 ch/group) -----
    u16* As = smem;            // 64 * 40
    u16* Bs = smem + 64 * 40;  // 64 * 40
    const int t  = bid - NBLK_QKV;
    const int m0 = (t & 63) * 64;
    const int g  = t >> 6;               // group 0..7
    const int cb = g * 32;
    const u16* Bt = Btoff1 + (size_t)g * 32 * 800;
    const float* bz = b_off1 + g * 32;
    const int mw = (wave & 1) * 32, nw = (wave >> 1) * 32;
    const int srow = tid >> 2, scol = (tid & 3) * 8;
    const int p = m0 + srow, y = p >> 6, x = p & 63;

    frag_cd acc[2][2] = {};
    const bool bok  = srow < 32;
    const u16* bptr = Bt + (size_t)srow * 800 + scol;

    auto stageA = [&](int k0) -> uint4 {
      int k = k0 + scol;
      int s = k >> 5;
      int c = k & 31;
      int dy = s / 5, dx = s - dy * 5;
      int yy = y + dy - 2, xx = x + dx - 2;
      if (((unsigned)yy < 64u) && ((unsigned)xx < 64u))
        return *(const uint4*)&feat[(size_t)(yy * 64 + xx) * 256 + cb + c];
      return uint4{0u, 0u, 0u, 0u};
    };

    uint4 av = stageA(0);
    uint4 bv = bok ? *(const uint4*)(bptr) : uint4{0u, 0u, 0u, 0u};

    for (int k0 = 0; k0 < 800; k0 += BK) {
      *(uint4*)&As[srow * LDSS + scol] = av;
      *(uint4*)&Bs[srow * LDSS + scol] = bv;
      __syncthreads();
      if (k0 + BK < 800) {
        av = stageA(k0 + BK);
        bv = bok ? *(const uint4*)(bptr + k0 + BK) : uint4{0u, 0u, 0u, 0u};
      }
      frag_ab af0 = *(const frag_ab*)&As[(mw      + lr) * LDSS + lk * 8];
      frag_ab af1 = *(const frag_ab*)&As[(mw + 16 + lr) * LDSS + lk * 8];
      frag_ab bf0 = *(const frag_ab*)&Bs[(nw      + lr) * LDSS + lk * 8];
      frag_ab bf1 = *(const frag_ab*)&Bs[(nw + 16 + lr) * LDSS + lk * 8];
      acc[0][0] = __builtin_amdgcn_mfma_f32_16x16x32_bf16(af0, bf0, acc[0][0], 0, 0, 0);
      acc[0][1] = __builtin_amdgcn_mfma_f32_16x16x32_bf16(af0, bf1, acc[0][1], 0, 0, 0);
      acc[1][0] = __builtin_amdgcn_mfma_f32_16x16x32_bf16(af1, bf0, acc[1][0], 0, 0, 0);
      acc[1][1] = __builtin_amdgcn_mfma_f32_16x16x32_bf16(af1, bf1, acc[1][1], 0, 0, 0);
      __syncthreads();
    }

    #pragma unroll
    for (int i = 0; i < 2; i++)
      #pragma unroll
      for (int j = 0; j < 2; j++) {
        int col = nw + j * 16 + lr;
        if (col >= 32) continue;
        float badd = bz[col];
        #pragma unroll
        for (int r = 0; r < 4; r++) {
          int row = m0 + mw + i * 16 + lk * 4 + r;
          obuf[(size_t)row * 256 + g * 32 + col] = acc[i][j][r] + badd;
        }
      }
  }
}

// ---------------------------------------------------------------------------
// Merged post-gemm_feat kernel:
//  blocks [0, RQ_BLKS)          : reduce_qkv (sum partials + bias)
//  blocks [RQ_BLKS, +LNO_BLKS)  : ln_gelu + off2 1x1-conv fused MFMA
// ---------------------------------------------------------------------------
#define RQ_BLKS 1536   // NQ*96/256
#define LNO_BLKS 256   // 4096 pixels / 16
__global__ __launch_bounds__(256)
void post_feat(const u16* __restrict__ P, const float* __restrict__ bias,
               u16* __restrict__ outb, u16* __restrict__ outV,
               const float* __restrict__ x, const float* __restrict__ g,
               const float* __restrict__ b, const u16* __restrict__ Btoff2,
               float* __restrict__ offsb)
{
  __shared__ u16 s_oc[16 * 264];   // lnoff2 branch only (8.25 KB)
  const int bid = blockIdx.x;
  const int tid = threadIdx.x;
  if (bid < RQ_BLKS) {
    // ----- reduce_qkv -----
    int i8 = bid * 256 + tid;
    size_t i = (size_t)i8 * 8;
    int row = (int)(i / 768);
    int c = (int)(i % 768);
    float v[8];
    #pragma unroll
    for (int t = 0; t < 8; t++) v[t] = bias[c + t];
    for (int z = 0; z < QSPLIT; z++) {
      uint4 a = *(const uint4*)&P[(size_t)z * (NQ * 768) + i];
      u32 aw[4] = {a.x, a.y, a.z, a.w};
      #pragma unroll
      for (int t = 0; t < 4; t++) {
        v[2 * t]     += __uint_as_float(aw[t] << 16);
        v[2 * t + 1] += __uint_as_float(aw[t] & 0xffff0000u);
      }
    }
    uint4 ob = {pk2(v[0], v[1]), pk2(v[2], v[3]), pk2(v[4], v[5]), pk2(v[6], v[7])};
    *(uint4*)&outb[i] = ob;
    if (c >= 512) {
      // bf16 V gather table: dense 2 MB (pos,256) layout for gemm_big.
      *(uint4*)&outV[(size_t)row * 256 + (c - 512)] = ob;
    }
  } else {
    // ----- ln_gelu + off2 (1x1 conv) fused, 16 pixels per block -----
    const int p0 = (bid - RQ_BLKS) * 16;
    const int p = tid >> 4, gl = tid & 15;   // pixel 0..15, 16-lane group
    float v[16];
    {
      const float* src = x + (size_t)(p0 + p) * 256 + gl * 16;
      #pragma unroll
      for (int t = 0; t < 4; t++) {
        float4 f = *(const float4*)(src + t * 4);
        v[4 * t] = f.x; v[4 * t + 1] = f.y; v[4 * t + 2] = f.z; v[4 * t + 3] = f.w;
      }
    }
    float s1 = 0.f, s2 = 0.f;
    #pragma unroll
    for (int t = 0; t < 16; t++) { s1 += v[t]; s2 += v[t] * v[t]; }
    #pragma unroll
    for (int off = 8; off; off >>= 1) {
      s1 += __shfl_xor(s1, off, 16);
      s2 += __shfl_xor(s2, off, 16);
    }
    float mu   = s1 * (1.f / 256.f);
    float var  = s2 * (1.f / 256.f) - mu * mu;
    float rstd = rsqrtf(var + 1e-5f);
    #pragma unroll
    for (int t = 0; t < 16; t++) {
      int c = gl * 16 + t;
      float xn = (v[t] - mu) * rstd * g[c] + b[c];
      float ge = 0.5f * xn * (1.f + erff(xn * 0.70710678118654752f));
      s_oc[p * 264 + c] = f2b(ge);
    }
    __syncthreads();
    // MFMA: out(16 x 112) = A(16 x 256) x Btoff2^T (112 rows, zero-padded).
    const int wave = tid >> 6, lane = tid & 63;
    const int lr = lane & 15, lk = lane >> 4;
    frag_cd a0 = {}, a1 = {};
    #pragma unroll
    for (int k0 = 0; k0 < 256; k0 += 32) {
      frag_ab af = *(const frag_ab*)&s_oc[lr * 264 + k0 + lk * 8];
      frag_ab bf0 = *(const frag_ab*)&Btoff2[(size_t)(wave * 16 + lr) * 256 + k0 + lk * 8];
      a0 = __builtin_amdgcn_mfma_f32_16x16x32_bf16(af, bf0, a0, 0, 0, 0);
      if (wave < 3) {
        frag_ab bf1 = *(const frag_ab*)&Btoff2[(size_t)((wave + 4) * 16 + lr) * 256 + k0 + lk * 8];
        a1 = __builtin_amdgcn_mfma_f32_16x16x32_bf16(af, bf1, a1, 0, 0, 0);
      }
    }
    {
      const int col0 = wave * 16 + lr;
      const int col1 = (wave + 4) * 16 + lr;
      #pragma unroll
      for (int r = 0; r < 4; r++) {
        int row = lk * 4 + r;
        offsb[(size_t)(p0 + row) * 98 + col0] = a0[r];   // col0 <= 63 < 98
        if (wave < 3 && col1 < 98)
          offsb[(size_t)(p0 + row) * 98 + col1] = a1[r];
      }
    }
  }
}

// ---------------------------------------------------------------------------
// Big MLP GEMM: fused gather-A (bf16 V, weight-mul + repack), 128x256 tile,
// double-buffered glds-B with counted-vmcnt pipeline, split-K(16), bf16
// partials. block 512 (8 waves), grid (32, 16) = 2/CU (reg-capped: ~60 VGPR
// + 64 AGPR unified; (512,4) — do NOT raise min-waves, r15 spilled).
// ---------------------------------------------------------------------------
__global__ __launch_bounds__(512, 4)
void gemm_big(const u16* __restrict__ Bt, const u16* __restrict__ fqkvV,
              const float* __restrict__ attnval, const int* __restrict__ vidx,
              const float* __restrict__ cell, u16* __restrict__ P)
{
  __shared__ u16 As[128 * LDSS];            // 10 KB padded, reg-staged gather
  __shared__ u16 Bs[2 * 256 * 32];          // 32 KB double-buffered glds target
  __shared__ short s_vidx[JMAX * 128];      // 1.25 KB (ids < 4096 fit short)
  __shared__ float s_attn[JMAX * 128 * 8];  // 20 KB
  const int tid  = threadIdx.x;
  const int m0   = blockIdx.x * 128;
  const int z    = blockIdx.y;
  const int kbeg = z * KCHUNK;
  const int kend = min(KBIG, kbeg + KCHUNK);
  const int jbeg = kbeg >> 8;
  const int jcnt = ((kend - 1) >> 8) - jbeg + 1;   // <= 5
  const int wave = tid >> 6, lane = tid & 63;
  const int mw = (wave & 1) * 64, nwv = (wave >> 1) * 64;
  const int lr = lane & 15, lk = lane >> 4;
  const int arow = tid >> 2, acol = (tid & 3) * 8;  // 128 rows x 4x8
  const int q = m0 + arow;

  for (int t = tid; t < 128 * jcnt; t += 512) {
    int r = t & 127, jj = t >> 7;
    int j = jbeg + jj;
    s_vidx[t] = (short)((j < 49) ? vidx[(m0 + r) * 49 + j] : -1);
  }
  for (int t = tid; t < 128 * 8 * jcnt; t += 512) {
    int h = t & 7, rr = (t >> 3) & 127, jj = t >> 10;
    int j = jbeg + jj;
    s_attn[t] = (j < 49) ? attnval[((size_t)((m0 + rr) * 49 + j)) * 8 + h] : 0.f;
  }
  __syncthreads();   // full drain: preload loads retired before pipeline starts

  auto loadA = [&](int k0, uint4& kv, float& w) {
    const int k = k0 + acol;
    const int j = k >> 8, c = k & 255;
    kv = uint4{0u, 0u, 0u, 0u};
    w = 0.f;
    if (j < 49) {
      const int jj = j - jbeg;
      int id = s_vidx[jj * 128 + arow];
      if (id >= 0) {
        w = s_attn[(jj * 128 + arow) * 8 + (c >> 5)];
        kv = *(const uint4*)(fqkvV + (size_t)id * 256 + c);   // 8 bf16
      }
    } else if (c == 0) {
      kv.x = pk2(cell[q * 2], cell[q * 2 + 1]);  // cell = 1/64, exact in bf16
      w = 64.f;
    }
  };

  frag_cd acc[4][4] = {};
  uint4 kvc; float wc_;
  const u16* bbase = Bt + (size_t)(tid >> 2) * KBIG + (tid & 3) * 8 + kbeg;

  // prologue: B tile 0 -> buffer 0 (2 glds in flight), A(0) -> regs
  glds16(bbase, &Bs[(size_t)tid * 8]);
  glds16(bbase + (size_t)128 * KBIG, &Bs[(size_t)tid * 8 + 4096]);
  loadA(kbeg, kvc, wc_);

  int par = 0;
  for (int k0 = kbeg; k0 < kend; k0 += BK, par ^= 1) {
    // stage A(t): unpack bf16 pair -> f32, scale by attn weight, repack.
    {
      u32 aw[4] = {kvc.x, kvc.y, kvc.z, kvc.w};
      uint4 av;
      u32 avw[4];
      #pragma unroll
      for (int t = 0; t < 4; t++) {
        float lo = __uint_as_float(aw[t] << 16) * wc_;
        float hi = __uint_as_float(aw[t] & 0xffff0000u) * wc_;
        avw[t] = pk2(lo, hi);
      }
      av.x = avw[0]; av.y = avw[1]; av.z = avw[2]; av.w = avw[3];
      *(uint4*)&As[arow * LDSS + acol] = av;
    }
    if (k0 + BK < kend) {
      // issue B(t+1) into the other buffer; keep it in flight across the
      // barrier — only the 2 newest VMEM ops may remain outstanding, so
      // vmcnt(2) guarantees B(t) (older) has landed.
      u16* bd = &Bs[(size_t)(par ^ 1) * 8192 + (size_t)tid * 8];
      glds16(bbase + (k0 + BK - kbeg), bd);
      glds16(bbase + (k0 + BK - kbeg) + (size_t)128 * KBIG, bd + 4096);
      asm volatile("s_waitcnt vmcnt(2) lgkmcnt(0)" ::: "memory");
    } else {
      asm volatile("s_waitcnt vmcnt(0) lgkmcnt(0)" ::: "memory");
    }
    __builtin_amdgcn_s_barrier();
    if (k0 + BK < kend) loadA(k0 + BK, kvc, wc_);   // A prefetch (compiler-waited)
    const u16* bsrc = &Bs[(size_t)par * 8192];
    frag_ab af[4];
    #pragma unroll
    for (int i = 0; i < 4; i++)
      af[i] = *(const frag_ab*)&As[(mw + i * 16 + lr) * LDSS + lk * 8];
    #pragma unroll
    for (int j = 0; j < 4; j++) {
      frag_ab bf = *(const frag_ab*)&bsrc[(nwv + j * 16 + lr) * 32 + lk * 8];
      #pragma unroll
      for (int i = 0; i < 4; i++)
        acc[i][j] = __builtin_amdgcn_mfma_f32_16x16x32_bf16(af[i], bf, acc[i][j], 0, 0, 0);
    }
    asm volatile("s_waitcnt lgkmcnt(0)" ::: "memory");
    __builtin_amdgcn_s_barrier();
  }

  #pragma unroll
  for (int i = 0; i < 4; i++)
    #pragma unroll
    for (int j = 0; j < 4; j++) {
      int col = nwv + j * 16 + lr;
      #pragma unroll
      for (int r = 0; r < 4; r++) {
        int row = m0 + mw + i * 16 + lk * 4 + r;
        P[(size_t)z * (NQ * 256) + (size_t)row * 256 + col] = f2b(acc[i][j][r]);
      }
    }
}

// ---------------------------------------------------------------------------
// Fused: hid2 = relu(sum_z Pb + bi1); out = bi2 + skip + hid2 . Wi2^T.
// ---------------------------------------------------------------------------
__global__ __launch_bounds__(256)
void reduce_final(const u16* __restrict__ Pb, const float* __restrict__ bi1,
                  const float* __restrict__ Wi2, const float* __restrict__ bi2,
                  const float* __restrict__ skipb, float* __restrict__ out)
{
  const int q = blockIdx.x, c = threadIdx.x;
  float s = 0.f;
  #pragma unroll
  for (int z = 0; z < SPLITK; z++)
    s += b2f(Pb[(size_t)z * (NQ * 256) + (size_t)q * 256 + c]);
  s += bi1[c];
  s = fmaxf(s, 0.f);

  __shared__ float part[3][4];
  float p0 = s * Wi2[c], p1 = s * Wi2[256 + c], p2 = s * Wi2[512 + c];
  #pragma unroll
  for (int off = 32; off; off >>= 1) {
    p0 += __shfl_xor(p0, off);
    p1 += __shfl_xor(p1, off);
    p2 += __shfl_xor(p2, off);
  }
  if ((c & 63) == 0) {
    int w = c >> 6;
    part[0][w] = p0; part[1][w] = p1; part[2][w] = p2;
  }
  __syncthreads();
  if (c < 3)
    out[q * 3 + c] = bi2[c] + skipb[q * 3 + c]
                   + part[c][0] + part[c][1] + part[c][2] + part[c][3];
}

// ---------------------------------------------------------------------------
// FUSED attention-weight chain: c1 MLP + c2 + softmax in one kernel.
// grid 256 blocks x 256 threads; each block owns 16 q rows.
// ---------------------------------------------------------------------------
__global__ __launch_bounds__(256)
void attn_wc(const u16* __restrict__ relbuf, const u16* __restrict__ Btc1,
             const float* __restrict__ bc1, const u16* __restrict__ Btc2,
             const float* __restrict__ bc2, float* __restrict__ attnval)
{
  __shared__ u16 s_rel[16 * 136];    // A: 16 q-rows x 128 (pad 136)
  __shared__ u16 s_hid[16 * 264];    // hid bf16: 16 x 256 (pad 264)
  __shared__ float s_wc[16 * 52];    // wc: 16 x 49 (pad 52)
  const int tid = threadIdx.x;
  const int m0 = blockIdx.x * 16;
  const int wave = tid >> 6, lane = tid & 63;
  const int lr = lane & 15, lk = lane >> 4;

  // load rel A tile: 16 rows x 128 = 256 uint4, one per thread
  {
    int r = tid >> 4, kc = (tid & 15) * 8;
    uint4 v = *(const uint4*)&relbuf[(size_t)(m0 + r) * 128 + kc];
    *(uint4*)&s_rel[r * 136 + kc] = v;
  }
  __syncthreads();

  // ---- c1: hid = relu(rel x Btc1^T + bc1); wave w covers cols w*64..+63
  frag_cd acc1[4] = {};
  #pragma unroll
  for (int k0 = 0; k0 < 128; k0 += 32) {
    frag_ab af = *(const frag_ab*)&s_rel[lr * 136 + k0 + lk * 8];
    #pragma unroll
    for (int j = 0; j < 4; j++) {
      int col = wave * 64 + j * 16 + lr;
      frag_ab bf = *(const frag_ab*)&Btc1[(size_t)col * 128 + k0 + lk * 8];
      acc1[j] = __builtin_amdgcn_mfma_f32_16x16x32_bf16(af, bf, acc1[j], 0, 0, 0);
    }
  }
  #pragma unroll
  for (int j = 0; j < 4; j++) {
    int col = wave * 64 + j * 16 + lr;
    float badd = bc1[col];
    #pragma unroll
    for (int r = 0; r < 4; r++) {
      int row = lk * 4 + r;
      s_hid[row * 264 + col] = f2b(fmaxf(acc1[j][r] + badd, 0.f));
    }
  }
  __syncthreads();

  // ---- c2: wc = hid x Btc2p^T + bc2; wave w covers cols w*16..+15
  frag_cd acc2 = {};
  #pragma unroll
  for (int k0 = 0; k0 < 256; k0 += 32) {
    frag_ab af = *(const frag_ab*)&s_hid[lr * 264 + k0 + lk * 8];
    frag_ab bf = *(const frag_ab*)&Btc2[(size_t)(wave * 16 + lr) * 256 + k0 + lk * 8];
    acc2 = __builtin_amdgcn_mfma_f32_16x16x32_bf16(af, bf, acc2, 0, 0, 0);
  }
  {
    int col = wave * 16 + lr;
    if (col < 49) {
      float badd = bc2[col];
      #pragma unroll
      for (int r = 0; r < 4; r++) {
        int row = lk * 4 + r;
        s_wc[row * 52 + col] = acc2[r] + badd;
      }
    }
  }
  __syncthreads();

  // ---- softmax per (q, h): threads 0..127, one pair each
  if (tid < 128) {
    const int qq = tid >> 3, h = tid & 7;
    float* avp = attnval + ((size_t)(m0 + qq) * 49) * 8 + h;
    float v[49];
    float m = -1e30f;
    #pragma unroll
    for (int l = 0; l < 49; l++) {
      v[l] = s_wc[qq * 52 + l] + avp[(size_t)l * 8];
      m = fmaxf(m, v[l]);
    }
    float ssum = 0.f;
    #pragma unroll
    for (int l = 0; l < 49; l++) { v[l] = expf(v[l] - m); ssum += v[l]; }
    float inv = 1.f / ssum;
    #pragma unroll
    for (int l = 0; l < 49; l++) avp[(size_t)l * 8] = v[l] * inv;
  }
}

// ---------------------------------------------------------------------------
// Packing helpers.
// ---------------------------------------------------------------------------
static __device__ __forceinline__
void packconv(const float* __restrict__ W, u16* __restrict__ Bt,
              int Cin, int K2, int idx)
{
  int o  = idx / (Cin * K2);
  int r  = idx - o * (Cin * K2);
  int ci = r / K2;
  int s  = r - ci * K2;
  Bt[(size_t)o * (Cin * K2) + s * Cin + ci] = f2b(W[idx]);
}
static __device__ __forceinline__
void packcast(const float* __restrict__ W, u16* __restrict__ Bt,
              int Kin, int Kout, int idx)
{
  int n = idx / Kout, k = idx - n * Kout;
  Bt[idx] = f2b(k < Kin ? W[(size_t)n * Kin + k] : 0.f);
}

#define SZ_CH    147456   // 256*64*9
#define SZ_QKV   589824   // 256*256*9
#define SZ_OFF1  204800   // 256*32*25
#define SZ_OFF2P 28672    // 112*256 (W_off2 zero-padded to 112 rows)
#define SZ_C1    32768    // 256*128
#define SZ_C2P   16384    // 64*256 (Wc2 zero-padded to 64 rows)
#define SZ_WI1   3219456  // 256*12576
#define SZ_REST (3*SZ_QKV + SZ_OFF1 + SZ_OFF2P + SZ_C1 + SZ_C2P + 768 + SZ_WI1)
#define CONV_BLKS 1024   // 4096 pixels, 4 per 256-thread block
#define CONV2_BLKS 256   // ch-conv GEMM: 64 m-tiles x 4 n-tiles

// ---------------------------------------------------------------------------
// Launch A: encoder conv ∥ Btch pack (only what gemm_conv needs next).
// ---------------------------------------------------------------------------
__global__ __launch_bounds__(256)
void pack_enc(const float* __restrict__ inp, const float* __restrict__ W_enc,
              const float* __restrict__ b_enc, u16* __restrict__ feat1,
              const float* __restrict__ W_ch, u16* __restrict__ Btch)
{
  const int bid = blockIdx.x;
  const int tid = threadIdx.x;
  if (bid < CONV_BLKS) {
    // ----- encoder conv: 3->64, 3x3 pad1, +bias, relu -----
    const int p = bid * 4 + (tid >> 6), c = tid & 63;
    const int y = p >> 6, x = p & 63;
    float s = b_enc[c];
    #pragma unroll
    for (int ci = 0; ci < 3; ci++)
      #pragma unroll
      for (int dy = 0; dy < 3; dy++) {
        int yy = y + dy - 1;
        if ((unsigned)yy >= 64u) continue;
        #pragma unroll
        for (int dx = 0; dx < 3; dx++) {
          int xx = x + dx - 1;
          if ((unsigned)xx >= 64u) continue;
          s += inp[ci * HW + yy * 64 + xx] * W_enc[((c * 3 + ci) * 3 + dy) * 3 + dx];
        }
      }
    feat1[(size_t)p * 64 + c] = f2b(fmaxf(s, 0.f));
    return;
  }
  int i = (bid - CONV_BLKS) * 256 + tid;
  if (i < SZ_CH) packconv(W_ch, Btch, 64, 9, i);
}

// ---------------------------------------------------------------------------
// Launch B: ch-conv GEMM (blocks [0,256), critical path) ∥ ALL remaining
// weight packing (nothing packed here is read before gemm_feat).
// ---------------------------------------------------------------------------
__global__ __launch_bounds__(256)
void conv_pack(const u16* __restrict__ feat1, const u16* __restrict__ Btch,
               u16* __restrict__ feat, const float* __restrict__ b_ch,
               const float* W_q, const float* W_k, const float* W_v,
               const float* W_off1, const float* W_off2,
               const float* Wc1, const float* Wc2, const float* Wi1,
               const float* b_q, const float* b_k, const float* b_v,
               u16* Btqkv, u16* Btoff1, u16* Btoff2,
               u16* Btc1, u16* Btc2, u16* Wi1p, float* bqkv)
{
  __shared__ u16 As[BM * LDSS];
  __shared__ u16 Bs[BN * LDSS];
  const int bid = blockIdx.x;
  const int tid = threadIdx.x;
  if (bid < CONV2_BLKS) {
    // ----- ch conv GEMM: 64x64 tile, im2col A (3x3 pad1, 64ch), bf16 out --
    const int m0 = (bid & 63) * 64;
    const int n0 = (bid >> 6) * 64;
    const int wave = tid >> 6, lane = tid & 63;
    const int mw = (wave & 1) * 32, nw = (wave >> 1) * 32;
    const int lr = lane & 15, lk = lane >> 4;
    const int srow = tid >> 2, scol = (tid & 3) * 8;
    const int p = m0 + srow, y = p >> 6, x = p & 63;

    frag_cd acc[2][2] = {};
    const u16* bptr = Btch + (size_t)(n0 + srow) * 576 + scol;

    auto stageA = [&](int k0) -> uint4 {
      int k = k0 + scol;
      int s = k >> 6;
      int c = k & 63;
      int dy = s / 3, dx = s - dy * 3;
      int yy = y + dy - 1, xx = x + dx - 1;
      if (((unsigned)yy < 64u) && ((unsigned)xx < 64u))
        return *(const uint4*)&feat1[(size_t)(yy * 64 + xx) * 64 + c];
      return uint4{0u, 0u, 0u, 0u};
    };

    uint4 av = stageA(0);
    uint4 bv = *(const uint4*)(bptr);

    for (int k0 = 0; k0 < 576; k0 += BK) {
      *(uint4*)&As[srow * LDSS + scol] = av;
      *(uint4*)&Bs[srow * LDSS + scol] = bv;
      __syncthreads();
      if (k0 + BK < 576) {
        av = stageA(k0 + BK);
        bv = *(const uint4*)(bptr + k0 + BK);
      }
      frag_ab af0 = *(const frag_ab*)&As[(mw      + lr) * LDSS + lk * 8];
      frag_ab af1 = *(const frag_ab*)&As[(mw + 16 + lr) * LDSS + lk * 8];
      frag_ab bf0 = *(const frag_ab*)&Bs[(nw      + lr) * LDSS + lk * 8];
      frag_ab bf1 = *(const frag_ab*)&Bs[(nw + 16 + lr) * LDSS + lk * 8];
      acc[0][0] = __builtin_amdgcn_mfma_f32_16x16x32_bf16(af0, bf0, acc[0][0], 0, 0, 0);
      acc[0][1] = __builtin_amdgcn_mfma_f32_16x16x32_bf16(af0, bf1, acc[0][1], 0, 0, 0);
      acc[1][0] = __builtin_amdgcn_mfma_f32_16x16x32_bf16(af1, bf0, acc[1][0], 0, 0, 0);
      acc[1][1] = __builtin_amdgcn_mfma_f32_16x16x32_bf16(af1, bf1, acc[1][1], 0, 0, 0);
      __syncthreads();
    }

    #pragma unroll
    for (int i = 0; i < 2; i++)
      #pragma unroll
      for (int j = 0; j < 2; j++) {
        int col = n0 + nw + j * 16 + lr;
        float badd = b_ch[col];
        #pragma unroll
        for (int r = 0; r < 4; r++) {
          int row = m0 + mw + i * 16 + lk * 4 + r;
          feat[(size_t)row * 256 + col] = f2b(acc[i][j][r] + badd);
        }
      }
    return;
  }
  // ----- remaining weight packing -----
  int i = (bid - CONV2_BLKS) * 256 + tid;
  if (i < SZ_QKV) { packconv(W_q, Btqkv, 256, 9, i); return; }
  i -= SZ_QKV;
  if (i < SZ_QKV) { packconv(W_k, Btqkv + (size_t)256 * 2304, 256, 9, i); return; }
  i -= SZ_QKV;
  if (i < SZ_QKV) { packconv(W_v, Btqkv + (size_t)512 * 2304, 256, 9, i); return; }
  i -= SZ_QKV;
  if (i < SZ_OFF1) { packconv(W_off1, Btoff1, 32, 25, i); return; }
  i -= SZ_OFF1;
  if (i < SZ_OFF2P) {
    int n = i >> 8, k = i & 255;
    Btoff2[i] = f2b(n < 98 ? W_off2[n * 256 + k] : 0.f);
    return;
  }
  i -= SZ_OFF2P;
  if (i < SZ_C1) { packcast(Wc1, Btc1, 98, 128, i); return; }
  i -= SZ_C1;
  if (i < SZ_C2P) {
    int n = i >> 8, k = i & 255;
    Btc2[i] = f2b(n < 49 ? Wc2[n * 256 + k] : 0.f);
    return;
  }
  i -= SZ_C2P;
  if (i < 768) {
    bqkv[i] = (i < 256) ? b_q[i] : (i < 512) ? b_k[i - 256] : b_v[i - 512];
    return;
  }
  i -= 768;
  if (i < SZ_WI1) { packcast(Wi1, Wi1p, 12546, 12576, i); }
}

// ---------------------------------------------------------------------------
// Per-query sampler (writes raw q.k dots to attnval; attn_wc finalizes).
// ---------------------------------------------------------------------------
__global__ __launch_bounds__(256)
void sampler(const float* __restrict__ coord, const u16* __restrict__ fqkvb,
             const float* __restrict__ offs, const float* __restrict__ inp,
             float* __restrict__ attnval, u16* __restrict__ relbuf,
             int* __restrict__ vidx, float* __restrict__ skipb)
{
  const int q = blockIdx.x;
  const int tid = threadIdx.x;
  __shared__ float s_off[98];
  __shared__ int s_idx[49];
  __shared__ float s_q[256];

  const float c0 = coord[q * 2], c1 = coord[q * 2 + 1];
  const float gxp = ((c1 + 1.f) * 64.f - 1.f) * 0.5f;
  const float gyp = ((c0 + 1.f) * 64.f - 1.f) * 0.5f;
  const int ixn = (int)rintf(gxp), iyn = (int)rintf(gyp);
  const bool inn = ((unsigned)ixn < 64u) && ((unsigned)iyn < 64u);

  if (tid < 98) {
    float v = inn ? offs[(size_t)(iyn * 64 + ixn) * 98 + tid] : 0.f;
    s_off[tid] = tanhf(v) * (2.f / 63.f);
  }
  __syncthreads();

  const float scky = inn ? (-1.f + (float)(2 * iyn + 1) * (1.f / 64.f)) : 0.f;
  const float sckx = inn ? (-1.f + (float)(2 * ixn + 1) * (1.f / 64.f)) : 0.f;

  if (tid < 49) {
    const int a = tid / 7, bb = tid - a * 7;
    float sy = scky + (float)(a - 3) * (2.f / 64.f) + s_off[2 * tid];
    float sx = sckx + (float)(bb - 3) * (2.f / 64.f) + s_off[2 * tid + 1];
    relbuf[(size_t)q * 128 + 2 * tid]     = f2b((c0 - sy) * 64.f);
    relbuf[(size_t)q * 128 + 2 * tid + 1] = f2b((c1 - sx) * 64.f);
    float gx2 = ((sx + 1.f) * 64.f - 1.f) * 0.5f;
    float gy2 = ((sy + 1.f) * 64.f - 1.f) * 0.5f;
    int ix2 = (int)rintf(gx2), iy2 = (int)rintf(gy2);
    int id = (((unsigned)ix2 < 64u) && ((unsigned)iy2 < 64u)) ? (iy2 * 64 + ix2) : -1;
    s_idx[tid] = id;
    vidx[q * 49 + tid] = id;
  } else if (tid >= 98 && tid < 128) {
    relbuf[(size_t)q * 128 + tid] = 0;
  }

  {
    const float x0f = floorf(gxp), y0f = floorf(gyp);
    const float wx = gxp - x0f, wy = gyp - y0f;
    const int x0 = (int)x0f, y0 = (int)y0f;
    float qc = 0.f;
    #pragma unroll
    for (int t = 0; t < 4; t++) {
      int xi = x0 + (t & 1), yi = y0 + (t >> 1);
      if (((unsigned)xi < 64u) && ((unsigned)yi < 64u)) {
        float w = ((t & 1) ? wx : 1.f - wx) * ((t >> 1) ? wy : 1.f - wy);
        qc += w * b2f(fqkvb[(size_t)(yi * 64 + xi) * 768 + tid]);
      }
    }
    s_q[tid] = qc * 0.17677669529663687f;
  }

  if (tid < 3) {
    float gx = fminf(fmaxf(gxp, 0.f), 63.f);
    float gy = fminf(fmaxf(gyp, 0.f), 63.f);
    float xf = floorf(gx), yf = floorf(gy);
    float wxs = gx - xf, wys = gy - yf;
    int xa = (int)xf, ya = (int)yf;
    int xb = min(xa + 1, 63), yb = min(ya + 1, 63);
    const float* ch = inp + tid * HW;
    float v = (1.f - wxs) * (1.f - wys) * ch[ya * 64 + xa]
            + wxs * (1.f - wys) * ch[ya * 64 + xb]
            + (1.f - wxs) * wys * ch[yb * 64 + xa]
            + wxs * wys * ch[yb * 64 + xb];
    skipb[q * 3 + tid] = v;
  }
  __syncthreads();

  const int wave = tid >> 6, lane = tid & 63;
  const int half = lane >> 5, sub = lane & 31;
  const int ch0 = sub * 8;
  const int h = sub >> 2;
  float qv[8];
  #pragma unroll
  for (int i = 0; i < 8; i++) qv[i] = s_q[ch0 + i];

  for (int it = 0; it < 7; it++) {
    int j = it * 8 + wave * 2 + half;
    if (j >= 49) break;
    int id = s_idx[j];
    float p = 0.f;
    if (id >= 0) {
      uint4 kv = *(const uint4*)&fqkvb[(size_t)id * 768 + 256 + ch0];
      u32 w0 = kv.x, w1 = kv.y, w2 = kv.z, w3 = kv.w;
      p = fmaf(qv[0], __uint_as_float(w0 << 16), p);
      p = fmaf(qv[1], __uint_as_float(w0 & 0xffff0000u), p);
      p = fmaf(qv[2], __uint_as_float(w1 << 16), p);
      p = fmaf(qv[3], __uint_as_float(w1 & 0xffff0000u), p);
      p = fmaf(qv[4], __uint_as_float(w2 << 16), p);
      p = fmaf(qv[5], __uint_as_float(w2 & 0xffff0000u), p);
      p = fmaf(qv[6], __uint_as_float(w3 << 16), p);
      p = fmaf(qv[7], __uint_as_float(w3 & 0xffff0000u), p);
    }
    p += __shfl_down(p, 2, 4);
    p += __shfl_down(p, 1, 4);
    if ((sub & 3) == 0) attnval[((size_t)q * 49 + j) * 8 + h] = p;
  }
}

// ===========================================================================
extern "C" void kernel_launch(void* const* d_in, const int* in_sizes, int n_in,
                              void* d_out, int out_size, void* d_ws, size_t ws_size,
                              hipStream_t stream)
{
  const float* inp    = (const float*)d_in[0];
  const float* coord  = (const float*)d_in[1];
  const float* cell   = (const float*)d_in[2];
  const float* W_enc  = (const float*)d_in[3];
  const float* b_enc  = (const float*)d_in[4];
  const float* W_ch   = (const float*)d_in[5];
  const float* b_ch   = (const float*)d_in[6];
  const float* W_q    = (const float*)d_in[7];
  const float* b_q    = (const float*)d_in[8];
  const float* W_k    = (const float*)d_in[9];
  const float* b_k    = (const float*)d_in[10];
  const float* W_v    = (const float*)d_in[11];
  const float* b_v    = (const float*)d_in[12];
  const float* W_off1 = (const float*)d_in[13];
  const float* b_off1 = (const float*)d_in[14];
  const float* ln_g   = (const float*)d_in[15];
  const float* ln_b   = (const float*)d_in[16];
  const float* W_off2 = (const float*)d_in[17];
  const float* Wc1    = (const float*)d_in[18];
  const float* bc1    = (const float*)d_in[19];
  const float* Wc2    = (const float*)d_in[20];
  const float* bc2    = (const float*)d_in[21];
  const float* Wi1    = (const float*)d_in[22];
  const float* bi1    = (const float*)d_in[23];
  const float* Wi2    = (const float*)d_in[24];
  const float* bi2    = (const float*)d_in[25];

  char* base = (char*)d_ws;
  size_t off = 0;
  auto alloc = [&](size_t bytes) -> char* {
    char* r = base + off;
    off = (off + bytes + 255) & ~(size_t)255;
    return r;
  };

  // --- scratch region (dead before gemm_big runs; Pb aliases it) ---
  float* obuf   = (float*)alloc((size_t)HW * 256 * 4);
  float* offsb  = (float*)alloc((size_t)HW * 98 * 4);
  u16*   feat1  = (u16*)  alloc((size_t)HW * 64 * 2);
  u16*   feat   = (u16*)  alloc((size_t)HW * 256 * 2);
  u16*   relbuf = (u16*)  alloc((size_t)NQ * 128 * 2);
  u16*   Btqkv  = (u16*)  alloc((size_t)768 * 2304 * 2);
  u16*   Btch   = (u16*)  alloc((size_t)256 * 576 * 2);
  u16*   Btoff1 = (u16*)  alloc((size_t)256 * 800 * 2);
  u16*   Btoff2 = (u16*)  alloc((size_t)112 * 256 * 2);
  u16*   Btc1   = (u16*)  alloc((size_t)256 * 128 * 2);
  u16*   Btc2   = (u16*)  alloc((size_t)64 * 256 * 2);
  // gemm_big bf16 partials alias scratch: 16 x 2MB = 33.6MB at base+0.
  u16* Pb = (u16*)base;
  // qkv bf16 partials at [36MB, 54.9MB): past live scratch (~16MB),
  // disjoint from Pb's 33.6MB, dead before gemm_big.
  u16* Pqb = (u16*)(base + ((size_t)36 << 20));
  {
    size_t need = ((size_t)36 << 20) + (size_t)QSPLIT * NQ * 768 * 2;
    if (off < need) off = (need + 255) & ~(size_t)255;
  }
  // --- persistent buffers ---
  u16*   fqkvb   = (u16*)  alloc((size_t)HW * 768 * 2);
  u16*   fqkvVb  = (u16*)  alloc((size_t)HW * 256 * 2);
  float* attnval = (float*)alloc((size_t)NQ * 49 * 8 * 4);
  int*   vidxb   = (int*)  alloc((size_t)NQ * 49 * 4);
  float* skipb   = (float*)alloc((size_t)NQ * 3 * 4);
  u16*   Wi1p    = (u16*)  alloc((size_t)256 * KBIG * 2);
  float* bqkv    = (float*)alloc(768 * 4);
  (void)ws_size; (void)in_sizes; (void)n_in; (void)out_size;

  // --- launch A: encoder conv ∥ Btch pack (only what the next kernel needs)
  pack_enc<<<CONV_BLKS + (SZ_CH + 255) / 256, 256, 0, stream>>>(
      inp, W_enc, b_enc, feat1, W_ch, Btch);

  // --- launch B: ch-conv GEMM ∥ ALL remaining packing (off critical path)
  conv_pack<<<CONV2_BLKS + (SZ_REST + 255) / 256, 256, 0, stream>>>(
      feat1, Btch, feat, b_ch,
      W_q, W_k, W_v, W_off1, W_off2, Wc1, Wc2, Wi1, b_q, b_k, b_v,
      Btqkv, Btoff1, Btoff2, Btc1, Btc2, Wi1p, bqkv);

  // merged qkv + off1 (overlap)
  gemm_feat<<<NBLK_QKV + NBLK_OFF1, 256, 0, stream>>>(
      feat, Btqkv, Pqb, Btoff1, obuf, b_off1);
  // merged reduce_qkv ∥ (ln_gelu + off2 1x1-conv MFMA)
  post_feat<<<RQ_BLKS + LNO_BLKS, 256, 0, stream>>>(
      Pqb, bqkv, fqkvb, fqkvVb, obuf, ln_g, ln_b, Btoff2, offsb);

  // --- per-query attention path ---
  sampler<<<NQ, 256, 0, stream>>>(coord, fqkvb, offsb, inp,
                                  attnval, relbuf, vidxb, skipb);
  // fused c1 + c2 + softmax
  attn_wc<<<NQ / 16, 256, 0, stream>>>(relbuf, Btc1, bc1, Btc2, bc2, attnval);

  // --- big MLP: 128x256 tile, bf16 gather-A, dbuf glds-B + counted vmcnt,
  //     split-K(16), bf16 partials ---
  gemm_big<<<dim3(32, SPLITK), 512, 0, stream>>>(
      Wi1p, fqkvVb, attnval, vidxb, cell, Pb);
  reduce_final<<<NQ, 256, 0, stream>>>(Pb, bi1, Wi2, bi2, skipb, (float*)d_out);
}

// Round 11
// 256.564 us; speedup vs baseline: 1.1961x; 1.0126x over previous
//
#include <hip/hip_runtime.h>
#include <hip/hip_bf16.h>

// ============================================================================
// IDASR pipeline on gfx950 — round 25.
// r24 post-mortem: pack split gained 2.6us (259.8, best); chain compression
// exhausted (true dependency chain remains). Next target derived by
// elimination: sampler's q.k loop reads 49 random taps x 512B from the
// 6MB interleaved fqkvb = 100MB of scatter vs a table BIGGER than the 4MB
// per-XCD L2 -> L3-served (FETCH-invisible). Same class of fix as r16's
// V-table (the only lever that ever moved gemm_big):
//  * NEW dense 2MB K-only table fqkvKb (4096 x 256 bf16) — fits per-XCD L2.
//    Written for free in post_feat's reduce_qkv branch (values identical).
//  * sampler k-loop reads fqkvKb[id*256 + ch0] instead of fqkvb[...+256+ch0].
// Everything else r24-identical.
// ============================================================================

typedef unsigned short u16;
typedef unsigned int u32;
using frag_ab = __attribute__((ext_vector_type(8))) short;  // 8 x bf16
using frag_cd = __attribute__((ext_vector_type(4))) float;  // 4 x f32 acc

#define HW 4096
#define NQ 4096
#define KBIG 12576
#define SPLITK 16
#define KCHUNK 800
#define JMAX 5
#define KQ 2304
#define QSPLIT 3
#define QCHUNK 768
#define NBLK_QKV (64 * 6 * QSPLIT)   // 1152
#define NBLK_OFF1 (64 * 8)           // 512

static __device__ __forceinline__ u16 f2b(float f) {
  union { __hip_bfloat16 h; u16 u; } c; c.h = __float2bfloat16(f); return c.u;
}
static __device__ __forceinline__ float b2f(u16 v) {
  return __uint_as_float((u32)v << 16);
}
static __device__ __forceinline__ u32 pk2(float a, float b) {
  union { __hip_bfloat162 h; u32 u; } c;
  c.h = __float22bfloat162_rn(float2{a, b});
  return c.u;
}
// async global->LDS, 16B per lane. LDS dest is wave-uniform base + lane*16.
static __device__ __forceinline__ void glds16(const u16* g, u16* l) {
  __builtin_amdgcn_global_load_lds(
      (const __attribute__((address_space(1))) u32*)(g),
      (__attribute__((address_space(3))) u32*)(l), 16, 0, 0);
}

#define BM 64
#define BN 64
#define BK 32
#define LDSS 40   // padded lds row stride for reg-staged tiles

// ---------------------------------------------------------------------------
// Merged feat-consumer kernel: blocks [0,1152) = qkv GEMM (64x128 tile,
// implicit im2col A, glds-B, split-K(3), bf16 partials); blocks
// [1152,1664) = grouped 5x5 off1 conv (64x64 tile). One launch -> overlap.
// ---------------------------------------------------------------------------
__global__ __launch_bounds__(256)
void gemm_feat(const u16* __restrict__ feat, const u16* __restrict__ Btqkv,
               u16* __restrict__ Pq, const u16* __restrict__ Btoff1,
               float* __restrict__ obuf, const float* __restrict__ b_off1)
{
  __shared__ u16 smem[6656];   // 13.3 KB: qkv As(2560)+Bs(4096); off1 uses 5120
  const int bid = blockIdx.x;
  const int tid = threadIdx.x;
  const int wave = tid >> 6, lane = tid & 63;
  const int lr = lane & 15, lk = lane >> 4;

  if (bid < NBLK_QKV) {
    // ----- qkv branch -----
    u16* As = smem;            // 64 * 40
    u16* Bs = smem + 64 * 40;  // 128 * 32, glds target
    const int mz  = bid & 63;
    const int rest = bid >> 6;
    const int ny  = rest % 6;
    const int z   = rest / 6;
    const int m0  = mz * 64;
    const int n0  = ny * 128;
    const int kbeg = z * QCHUNK;
    const int kend = kbeg + QCHUNK;
    const int nw = wave * 32;
    const int arow = tid >> 2, acol = (tid & 3) * 8;
    const int p = m0 + arow, y = p >> 6, x = p & 63;

    frag_cd acc[4][2] = {};
    const u16* bbase = Btqkv + (size_t)(n0 + (tid >> 2)) * KQ + (tid & 3) * 8 + kbeg;
    u16* bdst = &Bs[(size_t)tid * 8];

    auto stageA = [&](int k0) -> uint4 {
      int k = k0 + acol;
      int s = k >> 8, c = k & 255;
      int dy = s / 3, dx = s - dy * 3;
      int yy = y + dy - 1, xx = x + dx - 1;
      if (((unsigned)yy < 64u) && ((unsigned)xx < 64u))
        return *(const uint4*)&feat[(size_t)(yy * 64 + xx) * 256 + c];
      return uint4{0u, 0u, 0u, 0u};
    };

    uint4 av = stageA(kbeg);

    for (int k0 = kbeg; k0 < kend; k0 += BK) {
      glds16(bbase + (k0 - kbeg), bdst);
      glds16(bbase + (k0 - kbeg) + (size_t)64 * KQ, bdst + 2048);
      *(uint4*)&As[arow * LDSS + acol] = av;
      __syncthreads();
      if (k0 + BK < kend) av = stageA(k0 + BK);
      frag_ab af[4];
      #pragma unroll
      for (int i = 0; i < 4; i++)
        af[i] = *(const frag_ab*)&As[(i * 16 + lr) * LDSS + lk * 8];
      #pragma unroll
      for (int j = 0; j < 2; j++) {
        frag_ab bf = *(const frag_ab*)&Bs[(nw + j * 16 + lr) * 32 + lk * 8];
        #pragma unroll
        for (int i = 0; i < 4; i++)
          acc[i][j] = __builtin_amdgcn_mfma_f32_16x16x32_bf16(af[i], bf, acc[i][j], 0, 0, 0);
      }
      __syncthreads();
    }

    #pragma unroll
    for (int i = 0; i < 4; i++)
      #pragma unroll
      for (int j = 0; j < 2; j++) {
        int col = n0 + nw + j * 16 + lr;
        #pragma unroll
        for (int r = 0; r < 4; r++) {
          int row = m0 + i * 16 + lk * 4 + r;
          Pq[(size_t)z * (NQ * 768) + (size_t)row * 768 + col] = f2b(acc[i][j][r]);
        }
      }
  } else {
    // ----- off1 grouped conv branch (5x5 pad2, 32 ch/group) -----
    u16* As = smem;            // 64 * 40
    u16* Bs = smem + 64 * 40;  // 64 * 40
    const int t  = bid - NBLK_QKV;
    const int m0 = (t & 63) * 64;
    const int g  = t >> 6;               // group 0..7
    const int cb = g * 32;
    const u16* Bt = Btoff1 + (size_t)g * 32 * 800;
    const float* bz = b_off1 + g * 32;
    const int mw = (wave & 1) * 32, nw = (wave >> 1) * 32;
    const int srow = tid >> 2, scol = (tid & 3) * 8;
    const int p = m0 + srow, y = p >> 6, x = p & 63;

    frag_cd acc[2][2] = {};
    const bool bok  = srow < 32;
    const u16* bptr = Bt + (size_t)srow * 800 + scol;

    auto stageA = [&](int k0) -> uint4 {
      int k = k0 + scol;
      int s = k >> 5;
      int c = k & 31;
      int dy = s / 5, dx = s - dy * 5;
      int yy = y + dy - 2, xx = x + dx - 2;
      if (((unsigned)yy < 64u) && ((unsigned)xx < 64u))
        return *(const uint4*)&feat[(size_t)(yy * 64 + xx) * 256 + cb + c];
      return uint4{0u, 0u, 0u, 0u};
    };

    uint4 av = stageA(0);
    uint4 bv = bok ? *(const uint4*)(bptr) : uint4{0u, 0u, 0u, 0u};

    for (int k0 = 0; k0 < 800; k0 += BK) {
      *(uint4*)&As[srow * LDSS + scol] = av;
      *(uint4*)&Bs[srow * LDSS + scol] = bv;
      __syncthreads();
      if (k0 + BK < 800) {
        av = stageA(k0 + BK);
        bv = bok ? *(const uint4*)(bptr + k0 + BK) : uint4{0u, 0u, 0u, 0u};
      }
      frag_ab af0 = *(const frag_ab*)&As[(mw      + lr) * LDSS + lk * 8];
      frag_ab af1 = *(const frag_ab*)&As[(mw + 16 + lr) * LDSS + lk * 8];
      frag_ab bf0 = *(const frag_ab*)&Bs[(nw      + lr) * LDSS + lk * 8];
      frag_ab bf1 = *(const frag_ab*)&Bs[(nw + 16 + lr) * LDSS + lk * 8];
      acc[0][0] = __builtin_amdgcn_mfma_f32_16x16x32_bf16(af0, bf0, acc[0][0], 0, 0, 0);
      acc[0][1] = __builtin_amdgcn_mfma_f32_16x16x32_bf16(af0, bf1, acc[0][1], 0, 0, 0);
      acc[1][0] = __builtin_amdgcn_mfma_f32_16x16x32_bf16(af1, bf0, acc[1][0], 0, 0, 0);
      acc[1][1] = __builtin_amdgcn_mfma_f32_16x16x32_bf16(af1, bf1, acc[1][1], 0, 0, 0);
      __syncthreads();
    }

    #pragma unroll
    for (int i = 0; i < 2; i++)
      #pragma unroll
      for (int j = 0; j < 2; j++) {
        int col = nw + j * 16 + lr;
        if (col >= 32) continue;
        float badd = bz[col];
        #pragma unroll
        for (int r = 0; r < 4; r++) {
          int row = m0 + mw + i * 16 + lk * 4 + r;
          obuf[(size_t)row * 256 + g * 32 + col] = acc[i][j][r] + badd;
        }
      }
  }
}

// ---------------------------------------------------------------------------
// Merged post-gemm_feat kernel:
//  blocks [0, RQ_BLKS)          : reduce_qkv (sum partials + bias) -> fqkvb,
//                                 dense K table (2MB) and dense V table (2MB)
//  blocks [RQ_BLKS, +LNO_BLKS)  : ln_gelu + off2 1x1-conv fused MFMA
// ---------------------------------------------------------------------------
#define RQ_BLKS 1536   // NQ*96/256
#define LNO_BLKS 256   // 4096 pixels / 16
__global__ __launch_bounds__(256)
void post_feat(const u16* __restrict__ P, const float* __restrict__ bias,
               u16* __restrict__ outb, u16* __restrict__ outK,
               u16* __restrict__ outV,
               const float* __restrict__ x, const float* __restrict__ g,
               const float* __restrict__ b, const u16* __restrict__ Btoff2,
               float* __restrict__ offsb)
{
  __shared__ u16 s_oc[16 * 264];   // lnoff2 branch only (8.25 KB)
  const int bid = blockIdx.x;
  const int tid = threadIdx.x;
  if (bid < RQ_BLKS) {
    // ----- reduce_qkv -----
    int i8 = bid * 256 + tid;
    size_t i = (size_t)i8 * 8;
    int row = (int)(i / 768);
    int c = (int)(i % 768);
    float v[8];
    #pragma unroll
    for (int t = 0; t < 8; t++) v[t] = bias[c + t];
    for (int z = 0; z < QSPLIT; z++) {
      uint4 a = *(const uint4*)&P[(size_t)z * (NQ * 768) + i];
      u32 aw[4] = {a.x, a.y, a.z, a.w};
      #pragma unroll
      for (int t = 0; t < 4; t++) {
        v[2 * t]     += __uint_as_float(aw[t] << 16);
        v[2 * t + 1] += __uint_as_float(aw[t] & 0xffff0000u);
      }
    }
    uint4 ob = {pk2(v[0], v[1]), pk2(v[2], v[3]), pk2(v[4], v[5]), pk2(v[6], v[7])};
    *(uint4*)&outb[i] = ob;
    if (c >= 512) {
      // dense bf16 V gather table (2MB, per-XCD-L2-fit) for gemm_big.
      *(uint4*)&outV[(size_t)row * 256 + (c - 512)] = ob;
    } else if (c >= 256) {
      // dense bf16 K table (2MB, per-XCD-L2-fit) for sampler's q.k loop —
      // the interleaved 6MB fqkvb overflows the 4MB per-XCD L2.
      *(uint4*)&outK[(size_t)row * 256 + (c - 256)] = ob;
    }
  } else {
    // ----- ln_gelu + off2 (1x1 conv) fused, 16 pixels per block -----
    const int p0 = (bid - RQ_BLKS) * 16;
    const int p = tid >> 4, gl = tid & 15;   // pixel 0..15, 16-lane group
    float v[16];
    {
      const float* src = x + (size_t)(p0 + p) * 256 + gl * 16;
      #pragma unroll
      for (int t = 0; t < 4; t++) {
        float4 f = *(const float4*)(src + t * 4);
        v[4 * t] = f.x; v[4 * t + 1] = f.y; v[4 * t + 2] = f.z; v[4 * t + 3] = f.w;
      }
    }
    float s1 = 0.f, s2 = 0.f;
    #pragma unroll
    for (int t = 0; t < 16; t++) { s1 += v[t]; s2 += v[t] * v[t]; }
    #pragma unroll
    for (int off = 8; off; off >>= 1) {
      s1 += __shfl_xor(s1, off, 16);
      s2 += __shfl_xor(s2, off, 16);
    }
    float mu   = s1 * (1.f / 256.f);
    float var  = s2 * (1.f / 256.f) - mu * mu;
    float rstd = rsqrtf(var + 1e-5f);
    #pragma unroll
    for (int t = 0; t < 16; t++) {
      int c = gl * 16 + t;
      float xn = (v[t] - mu) * rstd * g[c] + b[c];
      float ge = 0.5f * xn * (1.f + erff(xn * 0.70710678118654752f));
      s_oc[p * 264 + c] = f2b(ge);
    }
    __syncthreads();
    // MFMA: out(16 x 112) = A(16 x 256) x Btoff2^T (112 rows, zero-padded).
    const int wave = tid >> 6, lane = tid & 63;
    const int lr = lane & 15, lk = lane >> 4;
    frag_cd a0 = {}, a1 = {};
    #pragma unroll
    for (int k0 = 0; k0 < 256; k0 += 32) {
      frag_ab af = *(const frag_ab*)&s_oc[lr * 264 + k0 + lk * 8];
      frag_ab bf0 = *(const frag_ab*)&Btoff2[(size_t)(wave * 16 + lr) * 256 + k0 + lk * 8];
      a0 = __builtin_amdgcn_mfma_f32_16x16x32_bf16(af, bf0, a0, 0, 0, 0);
      if (wave < 3) {
        frag_ab bf1 = *(const frag_ab*)&Btoff2[(size_t)((wave + 4) * 16 + lr) * 256 + k0 + lk * 8];
        a1 = __builtin_amdgcn_mfma_f32_16x16x32_bf16(af, bf1, a1, 0, 0, 0);
      }
    }
    {
      const int col0 = wave * 16 + lr;
      const int col1 = (wave + 4) * 16 + lr;
      #pragma unroll
      for (int r = 0; r < 4; r++) {
        int row = lk * 4 + r;
        offsb[(size_t)(p0 + row) * 98 + col0] = a0[r];   // col0 <= 63 < 98
        if (wave < 3 && col1 < 98)
          offsb[(size_t)(p0 + row) * 98 + col1] = a1[r];
      }
    }
  }
}

// ---------------------------------------------------------------------------
// Big MLP GEMM: fused gather-A (bf16 V, weight-mul + repack), 128x256 tile,
// double-buffered glds-B with counted-vmcnt pipeline, split-K(16), bf16
// partials. block 512 (8 waves), grid (32, 16) = 2/CU (reg-capped: ~60 VGPR
// + 64 AGPR unified; (512,4) — do NOT raise min-waves, r15 spilled).
// ---------------------------------------------------------------------------
__global__ __launch_bounds__(512, 4)
void gemm_big(const u16* __restrict__ Bt, const u16* __restrict__ fqkvV,
              const float* __restrict__ attnval, const int* __restrict__ vidx,
              const float* __restrict__ cell, u16* __restrict__ P)
{
  __shared__ u16 As[128 * LDSS];            // 10 KB padded, reg-staged gather
  __shared__ u16 Bs[2 * 256 * 32];          // 32 KB double-buffered glds target
  __shared__ short s_vidx[JMAX * 128];      // 1.25 KB (ids < 4096 fit short)
  __shared__ float s_attn[JMAX * 128 * 8];  // 20 KB
  const int tid  = threadIdx.x;
  const int m0   = blockIdx.x * 128;
  const int z    = blockIdx.y;
  const int kbeg = z * KCHUNK;
  const int kend = min(KBIG, kbeg + KCHUNK);
  const int jbeg = kbeg >> 8;
  const int jcnt = ((kend - 1) >> 8) - jbeg + 1;   // <= 5
  const int wave = tid >> 6, lane = tid & 63;
  const int mw = (wave & 1) * 64, nwv = (wave >> 1) * 64;
  const int lr = lane & 15, lk = lane >> 4;
  const int arow = tid >> 2, acol = (tid & 3) * 8;  // 128 rows x 4x8
  const int q = m0 + arow;

  for (int t = tid; t < 128 * jcnt; t += 512) {
    int r = t & 127, jj = t >> 7;
    int j = jbeg + jj;
    s_vidx[t] = (short)((j < 49) ? vidx[(m0 + r) * 49 + j] : -1);
  }
  for (int t = tid; t < 128 * 8 * jcnt; t += 512) {
    int h = t & 7, rr = (t >> 3) & 127, jj = t >> 10;
    int j = jbeg + jj;
    s_attn[t] = (j < 49) ? attnval[((size_t)((m0 + rr) * 49 + j)) * 8 + h] : 0.f;
  }
  __syncthreads();   // full drain: preload loads retired before pipeline starts

  auto loadA = [&](int k0, uint4& kv, float& w) {
    const int k = k0 + acol;
    const int j = k >> 8, c = k & 255;
    kv = uint4{0u, 0u, 0u, 0u};
    w = 0.f;
    if (j < 49) {
      const int jj = j - jbeg;
      int id = s_vidx[jj * 128 + arow];
      if (id >= 0) {
        w = s_attn[(jj * 128 + arow) * 8 + (c >> 5)];
        kv = *(const uint4*)(fqkvV + (size_t)id * 256 + c);   // 8 bf16
      }
    } else if (c == 0) {
      kv.x = pk2(cell[q * 2], cell[q * 2 + 1]);  // cell = 1/64, exact in bf16
      w = 64.f;
    }
  };

  frag_cd acc[4][4] = {};
  uint4 kvc; float wc_;
  const u16* bbase = Bt + (size_t)(tid >> 2) * KBIG + (tid & 3) * 8 + kbeg;

  // prologue: B tile 0 -> buffer 0 (2 glds in flight), A(0) -> regs
  glds16(bbase, &Bs[(size_t)tid * 8]);
  glds16(bbase + (size_t)128 * KBIG, &Bs[(size_t)tid * 8 + 4096]);
  loadA(kbeg, kvc, wc_);

  int par = 0;
  for (int k0 = kbeg; k0 < kend; k0 += BK, par ^= 1) {
    // stage A(t): unpack bf16 pair -> f32, scale by attn weight, repack.
    {
      u32 aw[4] = {kvc.x, kvc.y, kvc.z, kvc.w};
      uint4 av;
      u32 avw[4];
      #pragma unroll
      for (int t = 0; t < 4; t++) {
        float lo = __uint_as_float(aw[t] << 16) * wc_;
        float hi = __uint_as_float(aw[t] & 0xffff0000u) * wc_;
        avw[t] = pk2(lo, hi);
      }
      av.x = avw[0]; av.y = avw[1]; av.z = avw[2]; av.w = avw[3];
      *(uint4*)&As[arow * LDSS + acol] = av;
    }
    if (k0 + BK < kend) {
      // issue B(t+1) into the other buffer; keep it in flight across the
      // barrier — only the 2 newest VMEM ops may remain outstanding, so
      // vmcnt(2) guarantees B(t) (older) has landed.
      u16* bd = &Bs[(size_t)(par ^ 1) * 8192 + (size_t)tid * 8];
      glds16(bbase + (k0 + BK - kbeg), bd);
      glds16(bbase + (k0 + BK - kbeg) + (size_t)128 * KBIG, bd + 4096);
      asm volatile("s_waitcnt vmcnt(2) lgkmcnt(0)" ::: "memory");
    } else {
      asm volatile("s_waitcnt vmcnt(0) lgkmcnt(0)" ::: "memory");
    }
    __builtin_amdgcn_s_barrier();
    if (k0 + BK < kend) loadA(k0 + BK, kvc, wc_);   // A prefetch (compiler-waited)
    const u16* bsrc = &Bs[(size_t)par * 8192];
    frag_ab af[4];
    #pragma unroll
    for (int i = 0; i < 4; i++)
      af[i] = *(const frag_ab*)&As[(mw + i * 16 + lr) * LDSS + lk * 8];
    #pragma unroll
    for (int j = 0; j < 4; j++) {
      frag_ab bf = *(const frag_ab*)&bsrc[(nwv + j * 16 + lr) * 32 + lk * 8];
      #pragma unroll
      for (int i = 0; i < 4; i++)
        acc[i][j] = __builtin_amdgcn_mfma_f32_16x16x32_bf16(af[i], bf, acc[i][j], 0, 0, 0);
    }
    asm volatile("s_waitcnt lgkmcnt(0)" ::: "memory");
    __builtin_amdgcn_s_barrier();
  }

  #pragma unroll
  for (int i = 0; i < 4; i++)
    #pragma unroll
    for (int j = 0; j < 4; j++) {
      int col = nwv + j * 16 + lr;
      #pragma unroll
      for (int r = 0; r < 4; r++) {
        int row = m0 + mw + i * 16 + lk * 4 + r;
        P[(size_t)z * (NQ * 256) + (size_t)row * 256 + col] = f2b(acc[i][j][r]);
      }
    }
}

// ---------------------------------------------------------------------------
// Fused: hid2 = relu(sum_z Pb + bi1); out = bi2 + skip + hid2 . Wi2^T.
// ---------------------------------------------------------------------------
__global__ __launch_bounds__(256)
void reduce_final(const u16* __restrict__ Pb, const float* __restrict__ bi1,
                  const float* __restrict__ Wi2, const float* __restrict__ bi2,
                  const float* __restrict__ skipb, float* __restrict__ out)
{
  const int q = blockIdx.x, c = threadIdx.x;
  float s = 0.f;
  #pragma unroll
  for (int z = 0; z < SPLITK; z++)
    s += b2f(Pb[(size_t)z * (NQ * 256) + (size_t)q * 256 + c]);
  s += bi1[c];
  s = fmaxf(s, 0.f);

  __shared__ float part[3][4];
  float p0 = s * Wi2[c], p1 = s * Wi2[256 + c], p2 = s * Wi2[512 + c];
  #pragma unroll
  for (int off = 32; off; off >>= 1) {
    p0 += __shfl_xor(p0, off);
    p1 += __shfl_xor(p1, off);
    p2 += __shfl_xor(p2, off);
  }
  if ((c & 63) == 0) {
    int w = c >> 6;
    part[0][w] = p0; part[1][w] = p1; part[2][w] = p2;
  }
  __syncthreads();
  if (c < 3)
    out[q * 3 + c] = bi2[c] + skipb[q * 3 + c]
                   + part[c][0] + part[c][1] + part[c][2] + part[c][3];
}

// ---------------------------------------------------------------------------
// FUSED attention-weight chain: c1 MLP + c2 + softmax in one kernel.
// grid 256 blocks x 256 threads; each block owns 16 q rows.
// ---------------------------------------------------------------------------
__global__ __launch_bounds__(256)
void attn_wc(const u16* __restrict__ relbuf, const u16* __restrict__ Btc1,
             const float* __restrict__ bc1, const u16* __restrict__ Btc2,
             const float* __restrict__ bc2, float* __restrict__ attnval)
{
  __shared__ u16 s_rel[16 * 136];    // A: 16 q-rows x 128 (pad 136)
  __shared__ u16 s_hid[16 * 264];    // hid bf16: 16 x 256 (pad 264)
  __shared__ float s_wc[16 * 52];    // wc: 16 x 49 (pad 52)
  const int tid = threadIdx.x;
  const int m0 = blockIdx.x * 16;
  const int wave = tid >> 6, lane = tid & 63;
  const int lr = lane & 15, lk = lane >> 4;

  // load rel A tile: 16 rows x 128 = 256 uint4, one per thread
  {
    int r = tid >> 4, kc = (tid & 15) * 8;
    uint4 v = *(const uint4*)&relbuf[(size_t)(m0 + r) * 128 + kc];
    *(uint4*)&s_rel[r * 136 + kc] = v;
  }
  __syncthreads();

  // ---- c1: hid = relu(rel x Btc1^T + bc1); wave w covers cols w*64..+63
  frag_cd acc1[4] = {};
  #pragma unroll
  for (int k0 = 0; k0 < 128; k0 += 32) {
    frag_ab af = *(const frag_ab*)&s_rel[lr * 136 + k0 + lk * 8];
    #pragma unroll
    for (int j = 0; j < 4; j++) {
      int col = wave * 64 + j * 16 + lr;
      frag_ab bf = *(const frag_ab*)&Btc1[(size_t)col * 128 + k0 + lk * 8];
      acc1[j] = __builtin_amdgcn_mfma_f32_16x16x32_bf16(af, bf, acc1[j], 0, 0, 0);
    }
  }
  #pragma unroll
  for (int j = 0; j < 4; j++) {
    int col = wave * 64 + j * 16 + lr;
    float badd = bc1[col];
    #pragma unroll
    for (int r = 0; r < 4; r++) {
      int row = lk * 4 + r;
      s_hid[row * 264 + col] = f2b(fmaxf(acc1[j][r] + badd, 0.f));
    }
  }
  __syncthreads();

  // ---- c2: wc = hid x Btc2p^T + bc2; wave w covers cols w*16..+15
  frag_cd acc2 = {};
  #pragma unroll
  for (int k0 = 0; k0 < 256; k0 += 32) {
    frag_ab af = *(const frag_ab*)&s_hid[lr * 264 + k0 + lk * 8];
    frag_ab bf = *(const frag_ab*)&Btc2[(size_t)(wave * 16 + lr) * 256 + k0 + lk * 8];
    acc2 = __builtin_amdgcn_mfma_f32_16x16x32_bf16(af, bf, acc2, 0, 0, 0);
  }
  {
    int col = wave * 16 + lr;
    if (col < 49) {
      float badd = bc2[col];
      #pragma unroll
      for (int r = 0; r < 4; r++) {
        int row = lk * 4 + r;
        s_wc[row * 52 + col] = acc2[r] + badd;
      }
    }
  }
  __syncthreads();

  // ---- softmax per (q, h): threads 0..127, one pair each
  if (tid < 128) {
    const int qq = tid >> 3, h = tid & 7;
    float* avp = attnval + ((size_t)(m0 + qq) * 49) * 8 + h;
    float v[49];
    float m = -1e30f;
    #pragma unroll
    for (int l = 0; l < 49; l++) {
      v[l] = s_wc[qq * 52 + l] + avp[(size_t)l * 8];
      m = fmaxf(m, v[l]);
    }
    float ssum = 0.f;
    #pragma unroll
    for (int l = 0; l < 49; l++) { v[l] = expf(v[l] - m); ssum += v[l]; }
    float inv = 1.f / ssum;
    #pragma unroll
    for (int l = 0; l < 49; l++) avp[(size_t)l * 8] = v[l] * inv;
  }
}

// ---------------------------------------------------------------------------
// Packing helpers.
// ---------------------------------------------------------------------------
static __device__ __forceinline__
void packconv(const float* __restrict__ W, u16* __restrict__ Bt,
              int Cin, int K2, int idx)
{
  int o  = idx / (Cin * K2);
  int r  = idx - o * (Cin * K2);
  int ci = r / K2;
  int s  = r - ci * K2;
  Bt[(size_t)o * (Cin * K2) + s * Cin + ci] = f2b(W[idx]);
}
static __device__ __forceinline__
void packcast(const float* __restrict__ W, u16* __restrict__ Bt,
              int Kin, int Kout, int idx)
{
  int n = idx / Kout, k = idx - n * Kout;
  Bt[idx] = f2b(k < Kin ? W[(size_t)n * Kin + k] : 0.f);
}

#define SZ_CH    147456   // 256*64*9
#define SZ_QKV   589824   // 256*256*9
#define SZ_OFF1  204800   // 256*32*25
#define SZ_OFF2P 28672    // 112*256 (W_off2 zero-padded to 112 rows)
#define SZ_C1    32768    // 256*128
#define SZ_C2P   16384    // 64*256 (Wc2 zero-padded to 64 rows)
#define SZ_WI1   3219456  // 256*12576
#define SZ_REST (3*SZ_QKV + SZ_OFF1 + SZ_OFF2P + SZ_C1 + SZ_C2P + 768 + SZ_WI1)
#define CONV_BLKS 1024   // 4096 pixels, 4 per 256-thread block
#define CONV2_BLKS 256   // ch-conv GEMM: 64 m-tiles x 4 n-tiles

// ---------------------------------------------------------------------------
// Launch A: encoder conv ∥ Btch pack (only what the next kernel needs).
// ---------------------------------------------------------------------------
__global__ __launch_bounds__(256)
void pack_enc(const float* __restrict__ inp, const float* __restrict__ W_enc,
              const float* __restrict__ b_enc, u16* __restrict__ feat1,
              const float* __restrict__ W_ch, u16* __restrict__ Btch)
{
  const int bid = blockIdx.x;
  const int tid = threadIdx.x;
  if (bid < CONV_BLKS) {
    // ----- encoder conv: 3->64, 3x3 pad1, +bias, relu -----
    const int p = bid * 4 + (tid >> 6), c = tid & 63;
    const int y = p >> 6, x = p & 63;
    float s = b_enc[c];
    #pragma unroll
    for (int ci = 0; ci < 3; ci++)
      #pragma unroll
      for (int dy = 0; dy < 3; dy++) {
        int yy = y + dy - 1;
        if ((unsigned)yy >= 64u) continue;
        #pragma unroll
        for (int dx = 0; dx < 3; dx++) {
          int xx = x + dx - 1;
          if ((unsigned)xx >= 64u) continue;
          s += inp[ci * HW + yy * 64 + xx] * W_enc[((c * 3 + ci) * 3 + dy) * 3 + dx];
        }
      }
    feat1[(size_t)p * 64 + c] = f2b(fmaxf(s, 0.f));
    return;
  }
  int i = (bid - CONV_BLKS) * 256 + tid;
  if (i < SZ_CH) packconv(W_ch, Btch, 64, 9, i);
}

// ---------------------------------------------------------------------------
// Launch B: ch-conv GEMM (blocks [0,256), critical path) ∥ ALL remaining
// weight packing (nothing packed here is read before gemm_feat).
// ---------------------------------------------------------------------------
__global__ __launch_bounds__(256)
void conv_pack(const u16* __restrict__ feat1, const u16* __restrict__ Btch,
               u16* __restrict__ feat, const float* __restrict__ b_ch,
               const float* W_q, const float* W_k, const float* W_v,
               const float* W_off1, const float* W_off2,
               const float* Wc1, const float* Wc2, const float* Wi1,
               const float* b_q, const float* b_k, const float* b_v,
               u16* Btqkv, u16* Btoff1, u16* Btoff2,
               u16* Btc1, u16* Btc2, u16* Wi1p, float* bqkv)
{
  __shared__ u16 As[BM * LDSS];
  __shared__ u16 Bs[BN * LDSS];
  const int bid = blockIdx.x;
  const int tid = threadIdx.x;
  if (bid < CONV2_BLKS) {
    // ----- ch conv GEMM: 64x64 tile, im2col A (3x3 pad1, 64ch), bf16 out --
    const int m0 = (bid & 63) * 64;
    const int n0 = (bid >> 6) * 64;
    const int wave = tid >> 6, lane = tid & 63;
    const int mw = (wave & 1) * 32, nw = (wave >> 1) * 32;
    const int lr = lane & 15, lk = lane >> 4;
    const int srow = tid >> 2, scol = (tid & 3) * 8;
    const int p = m0 + srow, y = p >> 6, x = p & 63;

    frag_cd acc[2][2] = {};
    const u16* bptr = Btch + (size_t)(n0 + srow) * 576 + scol;

    auto stageA = [&](int k0) -> uint4 {
      int k = k0 + scol;
      int s = k >> 6;
      int c = k & 63;
      int dy = s / 3, dx = s - dy * 3;
      int yy = y + dy - 1, xx = x + dx - 1;
      if (((unsigned)yy < 64u) && ((unsigned)xx < 64u))
        return *(const uint4*)&feat1[(size_t)(yy * 64 + xx) * 64 + c];
      return uint4{0u, 0u, 0u, 0u};
    };

    uint4 av = stageA(0);
    uint4 bv = *(const uint4*)(bptr);

    for (int k0 = 0; k0 < 576; k0 += BK) {
      *(uint4*)&As[srow * LDSS + scol] = av;
      *(uint4*)&Bs[srow * LDSS + scol] = bv;
      __syncthreads();
      if (k0 + BK < 576) {
        av = stageA(k0 + BK);
        bv = *(const uint4*)(bptr + k0 + BK);
      }
      frag_ab af0 = *(const frag_ab*)&As[(mw      + lr) * LDSS + lk * 8];
      frag_ab af1 = *(const frag_ab*)&As[(mw + 16 + lr) * LDSS + lk * 8];
      frag_ab bf0 = *(const frag_ab*)&Bs[(nw      + lr) * LDSS + lk * 8];
      frag_ab bf1 = *(const frag_ab*)&Bs[(nw + 16 + lr) * LDSS + lk * 8];
      acc[0][0] = __builtin_amdgcn_mfma_f32_16x16x32_bf16(af0, bf0, acc[0][0], 0, 0, 0);
      acc[0][1] = __builtin_amdgcn_mfma_f32_16x16x32_bf16(af0, bf1, acc[0][1], 0, 0, 0);
      acc[1][0] = __builtin_amdgcn_mfma_f32_16x16x32_bf16(af1, bf0, acc[1][0], 0, 0, 0);
      acc[1][1] = __builtin_amdgcn_mfma_f32_16x16x32_bf16(af1, bf1, acc[1][1], 0, 0, 0);
      __syncthreads();
    }

    #pragma unroll
    for (int i = 0; i < 2; i++)
      #pragma unroll
      for (int j = 0; j < 2; j++) {
        int col = n0 + nw + j * 16 + lr;
        float badd = b_ch[col];
        #pragma unroll
        for (int r = 0; r < 4; r++) {
          int row = m0 + mw + i * 16 + lk * 4 + r;
          feat[(size_t)row * 256 + col] = f2b(acc[i][j][r] + badd);
        }
      }
    return;
  }
  // ----- remaining weight packing -----
  int i = (bid - CONV2_BLKS) * 256 + tid;
  if (i < SZ_QKV) { packconv(W_q, Btqkv, 256, 9, i); return; }
  i -= SZ_QKV;
  if (i < SZ_QKV) { packconv(W_k, Btqkv + (size_t)256 * 2304, 256, 9, i); return; }
  i -= SZ_QKV;
  if (i < SZ_QKV) { packconv(W_v, Btqkv + (size_t)512 * 2304, 256, 9, i); return; }
  i -= SZ_QKV;
  if (i < SZ_OFF1) { packconv(W_off1, Btoff1, 32, 25, i); return; }
  i -= SZ_OFF1;
  if (i < SZ_OFF2P) {
    int n = i >> 8, k = i & 255;
    Btoff2[i] = f2b(n < 98 ? W_off2[n * 256 + k] : 0.f);
    return;
  }
  i -= SZ_OFF2P;
  if (i < SZ_C1) { packcast(Wc1, Btc1, 98, 128, i); return; }
  i -= SZ_C1;
  if (i < SZ_C2P) {
    int n = i >> 8, k = i & 255;
    Btc2[i] = f2b(n < 49 ? Wc2[n * 256 + k] : 0.f);
    return;
  }
  i -= SZ_C2P;
  if (i < 768) {
    bqkv[i] = (i < 256) ? b_q[i] : (i < 512) ? b_k[i - 256] : b_v[i - 512];
    return;
  }
  i -= 768;
  if (i < SZ_WI1) { packcast(Wi1, Wi1p, 12546, 12576, i); }
}

// ---------------------------------------------------------------------------
// Per-query sampler (writes raw q.k dots to attnval; attn_wc finalizes).
// K reads go through the dense 2MB fqkvKb table (per-XCD-L2-fit).
// ---------------------------------------------------------------------------
__global__ __launch_bounds__(256)
void sampler(const float* __restrict__ coord, const u16* __restrict__ fqkvb,
             const u16* __restrict__ fqkvKb,
             const float* __restrict__ offs, const float* __restrict__ inp,
             float* __restrict__ attnval, u16* __restrict__ relbuf,
             int* __restrict__ vidx, float* __restrict__ skipb)
{
  const int q = blockIdx.x;
  const int tid = threadIdx.x;
  __shared__ float s_off[98];
  __shared__ int s_idx[49];
  __shared__ float s_q[256];

  const float c0 = coord[q * 2], c1 = coord[q * 2 + 1];
  const float gxp = ((c1 + 1.f) * 64.f - 1.f) * 0.5f;
  const float gyp = ((c0 + 1.f) * 64.f - 1.f) * 0.5f;
  const int ixn = (int)rintf(gxp), iyn = (int)rintf(gyp);
  const bool inn = ((unsigned)ixn < 64u) && ((unsigned)iyn < 64u);

  if (tid < 98) {
    float v = inn ? offs[(size_t)(iyn * 64 + ixn) * 98 + tid] : 0.f;
    s_off[tid] = tanhf(v) * (2.f / 63.f);
  }
  __syncthreads();

  const float scky = inn ? (-1.f + (float)(2 * iyn + 1) * (1.f / 64.f)) : 0.f;
  const float sckx = inn ? (-1.f + (float)(2 * ixn + 1) * (1.f / 64.f)) : 0.f;

  if (tid < 49) {
    const int a = tid / 7, bb = tid - a * 7;
    float sy = scky + (float)(a - 3) * (2.f / 64.f) + s_off[2 * tid];
    float sx = sckx + (float)(bb - 3) * (2.f / 64.f) + s_off[2 * tid + 1];
    relbuf[(size_t)q * 128 + 2 * tid]     = f2b((c0 - sy) * 64.f);
    relbuf[(size_t)q * 128 + 2 * tid + 1] = f2b((c1 - sx) * 64.f);
    float gx2 = ((sx + 1.f) * 64.f - 1.f) * 0.5f;
    float gy2 = ((sy + 1.f) * 64.f - 1.f) * 0.5f;
    int ix2 = (int)rintf(gx2), iy2 = (int)rintf(gy2);
    int id = (((unsigned)ix2 < 64u) && ((unsigned)iy2 < 64u)) ? (iy2 * 64 + ix2) : -1;
    s_idx[tid] = id;
    vidx[q * 49 + tid] = id;
  } else if (tid >= 98 && tid < 128) {
    relbuf[(size_t)q * 128 + tid] = 0;
  }

  {
    const float x0f = floorf(gxp), y0f = floorf(gyp);
    const float wx = gxp - x0f, wy = gyp - y0f;
    const int x0 = (int)x0f, y0 = (int)y0f;
    float qc = 0.f;
    #pragma unroll
    for (int t = 0; t < 4; t++) {
      int xi = x0 + (t & 1), yi = y0 + (t >> 1);
      if (((unsigned)xi < 64u) && ((unsigned)yi < 64u)) {
        float w = ((t & 1) ? wx : 1.f - wx) * ((t >> 1) ? wy : 1.f - wy);
        qc += w * b2f(fqkvb[(size_t)(yi * 64 + xi) * 768 + tid]);
      }
    }
    s_q[tid] = qc * 0.17677669529663687f;
  }

  if (tid < 3) {
    float gx = fminf(fmaxf(gxp, 0.f), 63.f);
    float gy = fminf(fmaxf(gyp, 0.f), 63.f);
    float xf = floorf(gx), yf = floorf(gy);
    float wxs = gx - xf, wys = gy - yf;
    int xa = (int)xf, ya = (int)yf;
    int xb = min(xa + 1, 63), yb = min(ya + 1, 63);
    const float* ch = inp + tid * HW;
    float v = (1.f - wxs) * (1.f - wys) * ch[ya * 64 + xa]
            + wxs * (1.f - wys) * ch[ya * 64 + xb]
            + (1.f - wxs) * wys * ch[yb * 64 + xa]
            + wxs * wys * ch[yb * 64 + xb];
    skipb[q * 3 + tid] = v;
  }
  __syncthreads();

  const int wave = tid >> 6, lane = tid & 63;
  const int half = lane >> 5, sub = lane & 31;
  const int ch0 = sub * 8;
  const int h = sub >> 2;
  float qv[8];
  #pragma unroll
  for (int i = 0; i < 8; i++) qv[i] = s_q[ch0 + i];

  for (int it = 0; it < 7; it++) {
    int j = it * 8 + wave * 2 + half;
    if (j >= 49) break;
    int id = s_idx[j];
    float p = 0.f;
    if (id >= 0) {
      uint4 kv = *(const uint4*)&fqkvKb[(size_t)id * 256 + ch0];
      u32 w0 = kv.x, w1 = kv.y, w2 = kv.z, w3 = kv.w;
      p = fmaf(qv[0], __uint_as_float(w0 << 16), p);
      p = fmaf(qv[1], __uint_as_float(w0 & 0xffff0000u), p);
      p = fmaf(qv[2], __uint_as_float(w1 << 16), p);
      p = fmaf(qv[3], __uint_as_float(w1 & 0xffff0000u), p);
      p = fmaf(qv[4], __uint_as_float(w2 << 16), p);
      p = fmaf(qv[5], __uint_as_float(w2 & 0xffff0000u), p);
      p = fmaf(qv[6], __uint_as_float(w3 << 16), p);
      p = fmaf(qv[7], __uint_as_float(w3 & 0xffff0000u), p);
    }
    p += __shfl_down(p, 2, 4);
    p += __shfl_down(p, 1, 4);
    if ((sub & 3) == 0) attnval[((size_t)q * 49 + j) * 8 + h] = p;
  }
}

// ===========================================================================
extern "C" void kernel_launch(void* const* d_in, const int* in_sizes, int n_in,
                              void* d_out, int out_size, void* d_ws, size_t ws_size,
                              hipStream_t stream)
{
  const float* inp    = (const float*)d_in[0];
  const float* coord  = (const float*)d_in[1];
  const float* cell   = (const float*)d_in[2];
  const float* W_enc  = (const float*)d_in[3];
  const float* b_enc  = (const float*)d_in[4];
  const float* W_ch   = (const float*)d_in[5];
  const float* b_ch   = (const float*)d_in[6];
  const float* W_q    = (const float*)d_in[7];
  const float* b_q    = (const float*)d_in[8];
  const float* W_k    = (const float*)d_in[9];
  const float* b_k    = (const float*)d_in[10];
  const float* W_v    = (const float*)d_in[11];
  const float* b_v    = (const float*)d_in[12];
  const float* W_off1 = (const float*)d_in[13];
  const float* b_off1 = (const float*)d_in[14];
  const float* ln_g   = (const float*)d_in[15];
  const float* ln_b   = (const float*)d_in[16];
  const float* W_off2 = (const float*)d_in[17];
  const float* Wc1    = (const float*)d_in[18];
  const float* bc1    = (const float*)d_in[19];
  const float* Wc2    = (const float*)d_in[20];
  const float* bc2    = (const float*)d_in[21];
  const float* Wi1    = (const float*)d_in[22];
  const float* bi1    = (const float*)d_in[23];
  const float* Wi2    = (const float*)d_in[24];
  const float* bi2    = (const float*)d_in[25];

  char* base = (char*)d_ws;
  size_t off = 0;
  auto alloc = [&](size_t bytes) -> char* {
    char* r = base + off;
    off = (off + bytes + 255) & ~(size_t)255;
    return r;
  };

  // --- scratch region (dead before gemm_big runs; Pb aliases it) ---
  float* obuf   = (float*)alloc((size_t)HW * 256 * 4);
  float* offsb  = (float*)alloc((size_t)HW * 98 * 4);
  u16*   feat1  = (u16*)  alloc((size_t)HW * 64 * 2);
  u16*   feat   = (u16*)  alloc((size_t)HW * 256 * 2);
  u16*   relbuf = (u16*)  alloc((size_t)NQ * 128 * 2);
  u16*   Btqkv  = (u16*)  alloc((size_t)768 * 2304 * 2);
  u16*   Btch   = (u16*)  alloc((size_t)256 * 576 * 2);
  u16*   Btoff1 = (u16*)  alloc((size_t)256 * 800 * 2);
  u16*   Btoff2 = (u16*)  alloc((size_t)112 * 256 * 2);
  u16*   Btc1   = (u16*)  alloc((size_t)256 * 128 * 2);
  u16*   Btc2   = (u16*)  alloc((size_t)64 * 256 * 2);
  // gemm_big bf16 partials alias scratch: 16 x 2MB = 33.6MB at base+0.
  u16* Pb = (u16*)base;
  // qkv bf16 partials at [36MB, 54.9MB): past live scratch (~16MB),
  // disjoint from Pb's 33.6MB, dead before gemm_big.
  u16* Pqb = (u16*)(base + ((size_t)36 << 20));
  {
    size_t need = ((size_t)36 << 20) + (size_t)QSPLIT * NQ * 768 * 2;
    if (off < need) off = (need + 255) & ~(size_t)255;
  }
  // --- persistent buffers ---
  u16*   fqkvb   = (u16*)  alloc((size_t)HW * 768 * 2);
  u16*   fqkvKb  = (u16*)  alloc((size_t)HW * 256 * 2);
  u16*   fqkvVb  = (u16*)  alloc((size_t)HW * 256 * 2);
  float* attnval = (float*)alloc((size_t)NQ * 49 * 8 * 4);
  int*   vidxb   = (int*)  alloc((size_t)NQ * 49 * 4);
  float* skipb   = (float*)alloc((size_t)NQ * 3 * 4);
  u16*   Wi1p    = (u16*)  alloc((size_t)256 * KBIG * 2);
  float* bqkv    = (float*)alloc(768 * 4);
  (void)ws_size; (void)in_sizes; (void)n_in; (void)out_size;

  // --- launch A: encoder conv ∥ Btch pack (only what the next kernel needs)
  pack_enc<<<CONV_BLKS + (SZ_CH + 255) / 256, 256, 0, stream>>>(
      inp, W_enc, b_enc, feat1, W_ch, Btch);

  // --- launch B: ch-conv GEMM ∥ ALL remaining packing (off critical path)
  conv_pack<<<CONV2_BLKS + (SZ_REST + 255) / 256, 256, 0, stream>>>(
      feat1, Btch, feat, b_ch,
      W_q, W_k, W_v, W_off1, W_off2, Wc1, Wc2, Wi1, b_q, b_k, b_v,
      Btqkv, Btoff1, Btoff2, Btc1, Btc2, Wi1p, bqkv);

  // merged qkv + off1 (overlap)
  gemm_feat<<<NBLK_QKV + NBLK_OFF1, 256, 0, stream>>>(
      feat, Btqkv, Pqb, Btoff1, obuf, b_off1);
  // merged reduce_qkv ∥ (ln_gelu + off2 1x1-conv MFMA); also emits the
  // dense 2MB K and V tables
  post_feat<<<RQ_BLKS + LNO_BLKS, 256, 0, stream>>>(
      Pqb, bqkv, fqkvb, fqkvKb, fqkvVb, obuf, ln_g, ln_b, Btoff2, offsb);

  // --- per-query attention path ---
  sampler<<<NQ, 256, 0, stream>>>(coord, fqkvb, fqkvKb, offsb, inp,
                                  attnval, relbuf, vidxb, skipb);
  // fused c1 + c2 + softmax
  attn_wc<<<NQ / 16, 256, 0, stream>>>(relbuf, Btc1, bc1, Btc2, bc2, attnval);

  // --- big MLP: 128x256 tile, bf16 gather-A, dbuf glds-B + counted vmcnt,
  //     split-K(16), bf16 partials ---
  gemm_big<<<dim3(32, SPLITK), 512, 0, stream>>>(
      Wi1p, fqkvVb, attnval, vidxb, cell, Pb);
  reduce_final<<<NQ, 256, 0, stream>>>(Pb, bi1, Wi2, bi2, skipb, (float*)d_out);
}